// Round 7
// baseline (366.641 us; speedup 1.0000x reference)
//
#include <hip/hip_runtime.h>
#include <cstdint>
#include <cstddef>

#define B_ 2
#define S_ 2048
#define HID_ 1024
#define H_ 16
#define DH_ 64

typedef __attribute__((ext_vector_type(8))) short short8;
typedef __attribute__((ext_vector_type(8))) unsigned short ushort8;
typedef __attribute__((ext_vector_type(4))) unsigned short ushort4v;
typedef __attribute__((ext_vector_type(4))) float floatx4;
typedef __attribute__((ext_vector_type(4))) float float4v;

static __device__ __forceinline__ unsigned short f2bf(float f) {
  unsigned int u = __float_as_uint(f);
  u += 0x7fffu + ((u >> 16) & 1u);
  return (unsigned short)(u >> 16);
}
static __device__ __forceinline__ float bf2f(unsigned short h) {
  return __uint_as_float(((unsigned int)h) << 16);
}

// ---------------------------------------------------------------------------
// Kernel 0: conversions. (unchanged, proven)
// ---------------------------------------------------------------------------
__global__ __launch_bounds__(256) void convert_kernel(
    const float* __restrict__ x, const float* __restrict__ w1,
    const float* __restrict__ w2, unsigned short* __restrict__ x_bf,
    unsigned short* __restrict__ w1t, unsigned short* __restrict__ w2t_hi,
    unsigned short* __restrict__ w2t_lo) {
  const int NX = B_ * S_ * HID_;
  const int NW = HID_ * HID_;
  int idx = blockIdx.x * 256 + threadIdx.x;
  if (idx < NX) {
    x_bf[idx] = f2bf(x[idx]);
  } else if (idx < NX + NW) {
    int i = idx - NX;
    int n = i >> 10, k = i & 1023;
    w1t[i] = f2bf(w1[k * HID_ + n]);
  } else if (idx < NX + 2 * NW) {
    int i = idx - NX - NW;
    int n = i >> 10, k = i & 1023;
    float v = w2[k * HID_ + n];
    unsigned short h = f2bf(v);
    w2t_hi[i] = h;
    w2t_lo[i] = f2bf(v - bf2f(h));
  }
}

// ---------------------------------------------------------------------------
// Kernel A: per-head QKV projection + bias + rotary. (unchanged, proven)
// ---------------------------------------------------------------------------
__global__ __launch_bounds__(256) void qkv_kernel(
    const float* __restrict__ x, const float* __restrict__ wq,
    const float* __restrict__ bq, const float* __restrict__ wk,
    const float* __restrict__ bk, const float* __restrict__ wv,
    const float* __restrict__ theta,
    unsigned short* __restrict__ q_h, unsigned short* __restrict__ q_l,
    unsigned short* __restrict__ k_h, unsigned short* __restrict__ k_l,
    unsigned short* __restrict__ v_th, unsigned short* __restrict__ v_tl,
    int b) {
  __shared__ __align__(16) float xs[64 * 68];
  __shared__ __align__(16) float wqs[64 * 68];
  __shared__ __align__(16) float wks[64 * 68];
  __shared__ __align__(16) float wvs[64 * 68];

  int tid = threadIdx.x;
  int st = blockIdx.x, h = blockIdx.y;
  int s0 = st * 64;

#pragma unroll
  for (int i = 0; i < 4; ++i) {
    int cid = tid + i * 256;
    int r = cid >> 4, c4 = (cid & 15) * 4;
    *reinterpret_cast<float4v*>(&xs[r * 68 + c4]) =
        *reinterpret_cast<const float4v*>(x + ((size_t)(b * S_ + s0 + r)) * HID_ + h * DH_ + c4);
  }
#pragma unroll
  for (int i = 0; i < 4; ++i) {
    int cid = tid + i * 256;
    int d = cid >> 4, c4 = (cid & 15) * 4;
    *reinterpret_cast<float4v*>(&wqs[d * 68 + c4]) =
        *reinterpret_cast<const float4v*>(wq + (size_t)(h * DH_ + d) * DH_ + c4);
    *reinterpret_cast<float4v*>(&wks[d * 68 + c4]) =
        *reinterpret_cast<const float4v*>(wk + (size_t)(h * DH_ + d) * DH_ + c4);
    *reinterpret_cast<float4v*>(&wvs[d * 68 + c4]) =
        *reinterpret_cast<const float4v*>(wv + (size_t)(h * DH_ + d) * DH_ + c4);
  }
  __syncthreads();

  int rg = tid >> 3;
  int cg = tid & 7;
  int r0 = rg * 2, c0 = cg * 8;

  float aq[2][8], ak[2][8], av[2][8];
#pragma unroll
  for (int i = 0; i < 2; ++i)
#pragma unroll
    for (int j = 0; j < 8; ++j) { aq[i][j] = 0.f; ak[i][j] = 0.f; av[i][j] = 0.f; }

  for (int d = 0; d < 64; ++d) {
    float x0 = xs[(r0 + 0) * 68 + d];
    float x1 = xs[(r0 + 1) * 68 + d];
#pragma unroll
    for (int j = 0; j < 8; ++j) {
      float wqv = wqs[d * 68 + c0 + j];
      float wkv = wks[d * 68 + c0 + j];
      float wvv = wvs[d * 68 + c0 + j];
      aq[0][j] += x0 * wqv; aq[1][j] += x1 * wqv;
      ak[0][j] += x0 * wkv; ak[1][j] += x1 * wkv;
      av[0][j] += x0 * wvv; av[1][j] += x1 * wvv;
    }
  }

  float thv[8], bqv[8], bkv[8];
#pragma unroll
  for (int j = 0; j < 8; ++j) {
    thv[j] = theta[h * DH_ + c0 + j];
    bqv[j] = bq[h * DH_ + c0 + j];
    bkv[j] = bk[h * DH_ + c0 + j];
  }

  // Reuse xs/wqs LDS as bf16 V-transpose staging (all reads of them are done).
  __syncthreads();
  unsigned short* VtH = reinterpret_cast<unsigned short*>(xs);   // [64 d][72]
  unsigned short* VtL = reinterpret_cast<unsigned short*>(wqs);  // [64 d][72]

#pragma unroll
  for (int i = 0; i < 2; ++i) {
    int s = s0 + r0 + i;
    size_t qb = ((size_t)h * S_ + s) * 128;
    ushort8 qch, qcl, qsh, qsl, kch, kcl, ksh, ksl;
#pragma unroll
    for (int j = 0; j < 8; ++j) {
      float q = aq[i][j] + bqv[j];
      float k = ak[i][j] + bkv[j];
      float ang = (float)s * thv[j];
      float cs = cosf(ang), sn = sinf(ang);
      float qc = q * cs, qs = q * sn;
      unsigned short hq1 = f2bf(qc);
      qch[j] = hq1;
      qcl[j] = f2bf(qc - bf2f(hq1));
      unsigned short hq2 = f2bf(qs);
      qsh[j] = hq2;
      qsl[j] = f2bf(qs - bf2f(hq2));
      float kc = k * cs, ksn = k * sn;
      unsigned short h1 = f2bf(kc);
      kch[j] = h1;
      kcl[j] = f2bf(kc - bf2f(h1));
      unsigned short h2 = f2bf(ksn);
      ksh[j] = h2;
      ksl[j] = f2bf(ksn - bf2f(h2));
      float vv = av[i][j];
      unsigned short vh1 = f2bf(vv);
      VtH[(c0 + j) * 72 + (r0 + i)] = vh1;
      VtL[(c0 + j) * 72 + (r0 + i)] = f2bf(vv - bf2f(vh1));
    }
    *reinterpret_cast<ushort8*>(q_h + qb + c0) = qch;
    *reinterpret_cast<ushort8*>(q_h + qb + 64 + c0) = qsh;
    *reinterpret_cast<ushort8*>(q_l + qb + c0) = qcl;
    *reinterpret_cast<ushort8*>(q_l + qb + 64 + c0) = qsl;
    *reinterpret_cast<ushort8*>(k_h + qb + c0) = kch;
    *reinterpret_cast<ushort8*>(k_h + qb + 64 + c0) = ksh;
    *reinterpret_cast<ushort8*>(k_l + qb + c0) = kcl;
    *reinterpret_cast<ushort8*>(k_l + qb + 64 + c0) = ksl;
  }
  __syncthreads();
  // Coalesced transposed store: v_t[h][d][S]
#pragma unroll
  for (int i = 0; i < 2; ++i) {
    int cid = tid + i * 256;
    int d = cid >> 3, t8 = (cid & 7) * 8;
    size_t gb = ((size_t)(h * 64 + d)) * S_ + s0 + t8;
    *reinterpret_cast<ushort8*>(v_th + gb) = *reinterpret_cast<const ushort8*>(&VtH[d * 72 + t8]);
    *reinterpret_cast<ushort8*>(v_tl + gb) = *reinterpret_cast<const ushort8*>(&VtL[d * 72 + t8]);
  }
}

// ---------------------------------------------------------------------------
// Kernel B: retention v5 — KVBLK=32 + quarter-split (the r6 lesson: LDS-pipe
// ~44% busy with 272KB/iter re-reads; 64KiB LDS capped us at 2 blocks/CU and
// latency exposure ate the rest).
//  - KV tile 32 wide: LDS = K 16K + V 16K + Sc 8K = 40 KiB -> 4 blocks/CU
//    (16 waves, 4/SIMD). Same MFMA mappings/swizzles; QK ns in {0,1}; PV is
//    a single 32-t MFMA chain; diagonal test kt >= 2*qt with offset
//    32*(kt-2*qt).
//  - Quarter-split: 4 blocks per (h,qt), grid 2048, 1024 resident + 1024
//    pending -> sustained backfill at 4 blocks/CU. Heavy-first, XCD-affine
//    head decode (bits 0-3) keeps K/V+Q inside each XCD's L2.
// ---------------------------------------------------------------------------
#define SCOFF(row, colb)   ((row) * 128 + ((colb) ^ (((row) & 7) << 4)))

__global__ __launch_bounds__(256, 4) void retention_q_kernel(
    const unsigned short* __restrict__ q_h, const unsigned short* __restrict__ q_l,
    const unsigned short* __restrict__ k_h, const unsigned short* __restrict__ k_l,
    const unsigned short* __restrict__ v_th, const unsigned short* __restrict__ v_tl,
    float* __restrict__ partial) {
  __shared__ __align__(16) unsigned short Kh[32 * 128];  // 8 KiB swizzled (256B rows)
  __shared__ __align__(16) unsigned short Kl[32 * 128];  // 8 KiB
  __shared__ __align__(16) unsigned short Vh[64 * 64];   // 8 KiB [d][t], 128B rows, t<32 used
  __shared__ __align__(16) unsigned short Vl[64 * 64];   // 8 KiB
  __shared__ __align__(16) float Sc[64 * 32];            // 8 KiB swizzled (128B rows)

  char* KhB = (char*)Kh;
  char* KlB = (char*)Kl;
  char* VhB = (char*)Vh;
  char* VlB = (char*)Vl;
  char* ScB = (char*)Sc;

  int tid = threadIdx.x;
  int w = tid >> 6;
  int lane = tid & 63, ln = lane & 15, quad = lane >> 4;
  // Decode (bijective on [0,2048)): bits0-3 -> head (XCD-affine), bits4-5 ->
  // quarter, bits6-10 -> qt heavy-first.
  int f = blockIdx.x;
  int h = ((f & 7) << 1) | ((f >> 3) & 1);
  int quarter = (f >> 4) & 3;
  int qt = 31 - (f >> 6);
  int s0 = qt * 64;
  int prow = quad * 4;

  // kt range for this quarter over T = 2*qt+2 tiles of 32.
  int T = 2 * qt + 2;
  int kt0 = (quarter * T) >> 2;
  int kt1 = ((quarter + 1) * T) >> 2;

  const float lo_c = -6.2383246250395075f, hi_c = -3.4657359027997265f;
  float gam = 1.f - __expf(lo_c + (hi_c - lo_c) * ((float)h * (1.f / 15.f)));
  float logg = __logf(gam);

  // Factored decay: gamma^(s-t) = gamma^(64qt-32kt) * gamma^lrow * gamma^-lcol
  float rowf[4], colf[2];
#pragma unroll
  for (int rr = 0; rr < 4; ++rr)
    rowf[rr] = __expf((float)(w * 16 + prow + rr) * logg);
#pragma unroll
  for (int ns = 0; ns < 2; ++ns)
    colf[ns] = __expf(-(float)(ns * 16 + ln) * logg);

  const unsigned short* khb = k_h + (size_t)h * S_ * 128;
  const unsigned short* klb = k_l + (size_t)h * S_ * 128;
  const unsigned short* vhb = v_th + (size_t)h * 64 * S_;
  const unsigned short* vlb = v_tl + (size_t)h * 64 * S_;

  // Q fragments (A-layout), precomputed bf16 hi/lo. (proven)
  int sQ = s0 + w * 16 + ln;
  const unsigned short* qhp = q_h + ((size_t)h * S_ + sQ) * 128 + quad * 8;
  const unsigned short* qlp = q_l + ((size_t)h * S_ + sQ) * 128 + quad * 8;
  short8 qfh[4], qfl[4];
#pragma unroll
  for (int c = 0; c < 4; ++c) {
    qfh[c] = *reinterpret_cast<const short8*>(qhp + c * 32);
    qfl[c] = *reinterpret_cast<const short8*>(qlp + c * 32);
  }

  floatx4 accO[4];
#pragma unroll
  for (int i = 0; i < 4; ++i) accO[i] = (floatx4){0.f, 0.f, 0.f, 0.f};

  // Prologue: stage tile kt0 -> LDS; prefetch kt0+1 into regs.
  ushort8 skh[2], skl[2], svh, svl;
  {
    int t00 = kt0 * 32;
#pragma unroll
    for (int i = 0; i < 2; ++i) {
      int cid = tid + i * 256;
      int r = cid >> 4, c8 = (cid & 15) * 8;
      skh[i] = *reinterpret_cast<const ushort8*>(khb + ((size_t)(t00 + r)) * 128 + c8);
      skl[i] = *reinterpret_cast<const ushort8*>(klb + ((size_t)(t00 + r)) * 128 + c8);
    }
    {
      int d = tid >> 2, t8 = (tid & 3) * 8;
      svh = *reinterpret_cast<const ushort8*>(vhb + (size_t)d * S_ + t00 + t8);
      svl = *reinterpret_cast<const ushort8*>(vlb + (size_t)d * S_ + t00 + t8);
    }
#pragma unroll
    for (int i = 0; i < 2; ++i) {
      int cid = tid + i * 256;
      int r = cid >> 4;
      int ko = r * 256 + (((cid & 15) * 16) ^ ((r & 7) << 4));
      *reinterpret_cast<ushort8*>(KhB + ko) = skh[i];
      *reinterpret_cast<ushort8*>(KlB + ko) = skl[i];
    }
    {
      int d = tid >> 2;
      int vo = d * 128 + (((tid & 3) * 16) ^ ((d & 7) << 4));
      *reinterpret_cast<ushort8*>(VhB + vo) = svh;
      *reinterpret_cast<ushort8*>(VlB + vo) = svl;
    }
    if (kt0 + 1 < kt1) {
      int t01 = (kt0 + 1) * 32;
#pragma unroll
      for (int i = 0; i < 2; ++i) {
        int cid = tid + i * 256;
        int r = cid >> 4, c8 = (cid & 15) * 8;
        skh[i] = *reinterpret_cast<const ushort8*>(khb + ((size_t)(t01 + r)) * 128 + c8);
        skl[i] = *reinterpret_cast<const ushort8*>(klb + ((size_t)(t01 + r)) * 128 + c8);
      }
      int d = tid >> 2, t8 = (tid & 3) * 8;
      svh = *reinterpret_cast<const ushort8*>(vhb + (size_t)d * S_ + t01 + t8);
      svl = *reinterpret_cast<const ushort8*>(vlb + (size_t)d * S_ + t01 + t8);
    }
  }
  __syncthreads();

  for (int kt = kt0; kt < kt1; ++kt) {
    // QK^T split-MFMA (proven structure; ns in {0,1}).
    floatx4 accS[2];
#pragma unroll
    for (int ns = 0; ns < 2; ++ns) {
      floatx4 a = (floatx4){0.f, 0.f, 0.f, 0.f};
      int row = ns * 16 + ln;
#pragma unroll
      for (int ks = 0; ks < 4; ++ks) {
        int off = row * 256 + ((ks * 64 + quad * 16) ^ ((ln & 7) << 4));
        short8 kh = *reinterpret_cast<const short8*>(KhB + off);
        short8 kl = *reinterpret_cast<const short8*>(KlB + off);
        a = __builtin_amdgcn_mfma_f32_16x16x32_bf16(qfh[ks], kh, a, 0, 0, 0);
        a = __builtin_amdgcn_mfma_f32_16x16x32_bf16(qfl[ks], kh, a, 0, 0, 0);
        a = __builtin_amdgcn_mfma_f32_16x16x32_bf16(qfh[ks], kl, a, 0, 0, 0);
      }
      accS[ns] = a;
    }

    // Factored decay; tiles kt >= 2*qt overlap the diagonal (mask with
    // row >= col + 32*(kt-2*qt)).
    float tf = __expf((float)(64 * qt - 32 * kt) * logg);
    float trf[4];
#pragma unroll
    for (int rr = 0; rr < 4; ++rr) trf[rr] = tf * rowf[rr];
    if (kt < 2 * qt) {
#pragma unroll
      for (int ns = 0; ns < 2; ++ns) {
        int col = ns * 16 + ln;
#pragma unroll
        for (int rr = 0; rr < 4; ++rr) {
          int row = w * 16 + prow + rr;
          *reinterpret_cast<float*>(ScB + SCOFF(row, col * 4)) =
              accS[ns][rr] * trf[rr] * colf[ns];
        }
      }
    } else {
      int off32 = 32 * (kt - 2 * qt);
#pragma unroll
      for (int ns = 0; ns < 2; ++ns) {
        int col = ns * 16 + ln;
#pragma unroll
        for (int rr = 0; rr < 4; ++rr) {
          int row = w * 16 + prow + rr;
          float v = accS[ns][rr] * trf[rr] * colf[ns];
          *reinterpret_cast<float*>(ScB + SCOFF(row, col * 4)) =
              (row >= col + off32) ? v : 0.f;
        }
      }
    }

    // PV split-MFMA: single 32-t chain. Sc rows are wave-private (no barrier).
    {
      int prw = w * 16 + ln;
      float4v p0 = *reinterpret_cast<const float4v*>(ScB + SCOFF(prw, quad * 32));
      float4v p1 = *reinterpret_cast<const float4v*>(ScB + SCOFF(prw, quad * 32 + 16));
      short8 ph, pl;
#pragma unroll
      for (int j = 0; j < 4; ++j) {
        unsigned short hh = f2bf(p0[j]);
        ph[j] = (short)hh;
        pl[j] = (short)f2bf(p0[j] - bf2f(hh));
        unsigned short hh2 = f2bf(p1[j]);
        ph[4 + j] = (short)hh2;
        pl[4 + j] = (short)f2bf(p1[j] - bf2f(hh2));
      }
#pragma unroll
      for (int ds = 0; ds < 4; ++ds) {
        int d = ds * 16 + ln;
        int voff = d * 128 + ((quad * 16) ^ ((ln & 7) << 4));
        short8 vh = *reinterpret_cast<const short8*>(VhB + voff);
        short8 vl = *reinterpret_cast<const short8*>(VlB + voff);
        accO[ds] = __builtin_amdgcn_mfma_f32_16x16x32_bf16(ph, vh, accO[ds], 0, 0, 0);
        accO[ds] = __builtin_amdgcn_mfma_f32_16x16x32_bf16(pl, vh, accO[ds], 0, 0, 0);
        accO[ds] = __builtin_amdgcn_mfma_f32_16x16x32_bf16(ph, vl, accO[ds], 0, 0, 0);
      }
    }

    __syncthreads();  // all waves done reading tile kt
    if (kt + 1 < kt1) {
      // Write prefetched tile kt+1 (vmcnt drains; co-resident blocks cover).
#pragma unroll
      for (int i = 0; i < 2; ++i) {
        int cid = tid + i * 256;
        int r = cid >> 4;
        int ko = r * 256 + (((cid & 15) * 16) ^ ((r & 7) << 4));
        *reinterpret_cast<ushort8*>(KhB + ko) = skh[i];
        *reinterpret_cast<ushort8*>(KlB + ko) = skl[i];
      }
      {
        int d = tid >> 2;
        int vo = d * 128 + (((tid & 3) * 16) ^ ((d & 7) << 4));
        *reinterpret_cast<ushort8*>(VhB + vo) = svh;
        *reinterpret_cast<ushort8*>(VlB + vo) = svl;
      }
      // Issue prefetch for tile kt+2.
      if (kt + 2 < kt1) {
        int t0n = (kt + 2) * 32;
#pragma unroll
        for (int i = 0; i < 2; ++i) {
          int cid = tid + i * 256;
          int r = cid >> 4, c8 = (cid & 15) * 8;
          skh[i] = *reinterpret_cast<const ushort8*>(khb + ((size_t)(t0n + r)) * 128 + c8);
          skl[i] = *reinterpret_cast<const ushort8*>(klb + ((size_t)(t0n + r)) * 128 + c8);
        }
        int d = tid >> 2, t8 = (tid & 3) * 8;
        svh = *reinterpret_cast<const ushort8*>(vhb + (size_t)d * S_ + t0n + t8);
        svl = *reinterpret_cast<const ushort8*>(vlb + (size_t)d * S_ + t0n + t8);
      }
      __syncthreads();  // tile kt+1 visible
    }
  }

  // Epilogue: store raw fp32 partial accO (16 KB/block).
  float* pout = partial + ((size_t)((h * 32 + qt) * 4 + quarter)) * 4096;
#pragma unroll
  for (int ds = 0; ds < 4; ++ds) {
#pragma unroll
    for (int rr = 0; rr < 4; ++rr) {
      pout[(w * 16 + quad * 4 + rr) * 64 + ds * 16 + ln] = accO[ds][rr];
    }
  }
}

// ---------------------------------------------------------------------------
// Kernel B2: combine 4 quarters + GroupNorm (proven (r2,sub) mapping).
// ---------------------------------------------------------------------------
__global__ __launch_bounds__(256) void combine_gn_kernel(
    const float* __restrict__ partial, const float* __restrict__ gn_w,
    const float* __restrict__ gn_b, float* __restrict__ retn, int b) {
  __shared__ float gnred[64][8];
  int tid = threadIdx.x;
  int qi = blockIdx.x;            // qi = h*32 + qt
  int h = qi >> 5, qt = qi & 31;
  const float* p = partial + (size_t)qi * 16384;

  int r2 = tid >> 2;
  int sub = tid & 3;
  float a16[16];
#pragma unroll
  for (int c = 0; c < 4; ++c) {
    int o = r2 * 64 + sub * 16 + c * 4;
    float4v v0 = *reinterpret_cast<const float4v*>(p + o);
    float4v v1 = *reinterpret_cast<const float4v*>(p + 4096 + o);
    float4v v2 = *reinterpret_cast<const float4v*>(p + 8192 + o);
    float4v v3 = *reinterpret_cast<const float4v*>(p + 12288 + o);
#pragma unroll
    for (int j = 0; j < 4; ++j) a16[c * 4 + j] = (v0[j] + v1[j]) + (v2[j] + v3[j]);
  }

  float psum = 0.f, psq = 0.f;
#pragma unroll
  for (int i = 0; i < 16; ++i) { psum += a16[i]; psq += a16[i] * a16[i]; }
  gnred[r2][sub] = psum;
  gnred[r2][4 + sub] = psq;
  float sum = gnred[r2][0] + gnred[r2][1] + gnred[r2][2] + gnred[r2][3];
  float sq = gnred[r2][4] + gnred[r2][5] + gnred[r2][6] + gnred[r2][7];
  float mean = sum * (1.f / 64.f);
  float var = sq * (1.f / 64.f) - mean * mean;
  float rstd = rsqrtf(var + 1e-5f);

  size_t obase = ((size_t)(b * S_ + qt * 64 + r2)) * HID_ + h * DH_ + sub * 16;
#pragma unroll
  for (int i = 0; i < 16; ++i) {
    float gw = gn_w[h * DH_ + sub * 16 + i];
    float gb = gn_b[h * DH_ + sub * 16 + i];
    retn[obase + i] = (a16[i] - mean) * rstd * gw + gb;
  }
}

// ---------------------------------------------------------------------------
// GEMM 1 (gate): BN 128->64 (grid 512 -> 2 blocks/CU; the r5 occupancy
// lesson applied to the GEMMs). Wave tile 64x32, acc[4][2]. Same MFMA
// mappings and epilogue math.
// ---------------------------------------------------------------------------
__global__ __launch_bounds__(256) void gemm_gate_kernel(
    const unsigned short* __restrict__ A, const unsigned short* __restrict__ Bt,
    const float* __restrict__ retn, unsigned short* __restrict__ pre_hi,
    unsigned short* __restrict__ pre_lo) {
  const int K = HID_;
  __shared__ __align__(16) unsigned short Al[128 * 56];
  __shared__ __align__(16) unsigned short Bl[64 * 56];

  int tid = threadIdx.x;
  int lane = tid & 63, ln = lane & 15, quad = lane >> 4;
  int w = tid >> 6, wm = w >> 1, wn = w & 1;
  int m0 = blockIdx.y * 128, n0 = blockIdx.x * 64;

  floatx4 acc[4][2];
#pragma unroll
  for (int i = 0; i < 4; ++i)
#pragma unroll
    for (int j = 0; j < 2; ++j) acc[i][j] = (floatx4){0.f, 0.f, 0.f, 0.f};

  for (int k0 = 0; k0 < K; k0 += 32) {
    __syncthreads();
#pragma unroll
    for (int i = 0; i < 2; ++i) {
      int cid = tid + i * 256;
      int r = cid >> 2, c8 = (cid & 3) * 8;
      *reinterpret_cast<ushort8*>(&Al[r * 56 + c8]) =
          *reinterpret_cast<const ushort8*>(A + (size_t)(m0 + r) * K + k0 + c8);
    }
    {
      int r = tid >> 2, c8 = (tid & 3) * 8;
      *reinterpret_cast<ushort8*>(&Bl[r * 56 + c8]) =
          *reinterpret_cast<const ushort8*>(Bt + (size_t)(n0 + r) * K + k0 + c8);
    }
    __syncthreads();

    short8 af[4], bfr[2];
#pragma unroll
    for (int i = 0; i < 4; ++i)
      af[i] = *reinterpret_cast<const short8*>(&Al[(wm * 64 + i * 16 + ln) * 56 + quad * 8]);
#pragma unroll
    for (int i = 0; i < 2; ++i)
      bfr[i] = *reinterpret_cast<const short8*>(&Bl[(wn * 32 + i * 16 + ln) * 56 + quad * 8]);
#pragma unroll
    for (int mi = 0; mi < 4; ++mi)
#pragma unroll
      for (int ni = 0; ni < 2; ++ni)
        acc[mi][ni] = __builtin_amdgcn_mfma_f32_16x16x32_bf16(af[mi], bfr[ni], acc[mi][ni], 0, 0, 0);
  }

#pragma unroll
  for (int mi = 0; mi < 4; ++mi) {
#pragma unroll
    for (int r = 0; r < 4; ++r) {
      int row = m0 + wm * 64 + mi * 16 + quad * 4 + r;
#pragma unroll
      for (int ni = 0; ni < 2; ++ni) {
        int col = n0 + wn * 32 + ni * 16 + ln;
        float g = acc[mi][ni][r];
        float val = g * (1.f / (1.f + __expf(-g))) + retn[(size_t)row * HID_ + col];
        unsigned short hh = f2bf(val);
        size_t oidx = (size_t)row * HID_ + col;
        pre_hi[oidx] = hh;
        pre_lo[oidx] = f2bf(val - bf2f(hh));
      }
    }
  }
}

// ---------------------------------------------------------------------------
// GEMM 2 (output): BN 128->64, same restructure.
// ---------------------------------------------------------------------------
__global__ __launch_bounds__(256) void gemm_out_kernel(
    const unsigned short* __restrict__ Ah, const unsigned short* __restrict__ Alo,
    const unsigned short* __restrict__ Bth, const unsigned short* __restrict__ Btlo,
    float* __restrict__ out_f) {
  const int K = HID_;
  __shared__ __align__(16) unsigned short AhS[128 * 56];
  __shared__ __align__(16) unsigned short AlS[128 * 56];
  __shared__ __align__(16) unsigned short BhS[64 * 56];
  __shared__ __align__(16) unsigned short BlS[64 * 56];

  int tid = threadIdx.x;
  int lane = tid & 63, ln = lane & 15, quad = lane >> 4;
  int w = tid >> 6, wm = w >> 1, wn = w & 1;
  int m0 = blockIdx.y * 128, n0 = blockIdx.x * 64;

  floatx4 acc[4][2];
#pragma unroll
  for (int i = 0; i < 4; ++i)
#pragma unroll
    for (int j = 0; j < 2; ++j) acc[i][j] = (floatx4){0.f, 0.f, 0.f, 0.f};

  for (int k0 = 0; k0 < K; k0 += 32) {
    __syncthreads();
#pragma unroll
    for (int i = 0; i < 2; ++i) {
      int cid = tid + i * 256;
      int r = cid >> 2, c8 = (cid & 3) * 8;
      size_t ga = (size_t)(m0 + r) * K + k0 + c8;
      *reinterpret_cast<ushort8*>(&AhS[r * 56 + c8]) = *reinterpret_cast<const ushort8*>(Ah + ga);
      *reinterpret_cast<ushort8*>(&AlS[r * 56 + c8]) = *reinterpret_cast<const ushort8*>(Alo + ga);
    }
    {
      int r = tid >> 2, c8 = (tid & 3) * 8;
      size_t gb = (size_t)(n0 + r) * K + k0 + c8;
      *reinterpret_cast<ushort8*>(&BhS[r * 56 + c8]) = *reinterpret_cast<const ushort8*>(Bth + gb);
      *reinterpret_cast<ushort8*>(&BlS[r * 56 + c8]) = *reinterpret_cast<const ushort8*>(Btlo + gb);
    }
    __syncthreads();

    short8 afh[4], afl[4], bfh[2], bfl[2];
#pragma unroll
    for (int i = 0; i < 4; ++i) {
      int ao = (wm * 64 + i * 16 + ln) * 56 + quad * 8;
      afh[i] = *reinterpret_cast<const short8*>(&AhS[ao]);
      afl[i] = *reinterpret_cast<const short8*>(&AlS[ao]);
    }
#pragma unroll
    for (int i = 0; i < 2; ++i) {
      int bo = (wn * 32 + i * 16 + ln) * 56 + quad * 8;
      bfh[i] = *reinterpret_cast<const short8*>(&BhS[bo]);
      bfl[i] = *reinterpret_cast<const short8*>(&BlS[bo]);
    }
#pragma unroll
    for (int mi = 0; mi < 4; ++mi)
#pragma unroll
      for (int ni = 0; ni < 2; ++ni) {
        floatx4 a = acc[mi][ni];
        a = __builtin_amdgcn_mfma_f32_16x16x32_bf16(afh[mi], bfh[ni], a, 0, 0, 0);
        a = __builtin_amdgcn_mfma_f32_16x16x32_bf16(afl[mi], bfh[ni], a, 0, 0, 0);
        a = __builtin_amdgcn_mfma_f32_16x16x32_bf16(afh[mi], bfl[ni], a, 0, 0, 0);
        acc[mi][ni] = a;
      }
  }

#pragma unroll
  for (int mi = 0; mi < 4; ++mi) {
#pragma unroll
    for (int r = 0; r < 4; ++r) {
      int row = m0 + wm * 64 + mi * 16 + quad * 4 + r;
#pragma unroll
      for (int ni = 0; ni < 2; ++ni) {
        int col = n0 + wn * 32 + ni * 16 + ln;
        out_f[(size_t)row * HID_ + col] = acc[mi][ni][r];
      }
    }
  }
}

// ---------------------------------------------------------------------------
extern "C" void kernel_launch(void* const* d_in, const int* in_sizes, int n_in,
                              void* d_out, int out_size, void* d_ws,
                              size_t ws_size, hipStream_t stream) {
  (void)in_sizes; (void)n_in; (void)out_size; (void)ws_size;
  const float* x = (const float*)d_in[0];
  const float* wq = (const float*)d_in[1];
  const float* bq = (const float*)d_in[2];
  const float* wk = (const float*)d_in[3];
  const float* bk = (const float*)d_in[4];
  const float* wv = (const float*)d_in[5];
  const float* theta = (const float*)d_in[6];
  const float* gn_w = (const float*)d_in[7];
  const float* gn_b = (const float*)d_in[8];
  const float* w1 = (const float*)d_in[9];
  const float* w2 = (const float*)d_in[10];

  const size_t MB = 1024 * 1024;
  char* ws = (char*)d_ws;
  unsigned short* x_bf   = (unsigned short*)(ws + 0 * MB);    //  8 MiB
  unsigned short* w1t    = (unsigned short*)(ws + 8 * MB);    //  2 MiB
  unsigned short* w2t_hi = (unsigned short*)(ws + 10 * MB);   //  2 MiB
  unsigned short* w2t_lo = (unsigned short*)(ws + 12 * MB);   //  2 MiB
  unsigned short* q_h    = (unsigned short*)(ws + 14 * MB);   //  8 MiB (1 batch)
  unsigned short* q_l    = (unsigned short*)(ws + 22 * MB);   //  8 MiB
  unsigned short* k_h    = (unsigned short*)(ws + 30 * MB);   //  8 MiB
  unsigned short* k_l    = (unsigned short*)(ws + 38 * MB);   //  8 MiB
  unsigned short* v_th   = (unsigned short*)(ws + 46 * MB);   //  4 MiB
  unsigned short* v_tl   = (unsigned short*)(ws + 50 * MB);   //  4 MiB
  float*          retn   = (float*)(ws + 54 * MB);            // 16 MiB (both batches)
  float*          partial= (float*)(ws + 70 * MB);            // 32 MiB (per batch, reused)
  unsigned short* pre_hi = (unsigned short*)(ws + 14 * MB);   //  8 MiB (alias q_h, dead by then)
  unsigned short* pre_lo = (unsigned short*)(ws + 22 * MB);   //  8 MiB (alias q_l)
  float* out = (float*)d_out;

  convert_kernel<<<dim3(24576), 256, 0, stream>>>(x, w1, w2, x_bf, w1t, w2t_hi, w2t_lo);
  for (int b = 0; b < B_; ++b) {
    qkv_kernel<<<dim3(S_ / 64, H_), 256, 0, stream>>>(
        x, wq, bq, wk, bk, wv, theta, q_h, q_l, k_h, k_l, v_th, v_tl, b);
    retention_q_kernel<<<dim3(2048), 256, 0, stream>>>(
        q_h, q_l, k_h, k_l, v_th, v_tl, partial);
    combine_gn_kernel<<<dim3(512), 256, 0, stream>>>(
        partial, gn_w, gn_b, retn, b);
  }
  gemm_gate_kernel<<<dim3(HID_ / 64, (B_ * S_) / 128), 256, 0, stream>>>(
      x_bf, w1t, retn, pre_hi, pre_lo);
  gemm_out_kernel<<<dim3(HID_ / 64, (B_ * S_) / 128), 256, 0, stream>>>(
      pre_hi, pre_lo, w2t_hi, w2t_lo, out);
}

// Round 9
// 337.951 us; speedup vs baseline: 1.0849x; 1.0849x over previous
//
#include <hip/hip_runtime.h>
#include <cstdint>
#include <cstddef>

#define B_ 2
#define S_ 2048
#define HID_ 1024
#define H_ 16
#define DH_ 64

typedef __attribute__((ext_vector_type(8))) short short8;
typedef __attribute__((ext_vector_type(8))) unsigned short ushort8;
typedef __attribute__((ext_vector_type(4))) unsigned short ushort4v;
typedef __attribute__((ext_vector_type(4))) float floatx4;
typedef __attribute__((ext_vector_type(4))) float float4v;

static __device__ __forceinline__ unsigned short f2bf(float f) {
  unsigned int u = __float_as_uint(f);
  u += 0x7fffu + ((u >> 16) & 1u);
  return (unsigned short)(u >> 16);
}
static __device__ __forceinline__ float bf2f(unsigned short h) {
  return __uint_as_float(((unsigned int)h) << 16);
}

// ---------------------------------------------------------------------------
// Kernel 0: conversions. (unchanged, proven)
// ---------------------------------------------------------------------------
__global__ __launch_bounds__(256) void convert_kernel(
    const float* __restrict__ x, const float* __restrict__ w1,
    const float* __restrict__ w2, unsigned short* __restrict__ x_bf,
    unsigned short* __restrict__ w1t, unsigned short* __restrict__ w2t_hi,
    unsigned short* __restrict__ w2t_lo) {
  const int NX = B_ * S_ * HID_;
  const int NW = HID_ * HID_;
  int idx = blockIdx.x * 256 + threadIdx.x;
  if (idx < NX) {
    x_bf[idx] = f2bf(x[idx]);
  } else if (idx < NX + NW) {
    int i = idx - NX;
    int n = i >> 10, k = i & 1023;
    w1t[i] = f2bf(w1[k * HID_ + n]);
  } else if (idx < NX + 2 * NW) {
    int i = idx - NX - NW;
    int n = i >> 10, k = i & 1023;
    float v = w2[k * HID_ + n];
    unsigned short h = f2bf(v);
    w2t_hi[i] = h;
    w2t_lo[i] = f2bf(v - bf2f(h));
  }
}

// ---------------------------------------------------------------------------
// Kernel A: per-head QKV projection + bias + rotary. (unchanged, proven)
// ---------------------------------------------------------------------------
__global__ __launch_bounds__(256) void qkv_kernel(
    const float* __restrict__ x, const float* __restrict__ wq,
    const float* __restrict__ bq, const float* __restrict__ wk,
    const float* __restrict__ bk, const float* __restrict__ wv,
    const float* __restrict__ theta,
    unsigned short* __restrict__ q_h, unsigned short* __restrict__ q_l,
    unsigned short* __restrict__ k_h, unsigned short* __restrict__ k_l,
    unsigned short* __restrict__ v_th, unsigned short* __restrict__ v_tl,
    int b) {
  __shared__ __align__(16) float xs[64 * 68];
  __shared__ __align__(16) float wqs[64 * 68];
  __shared__ __align__(16) float wks[64 * 68];
  __shared__ __align__(16) float wvs[64 * 68];

  int tid = threadIdx.x;
  int st = blockIdx.x, h = blockIdx.y;
  int s0 = st * 64;

#pragma unroll
  for (int i = 0; i < 4; ++i) {
    int cid = tid + i * 256;
    int r = cid >> 4, c4 = (cid & 15) * 4;
    *reinterpret_cast<float4v*>(&xs[r * 68 + c4]) =
        *reinterpret_cast<const float4v*>(x + ((size_t)(b * S_ + s0 + r)) * HID_ + h * DH_ + c4);
  }
#pragma unroll
  for (int i = 0; i < 4; ++i) {
    int cid = tid + i * 256;
    int d = cid >> 4, c4 = (cid & 15) * 4;
    *reinterpret_cast<float4v*>(&wqs[d * 68 + c4]) =
        *reinterpret_cast<const float4v*>(wq + (size_t)(h * DH_ + d) * DH_ + c4);
    *reinterpret_cast<float4v*>(&wks[d * 68 + c4]) =
        *reinterpret_cast<const float4v*>(wk + (size_t)(h * DH_ + d) * DH_ + c4);
    *reinterpret_cast<float4v*>(&wvs[d * 68 + c4]) =
        *reinterpret_cast<const float4v*>(wv + (size_t)(h * DH_ + d) * DH_ + c4);
  }
  __syncthreads();

  int rg = tid >> 3;
  int cg = tid & 7;
  int r0 = rg * 2, c0 = cg * 8;

  float aq[2][8], ak[2][8], av[2][8];
#pragma unroll
  for (int i = 0; i < 2; ++i)
#pragma unroll
    for (int j = 0; j < 8; ++j) { aq[i][j] = 0.f; ak[i][j] = 0.f; av[i][j] = 0.f; }

  for (int d = 0; d < 64; ++d) {
    float x0 = xs[(r0 + 0) * 68 + d];
    float x1 = xs[(r0 + 1) * 68 + d];
#pragma unroll
    for (int j = 0; j < 8; ++j) {
      float wqv = wqs[d * 68 + c0 + j];
      float wkv = wks[d * 68 + c0 + j];
      float wvv = wvs[d * 68 + c0 + j];
      aq[0][j] += x0 * wqv; aq[1][j] += x1 * wqv;
      ak[0][j] += x0 * wkv; ak[1][j] += x1 * wkv;
      av[0][j] += x0 * wvv; av[1][j] += x1 * wvv;
    }
  }

  float thv[8], bqv[8], bkv[8];
#pragma unroll
  for (int j = 0; j < 8; ++j) {
    thv[j] = theta[h * DH_ + c0 + j];
    bqv[j] = bq[h * DH_ + c0 + j];
    bkv[j] = bk[h * DH_ + c0 + j];
  }

  // Reuse xs/wqs LDS as bf16 V-transpose staging (all reads of them are done).
  __syncthreads();
  unsigned short* VtH = reinterpret_cast<unsigned short*>(xs);   // [64 d][72]
  unsigned short* VtL = reinterpret_cast<unsigned short*>(wqs);  // [64 d][72]

#pragma unroll
  for (int i = 0; i < 2; ++i) {
    int s = s0 + r0 + i;
    size_t qb = ((size_t)h * S_ + s) * 128;
    ushort8 qch, qcl, qsh, qsl, kch, kcl, ksh, ksl;
#pragma unroll
    for (int j = 0; j < 8; ++j) {
      float q = aq[i][j] + bqv[j];
      float k = ak[i][j] + bkv[j];
      float ang = (float)s * thv[j];
      float cs = cosf(ang), sn = sinf(ang);
      float qc = q * cs, qs = q * sn;
      unsigned short hq1 = f2bf(qc);
      qch[j] = hq1;
      qcl[j] = f2bf(qc - bf2f(hq1));
      unsigned short hq2 = f2bf(qs);
      qsh[j] = hq2;
      qsl[j] = f2bf(qs - bf2f(hq2));
      float kc = k * cs, ksn = k * sn;
      unsigned short h1 = f2bf(kc);
      kch[j] = h1;
      kcl[j] = f2bf(kc - bf2f(h1));
      unsigned short h2 = f2bf(ksn);
      ksh[j] = h2;
      ksl[j] = f2bf(ksn - bf2f(h2));
      float vv = av[i][j];
      unsigned short vh1 = f2bf(vv);
      VtH[(c0 + j) * 72 + (r0 + i)] = vh1;
      VtL[(c0 + j) * 72 + (r0 + i)] = f2bf(vv - bf2f(vh1));
    }
    *reinterpret_cast<ushort8*>(q_h + qb + c0) = qch;
    *reinterpret_cast<ushort8*>(q_h + qb + 64 + c0) = qsh;
    *reinterpret_cast<ushort8*>(q_l + qb + c0) = qcl;
    *reinterpret_cast<ushort8*>(q_l + qb + 64 + c0) = qsl;
    *reinterpret_cast<ushort8*>(k_h + qb + c0) = kch;
    *reinterpret_cast<ushort8*>(k_h + qb + 64 + c0) = ksh;
    *reinterpret_cast<ushort8*>(k_l + qb + c0) = kcl;
    *reinterpret_cast<ushort8*>(k_l + qb + 64 + c0) = ksl;
  }
  __syncthreads();
  // Coalesced transposed store: v_t[h][d][S]
#pragma unroll
  for (int i = 0; i < 2; ++i) {
    int cid = tid + i * 256;
    int d = cid >> 3, t8 = (cid & 7) * 8;
    size_t gb = ((size_t)(h * 64 + d)) * S_ + s0 + t8;
    *reinterpret_cast<ushort8*>(v_th + gb) = *reinterpret_cast<const ushort8*>(&VtH[d * 72 + t8]);
    *reinterpret_cast<ushort8*>(v_tl + gb) = *reinterpret_cast<const ushort8*>(&VtL[d * 72 + t8]);
  }
}

// ---------------------------------------------------------------------------
// Kernel B: retention v6 — r6 structure (KVBLK=64, half-split, backfill,
// 64 KiB LDS, 2 blocks/CU) + 2x2 wave-quadrant QK split (the r7 lesson:
// shrinking the tile duplicates fixed costs; the r6 LDS-roofline analysis
// says cut LDS BYTES instead).
//  - QK: wave (wr,wc)=(w>>1,w&1) computes S[wr*32..+32)x[wc*32..+32) as
//    2 row-tiles x 2 col-tiles of 16x16 MFMAs -> each wave reads only HALF
//    of K. K LDS traffic 128->64 KB/iter (total 272->208 KB, -24%).
//    Each K fragment load feeds 6 MFMAs (both row-tiles).
//  - PV/staging/prefetch/decode/partial: r6 code verbatim. Sc is now
//    cross-wave for PV -> one extra barrier (3/iter), covered by the
//    co-resident block.
//  - Decay exp arguments are the same integers as r6 -> bit-identical.
// ---------------------------------------------------------------------------
#define SCOFF(row, colb)   ((row) * 256 + ((colb) ^ (((row) & 7) << 4)))

__global__ __launch_bounds__(256) void retention_split_kernel(
    const unsigned short* __restrict__ q_h, const unsigned short* __restrict__ q_l,
    const unsigned short* __restrict__ k_h, const unsigned short* __restrict__ k_l,
    const unsigned short* __restrict__ v_th, const unsigned short* __restrict__ v_tl,
    float* __restrict__ partial) {
  __shared__ __align__(16) unsigned short Kh[64 * 128];  // 16 KiB swizzled
  __shared__ __align__(16) unsigned short Kl[64 * 128];  // 16 KiB
  __shared__ __align__(16) unsigned short Vh[64 * 64];   //  8 KiB [d][t]
  __shared__ __align__(16) unsigned short Vl[64 * 64];   //  8 KiB
  __shared__ __align__(16) float Sc[64 * 64];            // 16 KiB swizzled

  char* KhB = (char*)Kh;
  char* KlB = (char*)Kl;
  char* VhB = (char*)Vh;
  char* VlB = (char*)Vl;
  char* ScB = (char*)Sc;

  int tid = threadIdx.x;
  int w = tid >> 6;
  int lane = tid & 63, ln = lane & 15, quad = lane >> 4;
  int wr = w >> 1, wc = w & 1;
  // Decode (bijective on [0,1024)): xcd-affine h, half bit, heavy-first qt.
  int f = blockIdx.x;
  int h = ((f & 7) << 1) | ((f >> 3) & 1);
  int half = (f >> 4) & 1;
  int qt = 31 - (f >> 5);
  int s0 = qt * 64;

  // kt range for this half: [kt0, kt1). m = ceil((qt+1)/2).
  int m = (qt + 2) >> 1;
  int kt0 = half ? m : 0;
  int kt1 = half ? (qt + 1) : m;

  const float lo_c = -6.2383246250395075f, hi_c = -3.4657359027997265f;
  float gam = 1.f - __expf(lo_c + (hi_c - lo_c) * ((float)h * (1.f / 15.f)));
  float logg = __logf(gam);

  // Factored decay: gamma^(s-t) = gamma^(64*(qt-kt)) * gamma^lrow * gamma^-lcol
  // (same integer exp arguments as r6 -> identical fp32 values).
  float rowf[2][4], colf[2];
#pragma unroll
  for (int rt = 0; rt < 2; ++rt)
#pragma unroll
    for (int rr = 0; rr < 4; ++rr)
      rowf[rt][rr] = __expf((float)(wr * 32 + rt * 16 + quad * 4 + rr) * logg);
#pragma unroll
  for (int ns = 0; ns < 2; ++ns)
    colf[ns] = __expf(-(float)(wc * 32 + ns * 16 + ln) * logg);

  const unsigned short* khb = k_h + (size_t)h * S_ * 128;
  const unsigned short* klb = k_l + (size_t)h * S_ * 128;
  const unsigned short* vhb = v_th + (size_t)h * 64 * S_;
  const unsigned short* vlb = v_tl + (size_t)h * 64 * S_;

  // Q fragments (A-layout), 2 row-tiles, precomputed bf16 hi/lo.
  short8 qfh[2][4], qfl[2][4];
#pragma unroll
  for (int rt = 0; rt < 2; ++rt) {
    int sQ = s0 + wr * 32 + rt * 16 + ln;
    const unsigned short* qhp = q_h + ((size_t)h * S_ + sQ) * 128 + quad * 8;
    const unsigned short* qlp = q_l + ((size_t)h * S_ + sQ) * 128 + quad * 8;
#pragma unroll
    for (int c = 0; c < 4; ++c) {
      qfh[rt][c] = *reinterpret_cast<const short8*>(qhp + c * 32);
      qfl[rt][c] = *reinterpret_cast<const short8*>(qlp + c * 32);
    }
  }

  floatx4 accO[4];
#pragma unroll
  for (int i = 0; i < 4; ++i) accO[i] = (floatx4){0.f, 0.f, 0.f, 0.f};

  // Prologue: stage tile kt0 -> LDS; prefetch kt0+1 into regs. (r6 verbatim)
  ushort8 skh[4], skl[4], svh[2], svl[2];
  {
    int t00 = kt0 * 64;
#pragma unroll
    for (int i = 0; i < 4; ++i) {
      int cid = tid + i * 256;
      int r = cid >> 4, c8 = (cid & 15) * 8;
      skh[i] = *reinterpret_cast<const ushort8*>(khb + ((size_t)(t00 + r)) * 128 + c8);
      skl[i] = *reinterpret_cast<const ushort8*>(klb + ((size_t)(t00 + r)) * 128 + c8);
    }
#pragma unroll
    for (int i = 0; i < 2; ++i) {
      int cid = tid + i * 256;
      int d = cid >> 3, t8 = (cid & 7) * 8;
      svh[i] = *reinterpret_cast<const ushort8*>(vhb + (size_t)d * S_ + t00 + t8);
      svl[i] = *reinterpret_cast<const ushort8*>(vlb + (size_t)d * S_ + t00 + t8);
    }
#pragma unroll
    for (int i = 0; i < 4; ++i) {
      int cid = tid + i * 256;
      int r = cid >> 4;
      int ko = r * 256 + (((cid & 15) * 16) ^ ((r & 7) << 4));
      *reinterpret_cast<ushort8*>(KhB + ko) = skh[i];
      *reinterpret_cast<ushort8*>(KlB + ko) = skl[i];
    }
#pragma unroll
    for (int i = 0; i < 2; ++i) {
      int cid = tid + i * 256;
      int d = cid >> 3;
      int vo = d * 128 + (((cid & 7) * 16) ^ ((d & 7) << 4));
      *reinterpret_cast<ushort8*>(VhB + vo) = svh[i];
      *reinterpret_cast<ushort8*>(VlB + vo) = svl[i];
    }
    if (kt0 + 1 < kt1) {
      int t01 = (kt0 + 1) * 64;
#pragma unroll
      for (int i = 0; i < 4; ++i) {
        int cid = tid + i * 256;
        int r = cid >> 4, c8 = (cid & 15) * 8;
        skh[i] = *reinterpret_cast<const ushort8*>(khb + ((size_t)(t01 + r)) * 128 + c8);
        skl[i] = *reinterpret_cast<const ushort8*>(klb + ((size_t)(t01 + r)) * 128 + c8);
      }
#pragma unroll
      for (int i = 0; i < 2; ++i) {
        int cid = tid + i * 256;
        int d = cid >> 3, t8 = (cid & 7) * 8;
        svh[i] = *reinterpret_cast<const ushort8*>(vhb + (size_t)d * S_ + t01 + t8);
        svl[i] = *reinterpret_cast<const ushort8*>(vlb + (size_t)d * S_ + t01 + t8);
      }
    }
  }
  __syncthreads();

  for (int kt = kt0; kt < kt1; ++kt) {
    // QK^T split-MFMA, 2x2 quadrant: wave reads only K rows [wc*32, wc*32+32).
    // Each K fragment feeds both row-tiles (6 MFMAs per load pair).
    floatx4 accS[2][2];
#pragma unroll
    for (int rt = 0; rt < 2; ++rt)
#pragma unroll
      for (int ns = 0; ns < 2; ++ns) accS[rt][ns] = (floatx4){0.f, 0.f, 0.f, 0.f};
#pragma unroll
    for (int ns = 0; ns < 2; ++ns) {
      int krow = wc * 32 + ns * 16 + ln;
#pragma unroll
      for (int ks = 0; ks < 4; ++ks) {
        int off = krow * 256 + ((ks * 64 + quad * 16) ^ ((ln & 7) << 4));
        short8 kh = *reinterpret_cast<const short8*>(KhB + off);
        short8 kl = *reinterpret_cast<const short8*>(KlB + off);
#pragma unroll
        for (int rt = 0; rt < 2; ++rt) {
          accS[rt][ns] = __builtin_amdgcn_mfma_f32_16x16x32_bf16(qfh[rt][ks], kh, accS[rt][ns], 0, 0, 0);
          accS[rt][ns] = __builtin_amdgcn_mfma_f32_16x16x32_bf16(qfl[rt][ks], kh, accS[rt][ns], 0, 0, 0);
          accS[rt][ns] = __builtin_amdgcn_mfma_f32_16x16x32_bf16(qfh[rt][ks], kl, accS[rt][ns], 0, 0, 0);
        }
      }
    }

    // Factored decay (+ causal select only on the diagonal tile) -> Sc.
    float tf = __expf((float)(64 * (qt - kt)) * logg);
    float trf[2][4];
#pragma unroll
    for (int rt = 0; rt < 2; ++rt)
#pragma unroll
      for (int rr = 0; rr < 4; ++rr) trf[rt][rr] = tf * rowf[rt][rr];
    if (kt < qt) {
#pragma unroll
      for (int rt = 0; rt < 2; ++rt)
#pragma unroll
        for (int ns = 0; ns < 2; ++ns) {
          int col = wc * 32 + ns * 16 + ln;
#pragma unroll
          for (int rr = 0; rr < 4; ++rr) {
            int row = wr * 32 + rt * 16 + quad * 4 + rr;
            *reinterpret_cast<float*>(ScB + SCOFF(row, col * 4)) =
                accS[rt][ns][rr] * trf[rt][rr] * colf[ns];
          }
        }
    } else {
#pragma unroll
      for (int rt = 0; rt < 2; ++rt)
#pragma unroll
        for (int ns = 0; ns < 2; ++ns) {
          int col = wc * 32 + ns * 16 + ln;
#pragma unroll
          for (int rr = 0; rr < 4; ++rr) {
            int row = wr * 32 + rt * 16 + quad * 4 + rr;
            float v = accS[rt][ns][rr] * trf[rt][rr] * colf[ns];
            *reinterpret_cast<float*>(ScB + SCOFF(row, col * 4)) =
                (row >= col) ? v : 0.f;
          }
        }
    }
    __syncthreads();  // B1: Sc quadrants visible to all waves (K reads done)

    // PV split-MFMA (r6 verbatim): wave w -> O rows w*16..+16, all 64 d.
#pragma unroll
    for (int ks = 0; ks < 2; ++ks) {
      int prw = w * 16 + ln;
      int cb = ks * 128 + quad * 32;
      float4v p0 = *reinterpret_cast<const float4v*>(ScB + SCOFF(prw, cb));
      float4v p1 = *reinterpret_cast<const float4v*>(ScB + SCOFF(prw, cb + 16));
      short8 ph, pl;
#pragma unroll
      for (int j = 0; j < 4; ++j) {
        unsigned short hh = f2bf(p0[j]);
        ph[j] = (short)hh;
        pl[j] = (short)f2bf(p0[j] - bf2f(hh));
        unsigned short hh2 = f2bf(p1[j]);
        ph[4 + j] = (short)hh2;
        pl[4 + j] = (short)f2bf(p1[j] - bf2f(hh2));
      }
#pragma unroll
      for (int ds = 0; ds < 4; ++ds) {
        int d = ds * 16 + ln;
        int voff = d * 128 + ((ks * 64 + quad * 16) ^ ((ln & 7) << 4));
        short8 vh = *reinterpret_cast<const short8*>(VhB + voff);
        short8 vl = *reinterpret_cast<const short8*>(VlB + voff);
        accO[ds] = __builtin_amdgcn_mfma_f32_16x16x32_bf16(ph, vh, accO[ds], 0, 0, 0);
        accO[ds] = __builtin_amdgcn_mfma_f32_16x16x32_bf16(pl, vh, accO[ds], 0, 0, 0);
        accO[ds] = __builtin_amdgcn_mfma_f32_16x16x32_bf16(ph, vl, accO[ds], 0, 0, 0);
      }
    }

    __syncthreads();  // B2: all waves done reading V/Sc of tile kt
    if (kt + 1 < kt1) {
      // Write prefetched tile kt+1 (vmcnt drains; co-resident block covers).
#pragma unroll
      for (int i = 0; i < 4; ++i) {
        int cid = tid + i * 256;
        int r = cid >> 4;
        int ko = r * 256 + (((cid & 15) * 16) ^ ((r & 7) << 4));
        *reinterpret_cast<ushort8*>(KhB + ko) = skh[i];
        *reinterpret_cast<ushort8*>(KlB + ko) = skl[i];
      }
#pragma unroll
      for (int i = 0; i < 2; ++i) {
        int cid = tid + i * 256;
        int d = cid >> 3;
        int vo = d * 128 + (((cid & 7) * 16) ^ ((d & 7) << 4));
        *reinterpret_cast<ushort8*>(VhB + vo) = svh[i];
        *reinterpret_cast<ushort8*>(VlB + vo) = svl[i];
      }
      // Issue prefetch for tile kt+2 (full compute phase of latency cover).
      if (kt + 2 < kt1) {
        int t0n = (kt + 2) * 64;
#pragma unroll
        for (int i = 0; i < 4; ++i) {
          int cid = tid + i * 256;
          int r = cid >> 4, c8 = (cid & 15) * 8;
          skh[i] = *reinterpret_cast<const ushort8*>(khb + ((size_t)(t0n + r)) * 128 + c8);
          skl[i] = *reinterpret_cast<const ushort8*>(klb + ((size_t)(t0n + r)) * 128 + c8);
        }
#pragma unroll
        for (int i = 0; i < 2; ++i) {
          int cid = tid + i * 256;
          int d = cid >> 3, t8 = (cid & 7) * 8;
          svh[i] = *reinterpret_cast<const ushort8*>(vhb + (size_t)d * S_ + t0n + t8);
          svl[i] = *reinterpret_cast<const ushort8*>(vlb + (size_t)d * S_ + t0n + t8);
        }
      }
      __syncthreads();  // B3: tile kt+1 visible
    }
  }

  // Epilogue: store raw fp32 partial accO (16 KB/block). (r6 verbatim)
  float* pout = partial + ((size_t)(((h * 32 + qt) << 1) + half)) * 4096;
#pragma unroll
  for (int ds = 0; ds < 4; ++ds) {
#pragma unroll
    for (int rr = 0; rr < 4; ++rr) {
      pout[(w * 16 + quad * 4 + rr) * 64 + ds * 16 + ln] = accO[ds][rr];
    }
  }
}

// ---------------------------------------------------------------------------
// Kernel B2: combine halves + GroupNorm (r6 verbatim, proven).
// ---------------------------------------------------------------------------
__global__ __launch_bounds__(256) void combine_gn_kernel(
    const float* __restrict__ partial, const float* __restrict__ gn_w,
    const float* __restrict__ gn_b, float* __restrict__ retn, int b) {
  __shared__ float gnred[64][8];
  int tid = threadIdx.x;
  int qi = blockIdx.x;            // qi = h*32 + qt
  int h = qi >> 5, qt = qi & 31;
  const float* p0 = partial + (size_t)qi * 8192;
  const float* p1 = p0 + 4096;

  int r2 = tid >> 2;
  int sub = tid & 3;
  float a16[16];
#pragma unroll
  for (int c = 0; c < 4; ++c) {
    int o = r2 * 64 + sub * 16 + c * 4;
    float4v va = *reinterpret_cast<const float4v*>(p0 + o);
    float4v vb = *reinterpret_cast<const float4v*>(p1 + o);
#pragma unroll
    for (int j = 0; j < 4; ++j) a16[c * 4 + j] = va[j] + vb[j];
  }

  float psum = 0.f, psq = 0.f;
#pragma unroll
  for (int i = 0; i < 16; ++i) { psum += a16[i]; psq += a16[i] * a16[i]; }
  gnred[r2][sub] = psum;
  gnred[r2][4 + sub] = psq;
  float sum = gnred[r2][0] + gnred[r2][1] + gnred[r2][2] + gnred[r2][3];
  float sq = gnred[r2][4] + gnred[r2][5] + gnred[r2][6] + gnred[r2][7];
  float mean = sum * (1.f / 64.f);
  float var = sq * (1.f / 64.f) - mean * mean;
  float rstd = rsqrtf(var + 1e-5f);

  size_t obase = ((size_t)(b * S_ + qt * 64 + r2)) * HID_ + h * DH_ + sub * 16;
#pragma unroll
  for (int i = 0; i < 16; ++i) {
    float gw = gn_w[h * DH_ + sub * 16 + i];
    float gb = gn_b[h * DH_ + sub * 16 + i];
    retn[obase + i] = (a16[i] - mean) * rstd * gw + gb;
  }
}

// ---------------------------------------------------------------------------
// GEMM 1 (gate): BN=64, 2 blocks/CU. (r7, passing)
// ---------------------------------------------------------------------------
__global__ __launch_bounds__(256) void gemm_gate_kernel(
    const unsigned short* __restrict__ A, const unsigned short* __restrict__ Bt,
    const float* __restrict__ retn, unsigned short* __restrict__ pre_hi,
    unsigned short* __restrict__ pre_lo) {
  const int K = HID_;
  __shared__ __align__(16) unsigned short Al[128 * 56];
  __shared__ __align__(16) unsigned short Bl[64 * 56];

  int tid = threadIdx.x;
  int lane = tid & 63, ln = lane & 15, quad = lane >> 4;
  int w = tid >> 6, wm = w >> 1, wn = w & 1;
  int m0 = blockIdx.y * 128, n0 = blockIdx.x * 64;

  floatx4 acc[4][2];
#pragma unroll
  for (int i = 0; i < 4; ++i)
#pragma unroll
    for (int j = 0; j < 2; ++j) acc[i][j] = (floatx4){0.f, 0.f, 0.f, 0.f};

  for (int k0 = 0; k0 < K; k0 += 32) {
    __syncthreads();
#pragma unroll
    for (int i = 0; i < 2; ++i) {
      int cid = tid + i * 256;
      int r = cid >> 2, c8 = (cid & 3) * 8;
      *reinterpret_cast<ushort8*>(&Al[r * 56 + c8]) =
          *reinterpret_cast<const ushort8*>(A + (size_t)(m0 + r) * K + k0 + c8);
    }
    {
      int r = tid >> 2, c8 = (tid & 3) * 8;
      *reinterpret_cast<ushort8*>(&Bl[r * 56 + c8]) =
          *reinterpret_cast<const ushort8*>(Bt + (size_t)(n0 + r) * K + k0 + c8);
    }
    __syncthreads();

    short8 af[4], bfr[2];
#pragma unroll
    for (int i = 0; i < 4; ++i)
      af[i] = *reinterpret_cast<const short8*>(&Al[(wm * 64 + i * 16 + ln) * 56 + quad * 8]);
#pragma unroll
    for (int i = 0; i < 2; ++i)
      bfr[i] = *reinterpret_cast<const short8*>(&Bl[(wn * 32 + i * 16 + ln) * 56 + quad * 8]);
#pragma unroll
    for (int mi = 0; mi < 4; ++mi)
#pragma unroll
      for (int ni = 0; ni < 2; ++ni)
        acc[mi][ni] = __builtin_amdgcn_mfma_f32_16x16x32_bf16(af[mi], bfr[ni], acc[mi][ni], 0, 0, 0);
  }

#pragma unroll
  for (int mi = 0; mi < 4; ++mi) {
#pragma unroll
    for (int r = 0; r < 4; ++r) {
      int row = m0 + wm * 64 + mi * 16 + quad * 4 + r;
#pragma unroll
      for (int ni = 0; ni < 2; ++ni) {
        int col = n0 + wn * 32 + ni * 16 + ln;
        float g = acc[mi][ni][r];
        float val = g * (1.f / (1.f + __expf(-g))) + retn[(size_t)row * HID_ + col];
        unsigned short hh = f2bf(val);
        size_t oidx = (size_t)row * HID_ + col;
        pre_hi[oidx] = hh;
        pre_lo[oidx] = f2bf(val - bf2f(hh));
      }
    }
  }
}

// ---------------------------------------------------------------------------
// GEMM 2 (output): BN=64. (r7, passing)
// ---------------------------------------------------------------------------
__global__ __launch_bounds__(256) void gemm_out_kernel(
    const unsigned short* __restrict__ Ah, const unsigned short* __restrict__ Alo,
    const unsigned short* __restrict__ Bth, const unsigned short* __restrict__ Btlo,
    float* __restrict__ out_f) {
  const int K = HID_;
  __shared__ __align__(16) unsigned short AhS[128 * 56];
  __shared__ __align__(16) unsigned short AlS[128 * 56];
  __shared__ __align__(16) unsigned short BhS[64 * 56];
  __shared__ __align__(16) unsigned short BlS[64 * 56];

  int tid = threadIdx.x;
  int lane = tid & 63, ln = lane & 15, quad = lane >> 4;
  int w = tid >> 6, wm = w >> 1, wn = w & 1;
  int m0 = blockIdx.y * 128, n0 = blockIdx.x * 64;

  floatx4 acc[4][2];
#pragma unroll
  for (int i = 0; i < 4; ++i)
#pragma unroll
    for (int j = 0; j < 2; ++j) acc[i][j] = (floatx4){0.f, 0.f, 0.f, 0.f};

  for (int k0 = 0; k0 < K; k0 += 32) {
    __syncthreads();
#pragma unroll
    for (int i = 0; i < 2; ++i) {
      int cid = tid + i * 256;
      int r = cid >> 2, c8 = (cid & 3) * 8;
      size_t ga = (size_t)(m0 + r) * K + k0 + c8;
      *reinterpret_cast<ushort8*>(&AhS[r * 56 + c8]) = *reinterpret_cast<const ushort8*>(Ah + ga);
      *reinterpret_cast<ushort8*>(&AlS[r * 56 + c8]) = *reinterpret_cast<const ushort8*>(Alo + ga);
    }
    {
      int r = tid >> 2, c8 = (tid & 3) * 8;
      size_t gb = (size_t)(n0 + r) * K + k0 + c8;
      *reinterpret_cast<ushort8*>(&BhS[r * 56 + c8]) = *reinterpret_cast<const ushort8*>(Bth + gb);
      *reinterpret_cast<ushort8*>(&BlS[r * 56 + c8]) = *reinterpret_cast<const ushort8*>(Btlo + gb);
    }
    __syncthreads();

    short8 afh[4], afl[4], bfh[2], bfl[2];
#pragma unroll
    for (int i = 0; i < 4; ++i) {
      int ao = (wm * 64 + i * 16 + ln) * 56 + quad * 8;
      afh[i] = *reinterpret_cast<const short8*>(&AhS[ao]);
      afl[i] = *reinterpret_cast<const short8*>(&AlS[ao]);
    }
#pragma unroll
    for (int i = 0; i < 2; ++i) {
      int bo = (wn * 32 + i * 16 + ln) * 56 + quad * 8;
      bfh[i] = *reinterpret_cast<const short8*>(&BhS[bo]);
      bfl[i] = *reinterpret_cast<const short8*>(&BlS[bo]);
    }
#pragma unroll
    for (int mi = 0; mi < 4; ++mi)
#pragma unroll
      for (int ni = 0; ni < 2; ++ni) {
        floatx4 a = acc[mi][ni];
        a = __builtin_amdgcn_mfma_f32_16x16x32_bf16(afh[mi], bfh[ni], a, 0, 0, 0);
        a = __builtin_amdgcn_mfma_f32_16x16x32_bf16(afl[mi], bfh[ni], a, 0, 0, 0);
        a = __builtin_amdgcn_mfma_f32_16x16x32_bf16(afh[mi], bfl[ni], a, 0, 0, 0);
        acc[mi][ni] = a;
      }
  }

#pragma unroll
  for (int mi = 0; mi < 4; ++mi) {
#pragma unroll
    for (int r = 0; r < 4; ++r) {
      int row = m0 + wm * 64 + mi * 16 + quad * 4 + r;
#pragma unroll
      for (int ni = 0; ni < 2; ++ni) {
        int col = n0 + wn * 32 + ni * 16 + ln;
        out_f[(size_t)row * HID_ + col] = acc[mi][ni][r];
      }
    }
  }
}

// ---------------------------------------------------------------------------
extern "C" void kernel_launch(void* const* d_in, const int* in_sizes, int n_in,
                              void* d_out, int out_size, void* d_ws,
                              size_t ws_size, hipStream_t stream) {
  (void)in_sizes; (void)n_in; (void)out_size; (void)ws_size;
  const float* x = (const float*)d_in[0];
  const float* wq = (const float*)d_in[1];
  const float* bq = (const float*)d_in[2];
  const float* wk = (const float*)d_in[3];
  const float* bk = (const float*)d_in[4];
  const float* wv = (const float*)d_in[5];
  const float* theta = (const float*)d_in[6];
  const float* gn_w = (const float*)d_in[7];
  const float* gn_b = (const float*)d_in[8];
  const float* w1 = (const float*)d_in[9];
  const float* w2 = (const float*)d_in[10];

  const size_t MB = 1024 * 1024;
  char* ws = (char*)d_ws;
  unsigned short* x_bf   = (unsigned short*)(ws + 0 * MB);    //  8 MiB
  unsigned short* w1t    = (unsigned short*)(ws + 8 * MB);    //  2 MiB
  unsigned short* w2t_hi = (unsigned short*)(ws + 10 * MB);   //  2 MiB
  unsigned short* w2t_lo = (unsigned short*)(ws + 12 * MB);   //  2 MiB
  unsigned short* q_h    = (unsigned short*)(ws + 14 * MB);   //  8 MiB (1 batch)
  unsigned short* q_l    = (unsigned short*)(ws + 22 * MB);   //  8 MiB
  unsigned short* k_h    = (unsigned short*)(ws + 30 * MB);   //  8 MiB
  unsigned short* k_l    = (unsigned short*)(ws + 38 * MB);   //  8 MiB
  unsigned short* v_th   = (unsigned short*)(ws + 46 * MB);   //  4 MiB
  unsigned short* v_tl   = (unsigned short*)(ws + 50 * MB);   //  4 MiB
  float*          retn   = (float*)(ws + 54 * MB);            // 16 MiB (both batches)
  float*          partial= (float*)(ws + 70 * MB);            // 16 MiB (per batch, reused)
  unsigned short* pre_hi = (unsigned short*)(ws + 14 * MB);   //  8 MiB (alias q_h, dead by then)
  unsigned short* pre_lo = (unsigned short*)(ws + 22 * MB);   //  8 MiB (alias q_l)
  float* out = (float*)d_out;

  convert_kernel<<<dim3(24576), 256, 0, stream>>>(x, w1, w2, x_bf, w1t, w2t_hi, w2t_lo);
  for (int b = 0; b < B_; ++b) {
    qkv_kernel<<<dim3(S_ / 64, H_), 256, 0, stream>>>(
        x, wq, bq, wk, bk, wv, theta, q_h, q_l, k_h, k_l, v_th, v_tl, b);
    retention_split_kernel<<<dim3(1024), 256, 0, stream>>>(
        q_h, q_l, k_h, k_l, v_th, v_tl, partial);
    combine_gn_kernel<<<dim3(512), 256, 0, stream>>>(
        partial, gn_w, gn_b, retn, b);
  }
  gemm_gate_kernel<<<dim3(HID_ / 64, (B_ * S_) / 128), 256, 0, stream>>>(
      x_bf, w1t, retn, pre_hi, pre_lo);
  gemm_out_kernel<<<dim3(HID_ / 64, (B_ * S_) / 128), 256, 0, stream>>>(
      pre_hi, pre_lo, w2t_hi, w2t_lo, out);
}

// Round 10
// 330.679 us; speedup vs baseline: 1.1088x; 1.0220x over previous
//
#include <hip/hip_runtime.h>
#include <cstdint>
#include <cstddef>

#define B_ 2
#define S_ 2048
#define HID_ 1024
#define H_ 16
#define DH_ 64

typedef __attribute__((ext_vector_type(8))) short short8;
typedef __attribute__((ext_vector_type(8))) unsigned short ushort8;
typedef __attribute__((ext_vector_type(4))) unsigned short ushort4v;
typedef __attribute__((ext_vector_type(4))) float floatx4;
typedef __attribute__((ext_vector_type(4))) float float4v;

static __device__ __forceinline__ unsigned short f2bf(float f) {
  unsigned int u = __float_as_uint(f);
  u += 0x7fffu + ((u >> 16) & 1u);
  return (unsigned short)(u >> 16);
}
static __device__ __forceinline__ float bf2f(unsigned short h) {
  return __uint_as_float(((unsigned int)h) << 16);
}

// ---------------------------------------------------------------------------
// Kernel 0: conversions. (unchanged, proven)
// ---------------------------------------------------------------------------
__global__ __launch_bounds__(256) void convert_kernel(
    const float* __restrict__ x, const float* __restrict__ w1,
    const float* __restrict__ w2, unsigned short* __restrict__ x_bf,
    unsigned short* __restrict__ w1t, unsigned short* __restrict__ w2t_hi,
    unsigned short* __restrict__ w2t_lo) {
  const int NX = B_ * S_ * HID_;
  const int NW = HID_ * HID_;
  int idx = blockIdx.x * 256 + threadIdx.x;
  if (idx < NX) {
    x_bf[idx] = f2bf(x[idx]);
  } else if (idx < NX + NW) {
    int i = idx - NX;
    int n = i >> 10, k = i & 1023;
    w1t[i] = f2bf(w1[k * HID_ + n]);
  } else if (idx < NX + 2 * NW) {
    int i = idx - NX - NW;
    int n = i >> 10, k = i & 1023;
    float v = w2[k * HID_ + n];
    unsigned short h = f2bf(v);
    w2t_hi[i] = h;
    w2t_lo[i] = f2bf(v - bf2f(h));
  }
}

// ---------------------------------------------------------------------------
// Kernel A: per-head QKV projection + bias + rotary. (unchanged, proven)
// ---------------------------------------------------------------------------
__global__ __launch_bounds__(256) void qkv_kernel(
    const float* __restrict__ x, const float* __restrict__ wq,
    const float* __restrict__ bq, const float* __restrict__ wk,
    const float* __restrict__ bk, const float* __restrict__ wv,
    const float* __restrict__ theta,
    unsigned short* __restrict__ q_h, unsigned short* __restrict__ q_l,
    unsigned short* __restrict__ k_h, unsigned short* __restrict__ k_l,
    unsigned short* __restrict__ v_th, unsigned short* __restrict__ v_tl,
    int b) {
  __shared__ __align__(16) float xs[64 * 68];
  __shared__ __align__(16) float wqs[64 * 68];
  __shared__ __align__(16) float wks[64 * 68];
  __shared__ __align__(16) float wvs[64 * 68];

  int tid = threadIdx.x;
  int st = blockIdx.x, h = blockIdx.y;
  int s0 = st * 64;

#pragma unroll
  for (int i = 0; i < 4; ++i) {
    int cid = tid + i * 256;
    int r = cid >> 4, c4 = (cid & 15) * 4;
    *reinterpret_cast<float4v*>(&xs[r * 68 + c4]) =
        *reinterpret_cast<const float4v*>(x + ((size_t)(b * S_ + s0 + r)) * HID_ + h * DH_ + c4);
  }
#pragma unroll
  for (int i = 0; i < 4; ++i) {
    int cid = tid + i * 256;
    int d = cid >> 4, c4 = (cid & 15) * 4;
    *reinterpret_cast<float4v*>(&wqs[d * 68 + c4]) =
        *reinterpret_cast<const float4v*>(wq + (size_t)(h * DH_ + d) * DH_ + c4);
    *reinterpret_cast<float4v*>(&wks[d * 68 + c4]) =
        *reinterpret_cast<const float4v*>(wk + (size_t)(h * DH_ + d) * DH_ + c4);
    *reinterpret_cast<float4v*>(&wvs[d * 68 + c4]) =
        *reinterpret_cast<const float4v*>(wv + (size_t)(h * DH_ + d) * DH_ + c4);
  }
  __syncthreads();

  int rg = tid >> 3;
  int cg = tid & 7;
  int r0 = rg * 2, c0 = cg * 8;

  float aq[2][8], ak[2][8], av[2][8];
#pragma unroll
  for (int i = 0; i < 2; ++i)
#pragma unroll
    for (int j = 0; j < 8; ++j) { aq[i][j] = 0.f; ak[i][j] = 0.f; av[i][j] = 0.f; }

  for (int d = 0; d < 64; ++d) {
    float x0 = xs[(r0 + 0) * 68 + d];
    float x1 = xs[(r0 + 1) * 68 + d];
#pragma unroll
    for (int j = 0; j < 8; ++j) {
      float wqv = wqs[d * 68 + c0 + j];
      float wkv = wks[d * 68 + c0 + j];
      float wvv = wvs[d * 68 + c0 + j];
      aq[0][j] += x0 * wqv; aq[1][j] += x1 * wqv;
      ak[0][j] += x0 * wkv; ak[1][j] += x1 * wkv;
      av[0][j] += x0 * wvv; av[1][j] += x1 * wvv;
    }
  }

  float thv[8], bqv[8], bkv[8];
#pragma unroll
  for (int j = 0; j < 8; ++j) {
    thv[j] = theta[h * DH_ + c0 + j];
    bqv[j] = bq[h * DH_ + c0 + j];
    bkv[j] = bk[h * DH_ + c0 + j];
  }

  // Reuse xs/wqs LDS as bf16 V-transpose staging (all reads of them are done).
  __syncthreads();
  unsigned short* VtH = reinterpret_cast<unsigned short*>(xs);   // [64 d][72]
  unsigned short* VtL = reinterpret_cast<unsigned short*>(wqs);  // [64 d][72]

#pragma unroll
  for (int i = 0; i < 2; ++i) {
    int s = s0 + r0 + i;
    size_t qb = ((size_t)h * S_ + s) * 128;
    ushort8 qch, qcl, qsh, qsl, kch, kcl, ksh, ksl;
#pragma unroll
    for (int j = 0; j < 8; ++j) {
      float q = aq[i][j] + bqv[j];
      float k = ak[i][j] + bkv[j];
      float ang = (float)s * thv[j];
      float cs = cosf(ang), sn = sinf(ang);
      float qc = q * cs, qs = q * sn;
      unsigned short hq1 = f2bf(qc);
      qch[j] = hq1;
      qcl[j] = f2bf(qc - bf2f(hq1));
      unsigned short hq2 = f2bf(qs);
      qsh[j] = hq2;
      qsl[j] = f2bf(qs - bf2f(hq2));
      float kc = k * cs, ksn = k * sn;
      unsigned short h1 = f2bf(kc);
      kch[j] = h1;
      kcl[j] = f2bf(kc - bf2f(h1));
      unsigned short h2 = f2bf(ksn);
      ksh[j] = h2;
      ksl[j] = f2bf(ksn - bf2f(h2));
      float vv = av[i][j];
      unsigned short vh1 = f2bf(vv);
      VtH[(c0 + j) * 72 + (r0 + i)] = vh1;
      VtL[(c0 + j) * 72 + (r0 + i)] = f2bf(vv - bf2f(vh1));
    }
    *reinterpret_cast<ushort8*>(q_h + qb + c0) = qch;
    *reinterpret_cast<ushort8*>(q_h + qb + 64 + c0) = qsh;
    *reinterpret_cast<ushort8*>(q_l + qb + c0) = qcl;
    *reinterpret_cast<ushort8*>(q_l + qb + 64 + c0) = qsl;
    *reinterpret_cast<ushort8*>(k_h + qb + c0) = kch;
    *reinterpret_cast<ushort8*>(k_h + qb + 64 + c0) = ksh;
    *reinterpret_cast<ushort8*>(k_l + qb + c0) = kcl;
    *reinterpret_cast<ushort8*>(k_l + qb + 64 + c0) = ksl;
  }
  __syncthreads();
  // Coalesced transposed store: v_t[h][d][S]
#pragma unroll
  for (int i = 0; i < 2; ++i) {
    int cid = tid + i * 256;
    int d = cid >> 3, t8 = (cid & 7) * 8;
    size_t gb = ((size_t)(h * 64 + d)) * S_ + s0 + t8;
    *reinterpret_cast<ushort8*>(v_th + gb) = *reinterpret_cast<const ushort8*>(&VtH[d * 72 + t8]);
    *reinterpret_cast<ushort8*>(v_tl + gb) = *reinterpret_cast<const ushort8*>(&VtL[d * 72 + t8]);
  }
}

// ---------------------------------------------------------------------------
// Kernel B: retention v7 — 2-barrier schedule (the r9 lesson: not LDS-BW
// bound; per-iter critical path ~4800cyc vs ~1000 of pipe work -> cut the
// serial phases). V double-buffered (8KB x2 per stream), K single-buffered:
// QK's K reads complete at B1, so the staged K write is safe right after B1
// and overlaps PV; V[next] goes to the alternate buffer. Barriers 3 -> 2,
// exposed staging tail eliminated. LDS 80 KiB -> still 2 blocks/CU.
// QK quadrant split, decay, PV, partials: r9 verbatim (bit-identical math).
// ---------------------------------------------------------------------------
#define SCOFF(row, colb)   ((row) * 256 + ((colb) ^ (((row) & 7) << 4)))

__global__ __launch_bounds__(256) void retention_split_kernel(
    const unsigned short* __restrict__ q_h, const unsigned short* __restrict__ q_l,
    const unsigned short* __restrict__ k_h, const unsigned short* __restrict__ k_l,
    const unsigned short* __restrict__ v_th, const unsigned short* __restrict__ v_tl,
    float* __restrict__ partial) {
  __shared__ __align__(16) unsigned short Kh[64 * 128];     // 16 KiB swizzled
  __shared__ __align__(16) unsigned short Kl[64 * 128];     // 16 KiB
  __shared__ __align__(16) unsigned short Vh[2][64 * 64];   // 16 KiB [d][t] dbuf
  __shared__ __align__(16) unsigned short Vl[2][64 * 64];   // 16 KiB
  __shared__ __align__(16) float Sc[64 * 64];               // 16 KiB swizzled

  char* KhB = (char*)Kh;
  char* KlB = (char*)Kl;
  char* VhB = (char*)Vh;
  char* VlB = (char*)Vl;
  char* ScB = (char*)Sc;

  int tid = threadIdx.x;
  int w = tid >> 6;
  int lane = tid & 63, ln = lane & 15, quad = lane >> 4;
  int wr = w >> 1, wc = w & 1;
  // Decode (bijective on [0,1024)): xcd-affine h, half bit, heavy-first qt.
  int f = blockIdx.x;
  int h = ((f & 7) << 1) | ((f >> 3) & 1);
  int half = (f >> 4) & 1;
  int qt = 31 - (f >> 5);
  int s0 = qt * 64;

  // kt range for this half: [kt0, kt1). m = ceil((qt+1)/2).
  int m = (qt + 2) >> 1;
  int kt0 = half ? m : 0;
  int kt1 = half ? (qt + 1) : m;

  const float lo_c = -6.2383246250395075f, hi_c = -3.4657359027997265f;
  float gam = 1.f - __expf(lo_c + (hi_c - lo_c) * ((float)h * (1.f / 15.f)));
  float logg = __logf(gam);

  // Factored decay (same integer exp arguments as r6/r9 -> identical values).
  float rowf[2][4], colf[2];
#pragma unroll
  for (int rt = 0; rt < 2; ++rt)
#pragma unroll
    for (int rr = 0; rr < 4; ++rr)
      rowf[rt][rr] = __expf((float)(wr * 32 + rt * 16 + quad * 4 + rr) * logg);
#pragma unroll
  for (int ns = 0; ns < 2; ++ns)
    colf[ns] = __expf(-(float)(wc * 32 + ns * 16 + ln) * logg);

  const unsigned short* khb = k_h + (size_t)h * S_ * 128;
  const unsigned short* klb = k_l + (size_t)h * S_ * 128;
  const unsigned short* vhb = v_th + (size_t)h * 64 * S_;
  const unsigned short* vlb = v_tl + (size_t)h * 64 * S_;

  // Q fragments (A-layout), 2 row-tiles, precomputed bf16 hi/lo.
  short8 qfh[2][4], qfl[2][4];
#pragma unroll
  for (int rt = 0; rt < 2; ++rt) {
    int sQ = s0 + wr * 32 + rt * 16 + ln;
    const unsigned short* qhp = q_h + ((size_t)h * S_ + sQ) * 128 + quad * 8;
    const unsigned short* qlp = q_l + ((size_t)h * S_ + sQ) * 128 + quad * 8;
#pragma unroll
    for (int c = 0; c < 4; ++c) {
      qfh[rt][c] = *reinterpret_cast<const short8*>(qhp + c * 32);
      qfl[rt][c] = *reinterpret_cast<const short8*>(qlp + c * 32);
    }
  }

  floatx4 accO[4];
#pragma unroll
  for (int i = 0; i < 4; ++i) accO[i] = (floatx4){0.f, 0.f, 0.f, 0.f};

  // Prologue: stage tile kt0 -> K + V[0]; prefetch kt0+1 into regs.
  ushort8 skh[4], skl[4], svh[2], svl[2];
  {
    int t00 = kt0 * 64;
#pragma unroll
    for (int i = 0; i < 4; ++i) {
      int cid = tid + i * 256;
      int r = cid >> 4, c8 = (cid & 15) * 8;
      skh[i] = *reinterpret_cast<const ushort8*>(khb + ((size_t)(t00 + r)) * 128 + c8);
      skl[i] = *reinterpret_cast<const ushort8*>(klb + ((size_t)(t00 + r)) * 128 + c8);
    }
#pragma unroll
    for (int i = 0; i < 2; ++i) {
      int cid = tid + i * 256;
      int d = cid >> 3, t8 = (cid & 7) * 8;
      svh[i] = *reinterpret_cast<const ushort8*>(vhb + (size_t)d * S_ + t00 + t8);
      svl[i] = *reinterpret_cast<const ushort8*>(vlb + (size_t)d * S_ + t00 + t8);
    }
#pragma unroll
    for (int i = 0; i < 4; ++i) {
      int cid = tid + i * 256;
      int r = cid >> 4;
      int ko = r * 256 + (((cid & 15) * 16) ^ ((r & 7) << 4));
      *reinterpret_cast<ushort8*>(KhB + ko) = skh[i];
      *reinterpret_cast<ushort8*>(KlB + ko) = skl[i];
    }
#pragma unroll
    for (int i = 0; i < 2; ++i) {
      int cid = tid + i * 256;
      int d = cid >> 3;
      int vo = d * 128 + (((cid & 7) * 16) ^ ((d & 7) << 4));  // buffer 0
      *reinterpret_cast<ushort8*>(VhB + vo) = svh[i];
      *reinterpret_cast<ushort8*>(VlB + vo) = svl[i];
    }
    if (kt0 + 1 < kt1) {
      int t01 = (kt0 + 1) * 64;
#pragma unroll
      for (int i = 0; i < 4; ++i) {
        int cid = tid + i * 256;
        int r = cid >> 4, c8 = (cid & 15) * 8;
        skh[i] = *reinterpret_cast<const ushort8*>(khb + ((size_t)(t01 + r)) * 128 + c8);
        skl[i] = *reinterpret_cast<const ushort8*>(klb + ((size_t)(t01 + r)) * 128 + c8);
      }
#pragma unroll
      for (int i = 0; i < 2; ++i) {
        int cid = tid + i * 256;
        int d = cid >> 3, t8 = (cid & 7) * 8;
        svh[i] = *reinterpret_cast<const ushort8*>(vhb + (size_t)d * S_ + t01 + t8);
        svl[i] = *reinterpret_cast<const ushort8*>(vlb + (size_t)d * S_ + t01 + t8);
      }
    }
  }
  __syncthreads();

  for (int kt = kt0; kt < kt1; ++kt) {
    int vb = (kt - kt0) & 1;
    // QK^T split-MFMA, 2x2 quadrant (r9 verbatim).
    floatx4 accS[2][2];
#pragma unroll
    for (int rt = 0; rt < 2; ++rt)
#pragma unroll
      for (int ns = 0; ns < 2; ++ns) accS[rt][ns] = (floatx4){0.f, 0.f, 0.f, 0.f};
#pragma unroll
    for (int ns = 0; ns < 2; ++ns) {
      int krow = wc * 32 + ns * 16 + ln;
#pragma unroll
      for (int ks = 0; ks < 4; ++ks) {
        int off = krow * 256 + ((ks * 64 + quad * 16) ^ ((ln & 7) << 4));
        short8 kh = *reinterpret_cast<const short8*>(KhB + off);
        short8 kl = *reinterpret_cast<const short8*>(KlB + off);
#pragma unroll
        for (int rt = 0; rt < 2; ++rt) {
          accS[rt][ns] = __builtin_amdgcn_mfma_f32_16x16x32_bf16(qfh[rt][ks], kh, accS[rt][ns], 0, 0, 0);
          accS[rt][ns] = __builtin_amdgcn_mfma_f32_16x16x32_bf16(qfl[rt][ks], kh, accS[rt][ns], 0, 0, 0);
          accS[rt][ns] = __builtin_amdgcn_mfma_f32_16x16x32_bf16(qfh[rt][ks], kl, accS[rt][ns], 0, 0, 0);
        }
      }
    }

    // Factored decay (+ causal select only on the diagonal tile) -> Sc.
    float tf = __expf((float)(64 * (qt - kt)) * logg);
    float trf[2][4];
#pragma unroll
    for (int rt = 0; rt < 2; ++rt)
#pragma unroll
      for (int rr = 0; rr < 4; ++rr) trf[rt][rr] = tf * rowf[rt][rr];
    if (kt < qt) {
#pragma unroll
      for (int rt = 0; rt < 2; ++rt)
#pragma unroll
        for (int ns = 0; ns < 2; ++ns) {
          int col = wc * 32 + ns * 16 + ln;
#pragma unroll
          for (int rr = 0; rr < 4; ++rr) {
            int row = wr * 32 + rt * 16 + quad * 4 + rr;
            *reinterpret_cast<float*>(ScB + SCOFF(row, col * 4)) =
                accS[rt][ns][rr] * trf[rt][rr] * colf[ns];
          }
        }
    } else {
#pragma unroll
      for (int rt = 0; rt < 2; ++rt)
#pragma unroll
        for (int ns = 0; ns < 2; ++ns) {
          int col = wc * 32 + ns * 16 + ln;
#pragma unroll
          for (int rr = 0; rr < 4; ++rr) {
            int row = wr * 32 + rt * 16 + quad * 4 + rr;
            float v = accS[rt][ns][rr] * trf[rt][rr] * colf[ns];
            *reinterpret_cast<float*>(ScB + SCOFF(row, col * 4)) =
                (row >= col) ? v : 0.f;
          }
        }
    }
    __syncthreads();  // B1: Sc visible; all K reads AND V[vb^1] reads done

    // Staged writes overlap PV: K (single buffer, reads finished at B1) and
    // V[next] into the alternate buffer. Then issue kt+2 prefetch.
    if (kt + 1 < kt1) {
#pragma unroll
      for (int i = 0; i < 4; ++i) {
        int cid = tid + i * 256;
        int r = cid >> 4;
        int ko = r * 256 + (((cid & 15) * 16) ^ ((r & 7) << 4));
        *reinterpret_cast<ushort8*>(KhB + ko) = skh[i];
        *reinterpret_cast<ushort8*>(KlB + ko) = skl[i];
      }
#pragma unroll
      for (int i = 0; i < 2; ++i) {
        int cid = tid + i * 256;
        int d = cid >> 3;
        int vo = (vb ^ 1) * 8192 + d * 128 + (((cid & 7) * 16) ^ ((d & 7) << 4));
        *reinterpret_cast<ushort8*>(VhB + vo) = svh[i];
        *reinterpret_cast<ushort8*>(VlB + vo) = svl[i];
      }
      if (kt + 2 < kt1) {
        int t0n = (kt + 2) * 64;
#pragma unroll
        for (int i = 0; i < 4; ++i) {
          int cid = tid + i * 256;
          int r = cid >> 4, c8 = (cid & 15) * 8;
          skh[i] = *reinterpret_cast<const ushort8*>(khb + ((size_t)(t0n + r)) * 128 + c8);
          skl[i] = *reinterpret_cast<const ushort8*>(klb + ((size_t)(t0n + r)) * 128 + c8);
        }
#pragma unroll
        for (int i = 0; i < 2; ++i) {
          int cid = tid + i * 256;
          int d = cid >> 3, t8 = (cid & 7) * 8;
          svh[i] = *reinterpret_cast<const ushort8*>(vhb + (size_t)d * S_ + t0n + t8);
          svl[i] = *reinterpret_cast<const ushort8*>(vlb + (size_t)d * S_ + t0n + t8);
        }
      }
    }

    // PV split-MFMA: reads Sc + V[vb] (disjoint from the writes above).
#pragma unroll
    for (int ks = 0; ks < 2; ++ks) {
      int prw = w * 16 + ln;
      int cb = ks * 128 + quad * 32;
      float4v p0 = *reinterpret_cast<const float4v*>(ScB + SCOFF(prw, cb));
      float4v p1 = *reinterpret_cast<const float4v*>(ScB + SCOFF(prw, cb + 16));
      short8 ph, pl;
#pragma unroll
      for (int j = 0; j < 4; ++j) {
        unsigned short hh = f2bf(p0[j]);
        ph[j] = (short)hh;
        pl[j] = (short)f2bf(p0[j] - bf2f(hh));
        unsigned short hh2 = f2bf(p1[j]);
        ph[4 + j] = (short)hh2;
        pl[4 + j] = (short)f2bf(p1[j] - bf2f(hh2));
      }
#pragma unroll
      for (int ds = 0; ds < 4; ++ds) {
        int d = ds * 16 + ln;
        int voff = vb * 8192 + d * 128 + ((ks * 64 + quad * 16) ^ ((ln & 7) << 4));
        short8 vh = *reinterpret_cast<const short8*>(VhB + voff);
        short8 vl = *reinterpret_cast<const short8*>(VlB + voff);
        accO[ds] = __builtin_amdgcn_mfma_f32_16x16x32_bf16(ph, vh, accO[ds], 0, 0, 0);
        accO[ds] = __builtin_amdgcn_mfma_f32_16x16x32_bf16(pl, vh, accO[ds], 0, 0, 0);
        accO[ds] = __builtin_amdgcn_mfma_f32_16x16x32_bf16(ph, vl, accO[ds], 0, 0, 0);
      }
    }

    __syncthreads();  // B2: PV reads done; staged K/V writes visible
  }

  // Epilogue: store raw fp32 partial accO (16 KB/block). (r9 verbatim)
  float* pout = partial + ((size_t)(((h * 32 + qt) << 1) + half)) * 4096;
#pragma unroll
  for (int ds = 0; ds < 4; ++ds) {
#pragma unroll
    for (int rr = 0; rr < 4; ++rr) {
      pout[(w * 16 + quad * 4 + rr) * 64 + ds * 16 + ln] = accO[ds][rr];
    }
  }
}

// ---------------------------------------------------------------------------
// Kernel B2: combine halves + GroupNorm (r6 verbatim, proven).
// ---------------------------------------------------------------------------
__global__ __launch_bounds__(256) void combine_gn_kernel(
    const float* __restrict__ partial, const float* __restrict__ gn_w,
    const float* __restrict__ gn_b, float* __restrict__ retn, int b) {
  __shared__ float gnred[64][8];
  int tid = threadIdx.x;
  int qi = blockIdx.x;            // qi = h*32 + qt
  int h = qi >> 5, qt = qi & 31;
  const float* p0 = partial + (size_t)qi * 8192;
  const float* p1 = p0 + 4096;

  int r2 = tid >> 2;
  int sub = tid & 3;
  float a16[16];
#pragma unroll
  for (int c = 0; c < 4; ++c) {
    int o = r2 * 64 + sub * 16 + c * 4;
    float4v va = *reinterpret_cast<const float4v*>(p0 + o);
    float4v vb = *reinterpret_cast<const float4v*>(p1 + o);
#pragma unroll
    for (int j = 0; j < 4; ++j) a16[c * 4 + j] = va[j] + vb[j];
  }

  float psum = 0.f, psq = 0.f;
#pragma unroll
  for (int i = 0; i < 16; ++i) { psum += a16[i]; psq += a16[i] * a16[i]; }
  gnred[r2][sub] = psum;
  gnred[r2][4 + sub] = psq;
  float sum = gnred[r2][0] + gnred[r2][1] + gnred[r2][2] + gnred[r2][3];
  float sq = gnred[r2][4] + gnred[r2][5] + gnred[r2][6] + gnred[r2][7];
  float mean = sum * (1.f / 64.f);
  float var = sq * (1.f / 64.f) - mean * mean;
  float rstd = rsqrtf(var + 1e-5f);

  size_t obase = ((size_t)(b * S_ + qt * 64 + r2)) * HID_ + h * DH_ + sub * 16;
#pragma unroll
  for (int i = 0; i < 16; ++i) {
    float gw = gn_w[h * DH_ + sub * 16 + i];
    float gb = gn_b[h * DH_ + sub * 16 + i];
    retn[obase + i] = (a16[i] - mean) * rstd * gw + gb;
  }
}

// ---------------------------------------------------------------------------
// GEMM 1 (gate): BN=64 + register prefetch (global latency hides under the
// compute phase; previously the k-loop exposed it every iteration).
// ---------------------------------------------------------------------------
__global__ __launch_bounds__(256) void gemm_gate_kernel(
    const unsigned short* __restrict__ A, const unsigned short* __restrict__ Bt,
    const float* __restrict__ retn, unsigned short* __restrict__ pre_hi,
    unsigned short* __restrict__ pre_lo) {
  const int K = HID_;
  __shared__ __align__(16) unsigned short Al[128 * 56];
  __shared__ __align__(16) unsigned short Bl[64 * 56];

  int tid = threadIdx.x;
  int lane = tid & 63, ln = lane & 15, quad = lane >> 4;
  int w = tid >> 6, wm = w >> 1, wn = w & 1;
  int m0 = blockIdx.y * 128, n0 = blockIdx.x * 64;

  floatx4 acc[4][2];
#pragma unroll
  for (int i = 0; i < 4; ++i)
#pragma unroll
    for (int j = 0; j < 2; ++j) acc[i][j] = (floatx4){0.f, 0.f, 0.f, 0.f};

  int ra_r[2], ra_c[2], rb_r, rb_c;
#pragma unroll
  for (int i = 0; i < 2; ++i) {
    int cid = tid + i * 256;
    ra_r[i] = cid >> 2; ra_c[i] = (cid & 3) * 8;
  }
  rb_r = tid >> 2; rb_c = (tid & 3) * 8;

  // Prefetch tile 0.
  ushort8 ra[2], rb;
#pragma unroll
  for (int i = 0; i < 2; ++i)
    ra[i] = *reinterpret_cast<const ushort8*>(A + (size_t)(m0 + ra_r[i]) * K + ra_c[i]);
  rb = *reinterpret_cast<const ushort8*>(Bt + (size_t)(n0 + rb_r) * K + rb_c);

  for (int k0 = 0; k0 < K; k0 += 32) {
    // Write current tile (prev compute's reads ended at loop-bottom barrier).
#pragma unroll
    for (int i = 0; i < 2; ++i)
      *reinterpret_cast<ushort8*>(&Al[ra_r[i] * 56 + ra_c[i]]) = ra[i];
    *reinterpret_cast<ushort8*>(&Bl[rb_r * 56 + rb_c]) = rb;
    // Issue next-tile loads (latency covered by compute + barrier).
    if (k0 + 32 < K) {
#pragma unroll
      for (int i = 0; i < 2; ++i)
        ra[i] = *reinterpret_cast<const ushort8*>(A + (size_t)(m0 + ra_r[i]) * K + k0 + 32 + ra_c[i]);
      rb = *reinterpret_cast<const ushort8*>(Bt + (size_t)(n0 + rb_r) * K + k0 + 32 + rb_c);
    }
    __syncthreads();

    short8 af[4], bfr[2];
#pragma unroll
    for (int i = 0; i < 4; ++i)
      af[i] = *reinterpret_cast<const short8*>(&Al[(wm * 64 + i * 16 + ln) * 56 + quad * 8]);
#pragma unroll
    for (int i = 0; i < 2; ++i)
      bfr[i] = *reinterpret_cast<const short8*>(&Bl[(wn * 32 + i * 16 + ln) * 56 + quad * 8]);
#pragma unroll
    for (int mi = 0; mi < 4; ++mi)
#pragma unroll
      for (int ni = 0; ni < 2; ++ni)
        acc[mi][ni] = __builtin_amdgcn_mfma_f32_16x16x32_bf16(af[mi], bfr[ni], acc[mi][ni], 0, 0, 0);
    __syncthreads();
  }

#pragma unroll
  for (int mi = 0; mi < 4; ++mi) {
#pragma unroll
    for (int r = 0; r < 4; ++r) {
      int row = m0 + wm * 64 + mi * 16 + quad * 4 + r;
#pragma unroll
      for (int ni = 0; ni < 2; ++ni) {
        int col = n0 + wn * 32 + ni * 16 + ln;
        float g = acc[mi][ni][r];
        float val = g * (1.f / (1.f + __expf(-g))) + retn[(size_t)row * HID_ + col];
        unsigned short hh = f2bf(val);
        size_t oidx = (size_t)row * HID_ + col;
        pre_hi[oidx] = hh;
        pre_lo[oidx] = f2bf(val - bf2f(hh));
      }
    }
  }
}

// ---------------------------------------------------------------------------
// GEMM 2 (output): BN=64 + register prefetch (4 streams).
// ---------------------------------------------------------------------------
__global__ __launch_bounds__(256) void gemm_out_kernel(
    const unsigned short* __restrict__ Ah, const unsigned short* __restrict__ Alo,
    const unsigned short* __restrict__ Bth, const unsigned short* __restrict__ Btlo,
    float* __restrict__ out_f) {
  const int K = HID_;
  __shared__ __align__(16) unsigned short AhS[128 * 56];
  __shared__ __align__(16) unsigned short AlS[128 * 56];
  __shared__ __align__(16) unsigned short BhS[64 * 56];
  __shared__ __align__(16) unsigned short BlS[64 * 56];

  int tid = threadIdx.x;
  int lane = tid & 63, ln = lane & 15, quad = lane >> 4;
  int w = tid >> 6, wm = w >> 1, wn = w & 1;
  int m0 = blockIdx.y * 128, n0 = blockIdx.x * 64;

  floatx4 acc[4][2];
#pragma unroll
  for (int i = 0; i < 4; ++i)
#pragma unroll
    for (int j = 0; j < 2; ++j) acc[i][j] = (floatx4){0.f, 0.f, 0.f, 0.f};

  int ra_r[2], ra_c[2], rb_r, rb_c;
#pragma unroll
  for (int i = 0; i < 2; ++i) {
    int cid = tid + i * 256;
    ra_r[i] = cid >> 2; ra_c[i] = (cid & 3) * 8;
  }
  rb_r = tid >> 2; rb_c = (tid & 3) * 8;

  // Prefetch tile 0.
  ushort8 rah[2], ral[2], rbh, rbl;
#pragma unroll
  for (int i = 0; i < 2; ++i) {
    size_t ga = (size_t)(m0 + ra_r[i]) * K + ra_c[i];
    rah[i] = *reinterpret_cast<const ushort8*>(Ah + ga);
    ral[i] = *reinterpret_cast<const ushort8*>(Alo + ga);
  }
  {
    size_t gb = (size_t)(n0 + rb_r) * K + rb_c;
    rbh = *reinterpret_cast<const ushort8*>(Bth + gb);
    rbl = *reinterpret_cast<const ushort8*>(Btlo + gb);
  }

  for (int k0 = 0; k0 < K; k0 += 32) {
#pragma unroll
    for (int i = 0; i < 2; ++i) {
      *reinterpret_cast<ushort8*>(&AhS[ra_r[i] * 56 + ra_c[i]]) = rah[i];
      *reinterpret_cast<ushort8*>(&AlS[ra_r[i] * 56 + ra_c[i]]) = ral[i];
    }
    *reinterpret_cast<ushort8*>(&BhS[rb_r * 56 + rb_c]) = rbh;
    *reinterpret_cast<ushort8*>(&BlS[rb_r * 56 + rb_c]) = rbl;
    if (k0 + 32 < K) {
#pragma unroll
      for (int i = 0; i < 2; ++i) {
        size_t ga = (size_t)(m0 + ra_r[i]) * K + k0 + 32 + ra_c[i];
        rah[i] = *reinterpret_cast<const ushort8*>(Ah + ga);
        ral[i] = *reinterpret_cast<const ushort8*>(Alo + ga);
      }
      size_t gb = (size_t)(n0 + rb_r) * K + k0 + 32 + rb_c;
      rbh = *reinterpret_cast<const ushort8*>(Bth + gb);
      rbl = *reinterpret_cast<const ushort8*>(Btlo + gb);
    }
    __syncthreads();

    short8 afh[4], afl[4], bfh[2], bfl[2];
#pragma unroll
    for (int i = 0; i < 4; ++i) {
      int ao = (wm * 64 + i * 16 + ln) * 56 + quad * 8;
      afh[i] = *reinterpret_cast<const short8*>(&AhS[ao]);
      afl[i] = *reinterpret_cast<const short8*>(&AlS[ao]);
    }
#pragma unroll
    for (int i = 0; i < 2; ++i) {
      int bo = (wn * 32 + i * 16 + ln) * 56 + quad * 8;
      bfh[i] = *reinterpret_cast<const short8*>(&BhS[bo]);
      bfl[i] = *reinterpret_cast<const short8*>(&BlS[bo]);
    }
#pragma unroll
    for (int mi = 0; mi < 4; ++mi)
#pragma unroll
      for (int ni = 0; ni < 2; ++ni) {
        floatx4 a = acc[mi][ni];
        a = __builtin_amdgcn_mfma_f32_16x16x32_bf16(afh[mi], bfh[ni], a, 0, 0, 0);
        a = __builtin_amdgcn_mfma_f32_16x16x32_bf16(afl[mi], bfh[ni], a, 0, 0, 0);
        a = __builtin_amdgcn_mfma_f32_16x16x32_bf16(afh[mi], bfl[ni], a, 0, 0, 0);
        acc[mi][ni] = a;
      }
    __syncthreads();
  }

#pragma unroll
  for (int mi = 0; mi < 4; ++mi) {
#pragma unroll
    for (int r = 0; r < 4; ++r) {
      int row = m0 + wm * 64 + mi * 16 + quad * 4 + r;
#pragma unroll
      for (int ni = 0; ni < 2; ++ni) {
        int col = n0 + wn * 32 + ni * 16 + ln;
        out_f[(size_t)row * HID_ + col] = acc[mi][ni][r];
      }
    }
  }
}

// ---------------------------------------------------------------------------
extern "C" void kernel_launch(void* const* d_in, const int* in_sizes, int n_in,
                              void* d_out, int out_size, void* d_ws,
                              size_t ws_size, hipStream_t stream) {
  (void)in_sizes; (void)n_in; (void)out_size; (void)ws_size;
  const float* x = (const float*)d_in[0];
  const float* wq = (const float*)d_in[1];
  const float* bq = (const float*)d_in[2];
  const float* wk = (const float*)d_in[3];
  const float* bk = (const float*)d_in[4];
  const float* wv = (const float*)d_in[5];
  const float* theta = (const float*)d_in[6];
  const float* gn_w = (const float*)d_in[7];
  const float* gn_b = (const float*)d_in[8];
  const float* w1 = (const float*)d_in[9];
  const float* w2 = (const float*)d_in[10];

  const size_t MB = 1024 * 1024;
  char* ws = (char*)d_ws;
  unsigned short* x_bf   = (unsigned short*)(ws + 0 * MB);    //  8 MiB
  unsigned short* w1t    = (unsigned short*)(ws + 8 * MB);    //  2 MiB
  unsigned short* w2t_hi = (unsigned short*)(ws + 10 * MB);   //  2 MiB
  unsigned short* w2t_lo = (unsigned short*)(ws + 12 * MB);   //  2 MiB
  unsigned short* q_h    = (unsigned short*)(ws + 14 * MB);   //  8 MiB (1 batch)
  unsigned short* q_l    = (unsigned short*)(ws + 22 * MB);   //  8 MiB
  unsigned short* k_h    = (unsigned short*)(ws + 30 * MB);   //  8 MiB
  unsigned short* k_l    = (unsigned short*)(ws + 38 * MB);   //  8 MiB
  unsigned short* v_th   = (unsigned short*)(ws + 46 * MB);   //  4 MiB
  unsigned short* v_tl   = (unsigned short*)(ws + 50 * MB);   //  4 MiB
  float*          retn   = (float*)(ws + 54 * MB);            // 16 MiB (both batches)
  float*          partial= (float*)(ws + 70 * MB);            // 16 MiB (per batch, reused)
  unsigned short* pre_hi = (unsigned short*)(ws + 14 * MB);   //  8 MiB (alias q_h, dead by then)
  unsigned short* pre_lo = (unsigned short*)(ws + 22 * MB);   //  8 MiB (alias q_l)
  float* out = (float*)d_out;

  convert_kernel<<<dim3(24576), 256, 0, stream>>>(x, w1, w2, x_bf, w1t, w2t_hi, w2t_lo);
  for (int b = 0; b < B_; ++b) {
    qkv_kernel<<<dim3(S_ / 64, H_), 256, 0, stream>>>(
        x, wq, bq, wk, bk, wv, theta, q_h, q_l, k_h, k_l, v_th, v_tl, b);
    retention_split_kernel<<<dim3(1024), 256, 0, stream>>>(
        q_h, q_l, k_h, k_l, v_th, v_tl, partial);
    combine_gn_kernel<<<dim3(512), 256, 0, stream>>>(
        partial, gn_w, gn_b, retn, b);
  }
  gemm_gate_kernel<<<dim3(HID_ / 64, (B_ * S_) / 128), 256, 0, stream>>>(
      x_bf, w1t, retn, pre_hi, pre_lo);
  gemm_out_kernel<<<dim3(HID_ / 64, (B_ * S_) / 128), 256, 0, stream>>>(
      pre_hi, pre_lo, w2t_hi, w2t_lo, out);
}

// Round 11
// 329.745 us; speedup vs baseline: 1.1119x; 1.0028x over previous
//
#include <hip/hip_runtime.h>
#include <cstdint>
#include <cstddef>

#define B_ 2
#define S_ 2048
#define HID_ 1024
#define H_ 16
#define DH_ 64

typedef __attribute__((ext_vector_type(8))) short short8;
typedef __attribute__((ext_vector_type(8))) unsigned short ushort8;
typedef __attribute__((ext_vector_type(4))) unsigned short ushort4v;
typedef __attribute__((ext_vector_type(4))) float floatx4;
typedef __attribute__((ext_vector_type(4))) float float4v;

static __device__ __forceinline__ unsigned short f2bf(float f) {
  unsigned int u = __float_as_uint(f);
  u += 0x7fffu + ((u >> 16) & 1u);
  return (unsigned short)(u >> 16);
}
static __device__ __forceinline__ float bf2f(unsigned short h) {
  return __uint_as_float(((unsigned int)h) << 16);
}

// ---------------------------------------------------------------------------
// Kernel 0: conversions. (unchanged, proven)
// ---------------------------------------------------------------------------
__global__ __launch_bounds__(256) void convert_kernel(
    const float* __restrict__ x, const float* __restrict__ w1,
    const float* __restrict__ w2, unsigned short* __restrict__ x_bf,
    unsigned short* __restrict__ w1t, unsigned short* __restrict__ w2t_hi,
    unsigned short* __restrict__ w2t_lo) {
  const int NX = B_ * S_ * HID_;
  const int NW = HID_ * HID_;
  int idx = blockIdx.x * 256 + threadIdx.x;
  if (idx < NX) {
    x_bf[idx] = f2bf(x[idx]);
  } else if (idx < NX + NW) {
    int i = idx - NX;
    int n = i >> 10, k = i & 1023;
    w1t[i] = f2bf(w1[k * HID_ + n]);
  } else if (idx < NX + 2 * NW) {
    int i = idx - NX - NW;
    int n = i >> 10, k = i & 1023;
    float v = w2[k * HID_ + n];
    unsigned short h = f2bf(v);
    w2t_hi[i] = h;
    w2t_lo[i] = f2bf(v - bf2f(h));
  }
}

// ---------------------------------------------------------------------------
// Kernel A: per-head QKV projection + bias + rotary. (unchanged, proven)
// ---------------------------------------------------------------------------
__global__ __launch_bounds__(256) void qkv_kernel(
    const float* __restrict__ x, const float* __restrict__ wq,
    const float* __restrict__ bq, const float* __restrict__ wk,
    const float* __restrict__ bk, const float* __restrict__ wv,
    const float* __restrict__ theta,
    unsigned short* __restrict__ q_h, unsigned short* __restrict__ q_l,
    unsigned short* __restrict__ k_h, unsigned short* __restrict__ k_l,
    unsigned short* __restrict__ v_th, unsigned short* __restrict__ v_tl,
    int b) {
  __shared__ __align__(16) float xs[64 * 68];
  __shared__ __align__(16) float wqs[64 * 68];
  __shared__ __align__(16) float wks[64 * 68];
  __shared__ __align__(16) float wvs[64 * 68];

  int tid = threadIdx.x;
  int st = blockIdx.x, h = blockIdx.y;
  int s0 = st * 64;

#pragma unroll
  for (int i = 0; i < 4; ++i) {
    int cid = tid + i * 256;
    int r = cid >> 4, c4 = (cid & 15) * 4;
    *reinterpret_cast<float4v*>(&xs[r * 68 + c4]) =
        *reinterpret_cast<const float4v*>(x + ((size_t)(b * S_ + s0 + r)) * HID_ + h * DH_ + c4);
  }
#pragma unroll
  for (int i = 0; i < 4; ++i) {
    int cid = tid + i * 256;
    int d = cid >> 4, c4 = (cid & 15) * 4;
    *reinterpret_cast<float4v*>(&wqs[d * 68 + c4]) =
        *reinterpret_cast<const float4v*>(wq + (size_t)(h * DH_ + d) * DH_ + c4);
    *reinterpret_cast<float4v*>(&wks[d * 68 + c4]) =
        *reinterpret_cast<const float4v*>(wk + (size_t)(h * DH_ + d) * DH_ + c4);
    *reinterpret_cast<float4v*>(&wvs[d * 68 + c4]) =
        *reinterpret_cast<const float4v*>(wv + (size_t)(h * DH_ + d) * DH_ + c4);
  }
  __syncthreads();

  int rg = tid >> 3;
  int cg = tid & 7;
  int r0 = rg * 2, c0 = cg * 8;

  float aq[2][8], ak[2][8], av[2][8];
#pragma unroll
  for (int i = 0; i < 2; ++i)
#pragma unroll
    for (int j = 0; j < 8; ++j) { aq[i][j] = 0.f; ak[i][j] = 0.f; av[i][j] = 0.f; }

  for (int d = 0; d < 64; ++d) {
    float x0 = xs[(r0 + 0) * 68 + d];
    float x1 = xs[(r0 + 1) * 68 + d];
#pragma unroll
    for (int j = 0; j < 8; ++j) {
      float wqv = wqs[d * 68 + c0 + j];
      float wkv = wks[d * 68 + c0 + j];
      float wvv = wvs[d * 68 + c0 + j];
      aq[0][j] += x0 * wqv; aq[1][j] += x1 * wqv;
      ak[0][j] += x0 * wkv; ak[1][j] += x1 * wkv;
      av[0][j] += x0 * wvv; av[1][j] += x1 * wvv;
    }
  }

  float thv[8], bqv[8], bkv[8];
#pragma unroll
  for (int j = 0; j < 8; ++j) {
    thv[j] = theta[h * DH_ + c0 + j];
    bqv[j] = bq[h * DH_ + c0 + j];
    bkv[j] = bk[h * DH_ + c0 + j];
  }

  // Reuse xs/wqs LDS as bf16 V-transpose staging (all reads of them are done).
  __syncthreads();
  unsigned short* VtH = reinterpret_cast<unsigned short*>(xs);   // [64 d][72]
  unsigned short* VtL = reinterpret_cast<unsigned short*>(wqs);  // [64 d][72]

#pragma unroll
  for (int i = 0; i < 2; ++i) {
    int s = s0 + r0 + i;
    size_t qb = ((size_t)h * S_ + s) * 128;
    ushort8 qch, qcl, qsh, qsl, kch, kcl, ksh, ksl;
#pragma unroll
    for (int j = 0; j < 8; ++j) {
      float q = aq[i][j] + bqv[j];
      float k = ak[i][j] + bkv[j];
      float ang = (float)s * thv[j];
      float cs = cosf(ang), sn = sinf(ang);
      float qc = q * cs, qs = q * sn;
      unsigned short hq1 = f2bf(qc);
      qch[j] = hq1;
      qcl[j] = f2bf(qc - bf2f(hq1));
      unsigned short hq2 = f2bf(qs);
      qsh[j] = hq2;
      qsl[j] = f2bf(qs - bf2f(hq2));
      float kc = k * cs, ksn = k * sn;
      unsigned short h1 = f2bf(kc);
      kch[j] = h1;
      kcl[j] = f2bf(kc - bf2f(h1));
      unsigned short h2 = f2bf(ksn);
      ksh[j] = h2;
      ksl[j] = f2bf(ksn - bf2f(h2));
      float vv = av[i][j];
      unsigned short vh1 = f2bf(vv);
      VtH[(c0 + j) * 72 + (r0 + i)] = vh1;
      VtL[(c0 + j) * 72 + (r0 + i)] = f2bf(vv - bf2f(vh1));
    }
    *reinterpret_cast<ushort8*>(q_h + qb + c0) = qch;
    *reinterpret_cast<ushort8*>(q_h + qb + 64 + c0) = qsh;
    *reinterpret_cast<ushort8*>(q_l + qb + c0) = qcl;
    *reinterpret_cast<ushort8*>(q_l + qb + 64 + c0) = qsl;
    *reinterpret_cast<ushort8*>(k_h + qb + c0) = kch;
    *reinterpret_cast<ushort8*>(k_h + qb + 64 + c0) = ksh;
    *reinterpret_cast<ushort8*>(k_l + qb + c0) = kcl;
    *reinterpret_cast<ushort8*>(k_l + qb + 64 + c0) = ksl;
  }
  __syncthreads();
  // Coalesced transposed store: v_t[h][d][S]
#pragma unroll
  for (int i = 0; i < 2; ++i) {
    int cid = tid + i * 256;
    int d = cid >> 3, t8 = (cid & 7) * 8;
    size_t gb = ((size_t)(h * 64 + d)) * S_ + s0 + t8;
    *reinterpret_cast<ushort8*>(v_th + gb) = *reinterpret_cast<const ushort8*>(&VtH[d * 72 + t8]);
    *reinterpret_cast<ushort8*>(v_tl + gb) = *reinterpret_cast<const ushort8*>(&VtL[d * 72 + t8]);
  }
}

// ---------------------------------------------------------------------------
// Kernel B: retention v8 — r10 structure (passing) + T5 s_setprio around the
// QK and PV MFMA clusters (role diversity exists: 2 co-resident blocks at
// different kt phases + staging-overlaps-PV within each block).
// ---------------------------------------------------------------------------
#define SCOFF(row, colb)   ((row) * 256 + ((colb) ^ (((row) & 7) << 4)))

__global__ __launch_bounds__(256) void retention_split_kernel(
    const unsigned short* __restrict__ q_h, const unsigned short* __restrict__ q_l,
    const unsigned short* __restrict__ k_h, const unsigned short* __restrict__ k_l,
    const unsigned short* __restrict__ v_th, const unsigned short* __restrict__ v_tl,
    float* __restrict__ partial) {
  __shared__ __align__(16) unsigned short Kh[64 * 128];     // 16 KiB swizzled
  __shared__ __align__(16) unsigned short Kl[64 * 128];     // 16 KiB
  __shared__ __align__(16) unsigned short Vh[2][64 * 64];   // 16 KiB [d][t] dbuf
  __shared__ __align__(16) unsigned short Vl[2][64 * 64];   // 16 KiB
  __shared__ __align__(16) float Sc[64 * 64];               // 16 KiB swizzled

  char* KhB = (char*)Kh;
  char* KlB = (char*)Kl;
  char* VhB = (char*)Vh;
  char* VlB = (char*)Vl;
  char* ScB = (char*)Sc;

  int tid = threadIdx.x;
  int w = tid >> 6;
  int lane = tid & 63, ln = lane & 15, quad = lane >> 4;
  int wr = w >> 1, wc = w & 1;
  // Decode (bijective on [0,1024)): xcd-affine h, half bit, heavy-first qt.
  int f = blockIdx.x;
  int h = ((f & 7) << 1) | ((f >> 3) & 1);
  int half = (f >> 4) & 1;
  int qt = 31 - (f >> 5);
  int s0 = qt * 64;

  // kt range for this half: [kt0, kt1). m = ceil((qt+1)/2).
  int m = (qt + 2) >> 1;
  int kt0 = half ? m : 0;
  int kt1 = half ? (qt + 1) : m;

  const float lo_c = -6.2383246250395075f, hi_c = -3.4657359027997265f;
  float gam = 1.f - __expf(lo_c + (hi_c - lo_c) * ((float)h * (1.f / 15.f)));
  float logg = __logf(gam);

  // Factored decay (same integer exp arguments as r6/r9 -> identical values).
  float rowf[2][4], colf[2];
#pragma unroll
  for (int rt = 0; rt < 2; ++rt)
#pragma unroll
    for (int rr = 0; rr < 4; ++rr)
      rowf[rt][rr] = __expf((float)(wr * 32 + rt * 16 + quad * 4 + rr) * logg);
#pragma unroll
  for (int ns = 0; ns < 2; ++ns)
    colf[ns] = __expf(-(float)(wc * 32 + ns * 16 + ln) * logg);

  const unsigned short* khb = k_h + (size_t)h * S_ * 128;
  const unsigned short* klb = k_l + (size_t)h * S_ * 128;
  const unsigned short* vhb = v_th + (size_t)h * 64 * S_;
  const unsigned short* vlb = v_tl + (size_t)h * 64 * S_;

  // Q fragments (A-layout), 2 row-tiles, precomputed bf16 hi/lo.
  short8 qfh[2][4], qfl[2][4];
#pragma unroll
  for (int rt = 0; rt < 2; ++rt) {
    int sQ = s0 + wr * 32 + rt * 16 + ln;
    const unsigned short* qhp = q_h + ((size_t)h * S_ + sQ) * 128 + quad * 8;
    const unsigned short* qlp = q_l + ((size_t)h * S_ + sQ) * 128 + quad * 8;
#pragma unroll
    for (int c = 0; c < 4; ++c) {
      qfh[rt][c] = *reinterpret_cast<const short8*>(qhp + c * 32);
      qfl[rt][c] = *reinterpret_cast<const short8*>(qlp + c * 32);
    }
  }

  floatx4 accO[4];
#pragma unroll
  for (int i = 0; i < 4; ++i) accO[i] = (floatx4){0.f, 0.f, 0.f, 0.f};

  // Prologue: stage tile kt0 -> K + V[0]; prefetch kt0+1 into regs.
  ushort8 skh[4], skl[4], svh[2], svl[2];
  {
    int t00 = kt0 * 64;
#pragma unroll
    for (int i = 0; i < 4; ++i) {
      int cid = tid + i * 256;
      int r = cid >> 4, c8 = (cid & 15) * 8;
      skh[i] = *reinterpret_cast<const ushort8*>(khb + ((size_t)(t00 + r)) * 128 + c8);
      skl[i] = *reinterpret_cast<const ushort8*>(klb + ((size_t)(t00 + r)) * 128 + c8);
    }
#pragma unroll
    for (int i = 0; i < 2; ++i) {
      int cid = tid + i * 256;
      int d = cid >> 3, t8 = (cid & 7) * 8;
      svh[i] = *reinterpret_cast<const ushort8*>(vhb + (size_t)d * S_ + t00 + t8);
      svl[i] = *reinterpret_cast<const ushort8*>(vlb + (size_t)d * S_ + t00 + t8);
    }
#pragma unroll
    for (int i = 0; i < 4; ++i) {
      int cid = tid + i * 256;
      int r = cid >> 4;
      int ko = r * 256 + (((cid & 15) * 16) ^ ((r & 7) << 4));
      *reinterpret_cast<ushort8*>(KhB + ko) = skh[i];
      *reinterpret_cast<ushort8*>(KlB + ko) = skl[i];
    }
#pragma unroll
    for (int i = 0; i < 2; ++i) {
      int cid = tid + i * 256;
      int d = cid >> 3;
      int vo = d * 128 + (((cid & 7) * 16) ^ ((d & 7) << 4));  // buffer 0
      *reinterpret_cast<ushort8*>(VhB + vo) = svh[i];
      *reinterpret_cast<ushort8*>(VlB + vo) = svl[i];
    }
    if (kt0 + 1 < kt1) {
      int t01 = (kt0 + 1) * 64;
#pragma unroll
      for (int i = 0; i < 4; ++i) {
        int cid = tid + i * 256;
        int r = cid >> 4, c8 = (cid & 15) * 8;
        skh[i] = *reinterpret_cast<const ushort8*>(khb + ((size_t)(t01 + r)) * 128 + c8);
        skl[i] = *reinterpret_cast<const ushort8*>(klb + ((size_t)(t01 + r)) * 128 + c8);
      }
#pragma unroll
      for (int i = 0; i < 2; ++i) {
        int cid = tid + i * 256;
        int d = cid >> 3, t8 = (cid & 7) * 8;
        svh[i] = *reinterpret_cast<const ushort8*>(vhb + (size_t)d * S_ + t01 + t8);
        svl[i] = *reinterpret_cast<const ushort8*>(vlb + (size_t)d * S_ + t01 + t8);
      }
    }
  }
  __syncthreads();

  for (int kt = kt0; kt < kt1; ++kt) {
    int vb = (kt - kt0) & 1;
    // QK^T split-MFMA, 2x2 quadrant (r9 verbatim) — setprio'd cluster.
    floatx4 accS[2][2];
#pragma unroll
    for (int rt = 0; rt < 2; ++rt)
#pragma unroll
      for (int ns = 0; ns < 2; ++ns) accS[rt][ns] = (floatx4){0.f, 0.f, 0.f, 0.f};
    __builtin_amdgcn_s_setprio(1);
#pragma unroll
    for (int ns = 0; ns < 2; ++ns) {
      int krow = wc * 32 + ns * 16 + ln;
#pragma unroll
      for (int ks = 0; ks < 4; ++ks) {
        int off = krow * 256 + ((ks * 64 + quad * 16) ^ ((ln & 7) << 4));
        short8 kh = *reinterpret_cast<const short8*>(KhB + off);
        short8 kl = *reinterpret_cast<const short8*>(KlB + off);
#pragma unroll
        for (int rt = 0; rt < 2; ++rt) {
          accS[rt][ns] = __builtin_amdgcn_mfma_f32_16x16x32_bf16(qfh[rt][ks], kh, accS[rt][ns], 0, 0, 0);
          accS[rt][ns] = __builtin_amdgcn_mfma_f32_16x16x32_bf16(qfl[rt][ks], kh, accS[rt][ns], 0, 0, 0);
          accS[rt][ns] = __builtin_amdgcn_mfma_f32_16x16x32_bf16(qfh[rt][ks], kl, accS[rt][ns], 0, 0, 0);
        }
      }
    }
    __builtin_amdgcn_s_setprio(0);

    // Factored decay (+ causal select only on the diagonal tile) -> Sc.
    float tf = __expf((float)(64 * (qt - kt)) * logg);
    float trf[2][4];
#pragma unroll
    for (int rt = 0; rt < 2; ++rt)
#pragma unroll
      for (int rr = 0; rr < 4; ++rr) trf[rt][rr] = tf * rowf[rt][rr];
    if (kt < qt) {
#pragma unroll
      for (int rt = 0; rt < 2; ++rt)
#pragma unroll
        for (int ns = 0; ns < 2; ++ns) {
          int col = wc * 32 + ns * 16 + ln;
#pragma unroll
          for (int rr = 0; rr < 4; ++rr) {
            int row = wr * 32 + rt * 16 + quad * 4 + rr;
            *reinterpret_cast<float*>(ScB + SCOFF(row, col * 4)) =
                accS[rt][ns][rr] * trf[rt][rr] * colf[ns];
          }
        }
    } else {
#pragma unroll
      for (int rt = 0; rt < 2; ++rt)
#pragma unroll
        for (int ns = 0; ns < 2; ++ns) {
          int col = wc * 32 + ns * 16 + ln;
#pragma unroll
          for (int rr = 0; rr < 4; ++rr) {
            int row = wr * 32 + rt * 16 + quad * 4 + rr;
            float v = accS[rt][ns][rr] * trf[rt][rr] * colf[ns];
            *reinterpret_cast<float*>(ScB + SCOFF(row, col * 4)) =
                (row >= col) ? v : 0.f;
          }
        }
    }
    __syncthreads();  // B1: Sc visible; all K reads AND V[vb^1] reads done

    // Staged writes overlap PV: K (single buffer, reads finished at B1) and
    // V[next] into the alternate buffer. Then issue kt+2 prefetch.
    if (kt + 1 < kt1) {
#pragma unroll
      for (int i = 0; i < 4; ++i) {
        int cid = tid + i * 256;
        int r = cid >> 4;
        int ko = r * 256 + (((cid & 15) * 16) ^ ((r & 7) << 4));
        *reinterpret_cast<ushort8*>(KhB + ko) = skh[i];
        *reinterpret_cast<ushort8*>(KlB + ko) = skl[i];
      }
#pragma unroll
      for (int i = 0; i < 2; ++i) {
        int cid = tid + i * 256;
        int d = cid >> 3;
        int vo = (vb ^ 1) * 8192 + d * 128 + (((cid & 7) * 16) ^ ((d & 7) << 4));
        *reinterpret_cast<ushort8*>(VhB + vo) = svh[i];
        *reinterpret_cast<ushort8*>(VlB + vo) = svl[i];
      }
      if (kt + 2 < kt1) {
        int t0n = (kt + 2) * 64;
#pragma unroll
        for (int i = 0; i < 4; ++i) {
          int cid = tid + i * 256;
          int r = cid >> 4, c8 = (cid & 15) * 8;
          skh[i] = *reinterpret_cast<const ushort8*>(khb + ((size_t)(t0n + r)) * 128 + c8);
          skl[i] = *reinterpret_cast<const ushort8*>(klb + ((size_t)(t0n + r)) * 128 + c8);
        }
#pragma unroll
        for (int i = 0; i < 2; ++i) {
          int cid = tid + i * 256;
          int d = cid >> 3, t8 = (cid & 7) * 8;
          svh[i] = *reinterpret_cast<const ushort8*>(vhb + (size_t)d * S_ + t0n + t8);
          svl[i] = *reinterpret_cast<const ushort8*>(vlb + (size_t)d * S_ + t0n + t8);
        }
      }
    }

    // PV split-MFMA: reads Sc + V[vb] (disjoint from the writes above).
    __builtin_amdgcn_s_setprio(1);
#pragma unroll
    for (int ks = 0; ks < 2; ++ks) {
      int prw = w * 16 + ln;
      int cb = ks * 128 + quad * 32;
      float4v p0 = *reinterpret_cast<const float4v*>(ScB + SCOFF(prw, cb));
      float4v p1 = *reinterpret_cast<const float4v*>(ScB + SCOFF(prw, cb + 16));
      short8 ph, pl;
#pragma unroll
      for (int j = 0; j < 4; ++j) {
        unsigned short hh = f2bf(p0[j]);
        ph[j] = (short)hh;
        pl[j] = (short)f2bf(p0[j] - bf2f(hh));
        unsigned short hh2 = f2bf(p1[j]);
        ph[4 + j] = (short)hh2;
        pl[4 + j] = (short)f2bf(p1[j] - bf2f(hh2));
      }
#pragma unroll
      for (int ds = 0; ds < 4; ++ds) {
        int d = ds * 16 + ln;
        int voff = vb * 8192 + d * 128 + ((ks * 64 + quad * 16) ^ ((ln & 7) << 4));
        short8 vh = *reinterpret_cast<const short8*>(VhB + voff);
        short8 vl = *reinterpret_cast<const short8*>(VlB + voff);
        accO[ds] = __builtin_amdgcn_mfma_f32_16x16x32_bf16(ph, vh, accO[ds], 0, 0, 0);
        accO[ds] = __builtin_amdgcn_mfma_f32_16x16x32_bf16(pl, vh, accO[ds], 0, 0, 0);
        accO[ds] = __builtin_amdgcn_mfma_f32_16x16x32_bf16(ph, vl, accO[ds], 0, 0, 0);
      }
    }
    __builtin_amdgcn_s_setprio(0);

    __syncthreads();  // B2: PV reads done; staged K/V writes visible
  }

  // Epilogue: store raw fp32 partial accO (16 KB/block). (r9 verbatim)
  float* pout = partial + ((size_t)(((h * 32 + qt) << 1) + half)) * 4096;
#pragma unroll
  for (int ds = 0; ds < 4; ++ds) {
#pragma unroll
    for (int rr = 0; rr < 4; ++rr) {
      pout[(w * 16 + quad * 4 + rr) * 64 + ds * 16 + ln] = accO[ds][rr];
    }
  }
}

// ---------------------------------------------------------------------------
// Kernel B2: combine halves + GroupNorm (r6 verbatim, proven).
// ---------------------------------------------------------------------------
__global__ __launch_bounds__(256) void combine_gn_kernel(
    const float* __restrict__ partial, const float* __restrict__ gn_w,
    const float* __restrict__ gn_b, float* __restrict__ retn, int b) {
  __shared__ float gnred[64][8];
  int tid = threadIdx.x;
  int qi = blockIdx.x;            // qi = h*32 + qt
  int h = qi >> 5, qt = qi & 31;
  const float* p0 = partial + (size_t)qi * 8192;
  const float* p1 = p0 + 4096;

  int r2 = tid >> 2;
  int sub = tid & 3;
  float a16[16];
#pragma unroll
  for (int c = 0; c < 4; ++c) {
    int o = r2 * 64 + sub * 16 + c * 4;
    float4v va = *reinterpret_cast<const float4v*>(p0 + o);
    float4v vb = *reinterpret_cast<const float4v*>(p1 + o);
#pragma unroll
    for (int j = 0; j < 4; ++j) a16[c * 4 + j] = va[j] + vb[j];
  }

  float psum = 0.f, psq = 0.f;
#pragma unroll
  for (int i = 0; i < 16; ++i) { psum += a16[i]; psq += a16[i] * a16[i]; }
  gnred[r2][sub] = psum;
  gnred[r2][4 + sub] = psq;
  __syncthreads();
  float sum = gnred[r2][0] + gnred[r2][1] + gnred[r2][2] + gnred[r2][3];
  float sq = gnred[r2][4] + gnred[r2][5] + gnred[r2][6] + gnred[r2][7];
  float mean = sum * (1.f / 64.f);
  float var = sq * (1.f / 64.f) - mean * mean;
  float rstd = rsqrtf(var + 1e-5f);

  size_t obase = ((size_t)(b * S_ + qt * 64 + r2)) * HID_ + h * DH_ + sub * 16;
#pragma unroll
  for (int i = 0; i < 16; ++i) {
    float gw = gn_w[h * DH_ + sub * 16 + i];
    float gb = gn_b[h * DH_ + sub * 16 + i];
    retn[obase + i] = (a16[i] - mean) * rstd * gw + gb;
  }
}

// ---------------------------------------------------------------------------
// GEMM 1 (gate): BK 32->64 — halves barrier count (32 -> 16 barrier-pairs),
// doubles the async window of the register prefetch. LDS stride 72: all
// frag reads/writes are free 2-way bank patterns. Same k accumulation order.
// ---------------------------------------------------------------------------
__global__ __launch_bounds__(256) void gemm_gate_kernel(
    const unsigned short* __restrict__ A, const unsigned short* __restrict__ Bt,
    const float* __restrict__ retn, unsigned short* __restrict__ pre_hi,
    unsigned short* __restrict__ pre_lo) {
  const int K = HID_;
  __shared__ __align__(16) unsigned short Al[128 * 72];  // 18 KiB
  __shared__ __align__(16) unsigned short Bl[64 * 72];   //  9 KiB

  int tid = threadIdx.x;
  int lane = tid & 63, ln = lane & 15, quad = lane >> 4;
  int w = tid >> 6, wm = w >> 1, wn = w & 1;
  int m0 = blockIdx.y * 128, n0 = blockIdx.x * 64;

  floatx4 acc[4][2];
#pragma unroll
  for (int i = 0; i < 4; ++i)
#pragma unroll
    for (int j = 0; j < 2; ++j) acc[i][j] = (floatx4){0.f, 0.f, 0.f, 0.f};

  int ar[4], ac[4], br[2], bc[2];
#pragma unroll
  for (int i = 0; i < 4; ++i) {
    int cid = tid + i * 256;
    ar[i] = cid >> 3; ac[i] = (cid & 7) * 8;
  }
#pragma unroll
  for (int i = 0; i < 2; ++i) {
    int cid = tid + i * 256;
    br[i] = cid >> 3; bc[i] = (cid & 7) * 8;
  }

  // Prefetch tile 0 (64 k-cols).
  ushort8 ra[4], rb[2];
#pragma unroll
  for (int i = 0; i < 4; ++i)
    ra[i] = *reinterpret_cast<const ushort8*>(A + (size_t)(m0 + ar[i]) * K + ac[i]);
#pragma unroll
  for (int i = 0; i < 2; ++i)
    rb[i] = *reinterpret_cast<const ushort8*>(Bt + (size_t)(n0 + br[i]) * K + bc[i]);

  for (int k0 = 0; k0 < K; k0 += 64) {
#pragma unroll
    for (int i = 0; i < 4; ++i)
      *reinterpret_cast<ushort8*>(&Al[ar[i] * 72 + ac[i]]) = ra[i];
#pragma unroll
    for (int i = 0; i < 2; ++i)
      *reinterpret_cast<ushort8*>(&Bl[br[i] * 72 + bc[i]]) = rb[i];
    if (k0 + 64 < K) {
#pragma unroll
      for (int i = 0; i < 4; ++i)
        ra[i] = *reinterpret_cast<const ushort8*>(A + (size_t)(m0 + ar[i]) * K + k0 + 64 + ac[i]);
#pragma unroll
      for (int i = 0; i < 2; ++i)
        rb[i] = *reinterpret_cast<const ushort8*>(Bt + (size_t)(n0 + br[i]) * K + k0 + 64 + bc[i]);
    }
    __syncthreads();

#pragma unroll
    for (int ks = 0; ks < 2; ++ks) {
      short8 af[4], bfr[2];
#pragma unroll
      for (int i = 0; i < 4; ++i)
        af[i] = *reinterpret_cast<const short8*>(&Al[(wm * 64 + i * 16 + ln) * 72 + ks * 32 + quad * 8]);
#pragma unroll
      for (int i = 0; i < 2; ++i)
        bfr[i] = *reinterpret_cast<const short8*>(&Bl[(wn * 32 + i * 16 + ln) * 72 + ks * 32 + quad * 8]);
#pragma unroll
      for (int mi = 0; mi < 4; ++mi)
#pragma unroll
        for (int ni = 0; ni < 2; ++ni)
          acc[mi][ni] = __builtin_amdgcn_mfma_f32_16x16x32_bf16(af[mi], bfr[ni], acc[mi][ni], 0, 0, 0);
    }
    __syncthreads();
  }

#pragma unroll
  for (int mi = 0; mi < 4; ++mi) {
#pragma unroll
    for (int r = 0; r < 4; ++r) {
      int row = m0 + wm * 64 + mi * 16 + quad * 4 + r;
#pragma unroll
      for (int ni = 0; ni < 2; ++ni) {
        int col = n0 + wn * 32 + ni * 16 + ln;
        float g = acc[mi][ni][r];
        float val = g * (1.f / (1.f + __expf(-g))) + retn[(size_t)row * HID_ + col];
        unsigned short hh = f2bf(val);
        size_t oidx = (size_t)row * HID_ + col;
        pre_hi[oidx] = hh;
        pre_lo[oidx] = f2bf(val - bf2f(hh));
      }
    }
  }
}

// ---------------------------------------------------------------------------
// GEMM 2 (output): BK 32->64, same restructure (4 streams). LDS 54 KiB ->
// 2 blocks/CU retained.
// ---------------------------------------------------------------------------
__global__ __launch_bounds__(256) void gemm_out_kernel(
    const unsigned short* __restrict__ Ah, const unsigned short* __restrict__ Alo,
    const unsigned short* __restrict__ Bth, const unsigned short* __restrict__ Btlo,
    float* __restrict__ out_f) {
  const int K = HID_;
  __shared__ __align__(16) unsigned short AhS[128 * 72];  // 18 KiB
  __shared__ __align__(16) unsigned short AlS[128 * 72];  // 18 KiB
  __shared__ __align__(16) unsigned short BhS[64 * 72];   //  9 KiB
  __shared__ __align__(16) unsigned short BlS[64 * 72];   //  9 KiB

  int tid = threadIdx.x;
  int lane = tid & 63, ln = lane & 15, quad = lane >> 4;
  int w = tid >> 6, wm = w >> 1, wn = w & 1;
  int m0 = blockIdx.y * 128, n0 = blockIdx.x * 64;

  floatx4 acc[4][2];
#pragma unroll
  for (int i = 0; i < 4; ++i)
#pragma unroll
    for (int j = 0; j < 2; ++j) acc[i][j] = (floatx4){0.f, 0.f, 0.f, 0.f};

  int ar[4], ac[4], br[2], bc[2];
#pragma unroll
  for (int i = 0; i < 4; ++i) {
    int cid = tid + i * 256;
    ar[i] = cid >> 3; ac[i] = (cid & 7) * 8;
  }
#pragma unroll
  for (int i = 0; i < 2; ++i) {
    int cid = tid + i * 256;
    br[i] = cid >> 3; bc[i] = (cid & 7) * 8;
  }

  // Prefetch tile 0.
  ushort8 rah[4], ral[4], rbh[2], rbl[2];
#pragma unroll
  for (int i = 0; i < 4; ++i) {
    size_t ga = (size_t)(m0 + ar[i]) * K + ac[i];
    rah[i] = *reinterpret_cast<const ushort8*>(Ah + ga);
    ral[i] = *reinterpret_cast<const ushort8*>(Alo + ga);
  }
#pragma unroll
  for (int i = 0; i < 2; ++i) {
    size_t gb = (size_t)(n0 + br[i]) * K + bc[i];
    rbh[i] = *reinterpret_cast<const ushort8*>(Bth + gb);
    rbl[i] = *reinterpret_cast<const ushort8*>(Btlo + gb);
  }

  for (int k0 = 0; k0 < K; k0 += 64) {
#pragma unroll
    for (int i = 0; i < 4; ++i) {
      *reinterpret_cast<ushort8*>(&AhS[ar[i] * 72 + ac[i]]) = rah[i];
      *reinterpret_cast<ushort8*>(&AlS[ar[i] * 72 + ac[i]]) = ral[i];
    }
#pragma unroll
    for (int i = 0; i < 2; ++i) {
      *reinterpret_cast<ushort8*>(&BhS[br[i] * 72 + bc[i]]) = rbh[i];
      *reinterpret_cast<ushort8*>(&BlS[br[i] * 72 + bc[i]]) = rbl[i];
    }
    if (k0 + 64 < K) {
#pragma unroll
      for (int i = 0; i < 4; ++i) {
        size_t ga = (size_t)(m0 + ar[i]) * K + k0 + 64 + ac[i];
        rah[i] = *reinterpret_cast<const ushort8*>(Ah + ga);
        ral[i] = *reinterpret_cast<const ushort8*>(Alo + ga);
      }
#pragma unroll
      for (int i = 0; i < 2; ++i) {
        size_t gb = (size_t)(n0 + br[i]) * K + k0 + 64 + bc[i];
        rbh[i] = *reinterpret_cast<const ushort8*>(Bth + gb);
        rbl[i] = *reinterpret_cast<const ushort8*>(Btlo + gb);
      }
    }
    __syncthreads();

#pragma unroll
    for (int ks = 0; ks < 2; ++ks) {
      short8 afh[4], afl[4], bfh[2], bfl[2];
#pragma unroll
      for (int i = 0; i < 4; ++i) {
        int ao = (wm * 64 + i * 16 + ln) * 72 + ks * 32 + quad * 8;
        afh[i] = *reinterpret_cast<const short8*>(&AhS[ao]);
        afl[i] = *reinterpret_cast<const short8*>(&AlS[ao]);
      }
#pragma unroll
      for (int i = 0; i < 2; ++i) {
        int bo = (wn * 32 + i * 16 + ln) * 72 + ks * 32 + quad * 8;
        bfh[i] = *reinterpret_cast<const short8*>(&BhS[bo]);
        bfl[i] = *reinterpret_cast<const short8*>(&BlS[bo]);
      }
#pragma unroll
      for (int mi = 0; mi < 4; ++mi)
#pragma unroll
        for (int ni = 0; ni < 2; ++ni) {
          floatx4 a = acc[mi][ni];
          a = __builtin_amdgcn_mfma_f32_16x16x32_bf16(afh[mi], bfh[ni], a, 0, 0, 0);
          a = __builtin_amdgcn_mfma_f32_16x16x32_bf16(afl[mi], bfh[ni], a, 0, 0, 0);
          a = __builtin_amdgcn_mfma_f32_16x16x32_bf16(afh[mi], bfl[ni], a, 0, 0, 0);
          acc[mi][ni] = a;
        }
    }
    __syncthreads();
  }

#pragma unroll
  for (int mi = 0; mi < 4; ++mi) {
#pragma unroll
    for (int r = 0; r < 4; ++r) {
      int row = m0 + wm * 64 + mi * 16 + quad * 4 + r;
#pragma unroll
      for (int ni = 0; ni < 2; ++ni) {
        int col = n0 + wn * 32 + ni * 16 + ln;
        out_f[(size_t)row * HID_ + col] = acc[mi][ni][r];
      }
    }
  }
}

// ---------------------------------------------------------------------------
extern "C" void kernel_launch(void* const* d_in, const int* in_sizes, int n_in,
                              void* d_out, int out_size, void* d_ws,
                              size_t ws_size, hipStream_t stream) {
  (void)in_sizes; (void)n_in; (void)out_size; (void)ws_size;
  const float* x = (const float*)d_in[0];
  const float* wq = (const float*)d_in[1];
  const float* bq = (const float*)d_in[2];
  const float* wk = (const float*)d_in[3];
  const float* bk = (const float*)d_in[4];
  const float* wv = (const float*)d_in[5];
  const float* theta = (const float*)d_in[6];
  const float* gn_w = (const float*)d_in[7];
  const float* gn_b = (const float*)d_in[8];
  const float* w1 = (const float*)d_in[9];
  const float* w2 = (const float*)d_in[10];

  const size_t MB = 1024 * 1024;
  char* ws = (char*)d_ws;
  unsigned short* x_bf   = (unsigned short*)(ws + 0 * MB);    //  8 MiB
  unsigned short* w1t    = (unsigned short*)(ws + 8 * MB);    //  2 MiB
  unsigned short* w2t_hi = (unsigned short*)(ws + 10 * MB);   //  2 MiB
  unsigned short* w2t_lo = (unsigned short*)(ws + 12 * MB);   //  2 MiB
  unsigned short* q_h    = (unsigned short*)(ws + 14 * MB);   //  8 MiB (1 batch)
  unsigned short* q_l    = (unsigned short*)(ws + 22 * MB);   //  8 MiB
  unsigned short* k_h    = (unsigned short*)(ws + 30 * MB);   //  8 MiB
  unsigned short* k_l    = (unsigned short*)(ws + 38 * MB);   //  8 MiB
  unsigned short* v_th   = (unsigned short*)(ws + 46 * MB);   //  4 MiB
  unsigned short* v_tl   = (unsigned short*)(ws + 50 * MB);   //  4 MiB
  float*          retn   = (float*)(ws + 54 * MB);            // 16 MiB (both batches)
  float*          partial= (float*)(ws + 70 * MB);            // 16 MiB (per batch, reused)
  unsigned short* pre_hi = (unsigned short*)(ws + 14 * MB);   //  8 MiB (alias q_h, dead by then)
  unsigned short* pre_lo = (unsigned short*)(ws + 22 * MB);   //  8 MiB (alias q_l)
  float* out = (float*)d_out;

  convert_kernel<<<dim3(24576), 256, 0, stream>>>(x, w1, w2, x_bf, w1t, w2t_hi, w2t_lo);
  for (int b = 0; b < B_; ++b) {
    qkv_kernel<<<dim3(S_ / 64, H_), 256, 0, stream>>>(
        x, wq, bq, wk, bk, wv, theta, q_h, q_l, k_h, k_l, v_th, v_tl, b);
    retention_split_kernel<<<dim3(1024), 256, 0, stream>>>(
        q_h, q_l, k_h, k_l, v_th, v_tl, partial);
    combine_gn_kernel<<<dim3(512), 256, 0, stream>>>(
        partial, gn_w, gn_b, retn, b);
  }
  gemm_gate_kernel<<<dim3(HID_ / 64, (B_ * S_) / 128), 256, 0, stream>>>(
      x_bf, w1t, retn, pre_hi, pre_lo);
  gemm_out_kernel<<<dim3(HID_ / 64, (B_ * S_) / 128), 256, 0, stream>>>(
      pre_hi, pre_lo, w2t_hi, w2t_lo, out);
}

// Round 12
// 327.214 us; speedup vs baseline: 1.1205x; 1.0077x over previous
//
#include <hip/hip_runtime.h>
#include <cstdint>
#include <cstddef>

#define B_ 2
#define S_ 2048
#define HID_ 1024
#define H_ 16
#define DH_ 64

typedef __attribute__((ext_vector_type(8))) short short8;
typedef __attribute__((ext_vector_type(8))) unsigned short ushort8;
typedef __attribute__((ext_vector_type(4))) unsigned short ushort4v;
typedef __attribute__((ext_vector_type(4))) float floatx4;
typedef __attribute__((ext_vector_type(4))) float float4v;

static __device__ __forceinline__ unsigned short f2bf(float f) {
  unsigned int u = __float_as_uint(f);
  u += 0x7fffu + ((u >> 16) & 1u);
  return (unsigned short)(u >> 16);
}
static __device__ __forceinline__ float bf2f(unsigned short h) {
  return __uint_as_float(((unsigned int)h) << 16);
}

// ---------------------------------------------------------------------------
// Kernel 0: conversions. (unchanged, proven)
// ---------------------------------------------------------------------------
__global__ __launch_bounds__(256) void convert_kernel(
    const float* __restrict__ x, const float* __restrict__ w1,
    const float* __restrict__ w2, unsigned short* __restrict__ x_bf,
    unsigned short* __restrict__ w1t, unsigned short* __restrict__ w2t_hi,
    unsigned short* __restrict__ w2t_lo) {
  const int NX = B_ * S_ * HID_;
  const int NW = HID_ * HID_;
  int idx = blockIdx.x * 256 + threadIdx.x;
  if (idx < NX) {
    x_bf[idx] = f2bf(x[idx]);
  } else if (idx < NX + NW) {
    int i = idx - NX;
    int n = i >> 10, k = i & 1023;
    w1t[i] = f2bf(w1[k * HID_ + n]);
  } else if (idx < NX + 2 * NW) {
    int i = idx - NX - NW;
    int n = i >> 10, k = i & 1023;
    float v = w2[k * HID_ + n];
    unsigned short h = f2bf(v);
    w2t_hi[i] = h;
    w2t_lo[i] = f2bf(v - bf2f(h));
  }
}

// ---------------------------------------------------------------------------
// Kernel A: per-head QKV projection + bias + rotary. (unchanged, proven)
// ---------------------------------------------------------------------------
__global__ __launch_bounds__(256) void qkv_kernel(
    const float* __restrict__ x, const float* __restrict__ wq,
    const float* __restrict__ bq, const float* __restrict__ wk,
    const float* __restrict__ bk, const float* __restrict__ wv,
    const float* __restrict__ theta,
    unsigned short* __restrict__ q_h, unsigned short* __restrict__ q_l,
    unsigned short* __restrict__ k_h, unsigned short* __restrict__ k_l,
    unsigned short* __restrict__ v_th, unsigned short* __restrict__ v_tl,
    int b) {
  __shared__ __align__(16) float xs[64 * 68];
  __shared__ __align__(16) float wqs[64 * 68];
  __shared__ __align__(16) float wks[64 * 68];
  __shared__ __align__(16) float wvs[64 * 68];

  int tid = threadIdx.x;
  int st = blockIdx.x, h = blockIdx.y;
  int s0 = st * 64;

#pragma unroll
  for (int i = 0; i < 4; ++i) {
    int cid = tid + i * 256;
    int r = cid >> 4, c4 = (cid & 15) * 4;
    *reinterpret_cast<float4v*>(&xs[r * 68 + c4]) =
        *reinterpret_cast<const float4v*>(x + ((size_t)(b * S_ + s0 + r)) * HID_ + h * DH_ + c4);
  }
#pragma unroll
  for (int i = 0; i < 4; ++i) {
    int cid = tid + i * 256;
    int d = cid >> 4, c4 = (cid & 15) * 4;
    *reinterpret_cast<float4v*>(&wqs[d * 68 + c4]) =
        *reinterpret_cast<const float4v*>(wq + (size_t)(h * DH_ + d) * DH_ + c4);
    *reinterpret_cast<float4v*>(&wks[d * 68 + c4]) =
        *reinterpret_cast<const float4v*>(wk + (size_t)(h * DH_ + d) * DH_ + c4);
    *reinterpret_cast<float4v*>(&wvs[d * 68 + c4]) =
        *reinterpret_cast<const float4v*>(wv + (size_t)(h * DH_ + d) * DH_ + c4);
  }
  __syncthreads();

  int rg = tid >> 3;
  int cg = tid & 7;
  int r0 = rg * 2, c0 = cg * 8;

  float aq[2][8], ak[2][8], av[2][8];
#pragma unroll
  for (int i = 0; i < 2; ++i)
#pragma unroll
    for (int j = 0; j < 8; ++j) { aq[i][j] = 0.f; ak[i][j] = 0.f; av[i][j] = 0.f; }

  for (int d = 0; d < 64; ++d) {
    float x0 = xs[(r0 + 0) * 68 + d];
    float x1 = xs[(r0 + 1) * 68 + d];
#pragma unroll
    for (int j = 0; j < 8; ++j) {
      float wqv = wqs[d * 68 + c0 + j];
      float wkv = wks[d * 68 + c0 + j];
      float wvv = wvs[d * 68 + c0 + j];
      aq[0][j] += x0 * wqv; aq[1][j] += x1 * wqv;
      ak[0][j] += x0 * wkv; ak[1][j] += x1 * wkv;
      av[0][j] += x0 * wvv; av[1][j] += x1 * wvv;
    }
  }

  float thv[8], bqv[8], bkv[8];
#pragma unroll
  for (int j = 0; j < 8; ++j) {
    thv[j] = theta[h * DH_ + c0 + j];
    bqv[j] = bq[h * DH_ + c0 + j];
    bkv[j] = bk[h * DH_ + c0 + j];
  }

  // Reuse xs/wqs LDS as bf16 V-transpose staging (all reads of them are done).
  __syncthreads();
  unsigned short* VtH = reinterpret_cast<unsigned short*>(xs);   // [64 d][72]
  unsigned short* VtL = reinterpret_cast<unsigned short*>(wqs);  // [64 d][72]

#pragma unroll
  for (int i = 0; i < 2; ++i) {
    int s = s0 + r0 + i;
    size_t qb = ((size_t)h * S_ + s) * 128;
    ushort8 qch, qcl, qsh, qsl, kch, kcl, ksh, ksl;
#pragma unroll
    for (int j = 0; j < 8; ++j) {
      float q = aq[i][j] + bqv[j];
      float k = ak[i][j] + bkv[j];
      float ang = (float)s * thv[j];
      float cs = cosf(ang), sn = sinf(ang);
      float qc = q * cs, qs = q * sn;
      unsigned short hq1 = f2bf(qc);
      qch[j] = hq1;
      qcl[j] = f2bf(qc - bf2f(hq1));
      unsigned short hq2 = f2bf(qs);
      qsh[j] = hq2;
      qsl[j] = f2bf(qs - bf2f(hq2));
      float kc = k * cs, ksn = k * sn;
      unsigned short h1 = f2bf(kc);
      kch[j] = h1;
      kcl[j] = f2bf(kc - bf2f(h1));
      unsigned short h2 = f2bf(ksn);
      ksh[j] = h2;
      ksl[j] = f2bf(ksn - bf2f(h2));
      float vv = av[i][j];
      unsigned short vh1 = f2bf(vv);
      VtH[(c0 + j) * 72 + (r0 + i)] = vh1;
      VtL[(c0 + j) * 72 + (r0 + i)] = f2bf(vv - bf2f(vh1));
    }
    *reinterpret_cast<ushort8*>(q_h + qb + c0) = qch;
    *reinterpret_cast<ushort8*>(q_h + qb + 64 + c0) = qsh;
    *reinterpret_cast<ushort8*>(q_l + qb + c0) = qcl;
    *reinterpret_cast<ushort8*>(q_l + qb + 64 + c0) = qsl;
    *reinterpret_cast<ushort8*>(k_h + qb + c0) = kch;
    *reinterpret_cast<ushort8*>(k_h + qb + 64 + c0) = ksh;
    *reinterpret_cast<ushort8*>(k_l + qb + c0) = kcl;
    *reinterpret_cast<ushort8*>(k_l + qb + 64 + c0) = ksl;
  }
  __syncthreads();
  // Coalesced transposed store: v_t[h][d][S]
#pragma unroll
  for (int i = 0; i < 2; ++i) {
    int cid = tid + i * 256;
    int d = cid >> 3, t8 = (cid & 7) * 8;
    size_t gb = ((size_t)(h * 64 + d)) * S_ + s0 + t8;
    *reinterpret_cast<ushort8*>(v_th + gb) = *reinterpret_cast<const ushort8*>(&VtH[d * 72 + t8]);
    *reinterpret_cast<ushort8*>(v_tl + gb) = *reinterpret_cast<const ushort8*>(&VtL[d * 72 + t8]);
  }
}

// ---------------------------------------------------------------------------
// Kernel B: retention v8 (r11, passing: 60.1 µs) — unchanged.
// ---------------------------------------------------------------------------
#define SCOFF(row, colb)   ((row) * 256 + ((colb) ^ (((row) & 7) << 4)))

__global__ __launch_bounds__(256) void retention_split_kernel(
    const unsigned short* __restrict__ q_h, const unsigned short* __restrict__ q_l,
    const unsigned short* __restrict__ k_h, const unsigned short* __restrict__ k_l,
    const unsigned short* __restrict__ v_th, const unsigned short* __restrict__ v_tl,
    float* __restrict__ partial) {
  __shared__ __align__(16) unsigned short Kh[64 * 128];     // 16 KiB swizzled
  __shared__ __align__(16) unsigned short Kl[64 * 128];     // 16 KiB
  __shared__ __align__(16) unsigned short Vh[2][64 * 64];   // 16 KiB [d][t] dbuf
  __shared__ __align__(16) unsigned short Vl[2][64 * 64];   // 16 KiB
  __shared__ __align__(16) float Sc[64 * 64];               // 16 KiB swizzled

  char* KhB = (char*)Kh;
  char* KlB = (char*)Kl;
  char* VhB = (char*)Vh;
  char* VlB = (char*)Vl;
  char* ScB = (char*)Sc;

  int tid = threadIdx.x;
  int w = tid >> 6;
  int lane = tid & 63, ln = lane & 15, quad = lane >> 4;
  int wr = w >> 1, wc = w & 1;
  // Decode (bijective on [0,1024)): xcd-affine h, half bit, heavy-first qt.
  int f = blockIdx.x;
  int h = ((f & 7) << 1) | ((f >> 3) & 1);
  int half = (f >> 4) & 1;
  int qt = 31 - (f >> 5);
  int s0 = qt * 64;

  // kt range for this half: [kt0, kt1). m = ceil((qt+1)/2).
  int m = (qt + 2) >> 1;
  int kt0 = half ? m : 0;
  int kt1 = half ? (qt + 1) : m;

  const float lo_c = -6.2383246250395075f, hi_c = -3.4657359027997265f;
  float gam = 1.f - __expf(lo_c + (hi_c - lo_c) * ((float)h * (1.f / 15.f)));
  float logg = __logf(gam);

  // Factored decay (same integer exp arguments as r6/r9 -> identical values).
  float rowf[2][4], colf[2];
#pragma unroll
  for (int rt = 0; rt < 2; ++rt)
#pragma unroll
    for (int rr = 0; rr < 4; ++rr)
      rowf[rt][rr] = __expf((float)(wr * 32 + rt * 16 + quad * 4 + rr) * logg);
#pragma unroll
  for (int ns = 0; ns < 2; ++ns)
    colf[ns] = __expf(-(float)(wc * 32 + ns * 16 + ln) * logg);

  const unsigned short* khb = k_h + (size_t)h * S_ * 128;
  const unsigned short* klb = k_l + (size_t)h * S_ * 128;
  const unsigned short* vhb = v_th + (size_t)h * 64 * S_;
  const unsigned short* vlb = v_tl + (size_t)h * 64 * S_;

  // Q fragments (A-layout), 2 row-tiles, precomputed bf16 hi/lo.
  short8 qfh[2][4], qfl[2][4];
#pragma unroll
  for (int rt = 0; rt < 2; ++rt) {
    int sQ = s0 + wr * 32 + rt * 16 + ln;
    const unsigned short* qhp = q_h + ((size_t)h * S_ + sQ) * 128 + quad * 8;
    const unsigned short* qlp = q_l + ((size_t)h * S_ + sQ) * 128 + quad * 8;
#pragma unroll
    for (int c = 0; c < 4; ++c) {
      qfh[rt][c] = *reinterpret_cast<const short8*>(qhp + c * 32);
      qfl[rt][c] = *reinterpret_cast<const short8*>(qlp + c * 32);
    }
  }

  floatx4 accO[4];
#pragma unroll
  for (int i = 0; i < 4; ++i) accO[i] = (floatx4){0.f, 0.f, 0.f, 0.f};

  // Prologue: stage tile kt0 -> K + V[0]; prefetch kt0+1 into regs.
  ushort8 skh[4], skl[4], svh[2], svl[2];
  {
    int t00 = kt0 * 64;
#pragma unroll
    for (int i = 0; i < 4; ++i) {
      int cid = tid + i * 256;
      int r = cid >> 4, c8 = (cid & 15) * 8;
      skh[i] = *reinterpret_cast<const ushort8*>(khb + ((size_t)(t00 + r)) * 128 + c8);
      skl[i] = *reinterpret_cast<const ushort8*>(klb + ((size_t)(t00 + r)) * 128 + c8);
    }
#pragma unroll
    for (int i = 0; i < 2; ++i) {
      int cid = tid + i * 256;
      int d = cid >> 3, t8 = (cid & 7) * 8;
      svh[i] = *reinterpret_cast<const ushort8*>(vhb + (size_t)d * S_ + t00 + t8);
      svl[i] = *reinterpret_cast<const ushort8*>(vlb + (size_t)d * S_ + t00 + t8);
    }
#pragma unroll
    for (int i = 0; i < 4; ++i) {
      int cid = tid + i * 256;
      int r = cid >> 4;
      int ko = r * 256 + (((cid & 15) * 16) ^ ((r & 7) << 4));
      *reinterpret_cast<ushort8*>(KhB + ko) = skh[i];
      *reinterpret_cast<ushort8*>(KlB + ko) = skl[i];
    }
#pragma unroll
    for (int i = 0; i < 2; ++i) {
      int cid = tid + i * 256;
      int d = cid >> 3;
      int vo = d * 128 + (((cid & 7) * 16) ^ ((d & 7) << 4));  // buffer 0
      *reinterpret_cast<ushort8*>(VhB + vo) = svh[i];
      *reinterpret_cast<ushort8*>(VlB + vo) = svl[i];
    }
    if (kt0 + 1 < kt1) {
      int t01 = (kt0 + 1) * 64;
#pragma unroll
      for (int i = 0; i < 4; ++i) {
        int cid = tid + i * 256;
        int r = cid >> 4, c8 = (cid & 15) * 8;
        skh[i] = *reinterpret_cast<const ushort8*>(khb + ((size_t)(t01 + r)) * 128 + c8);
        skl[i] = *reinterpret_cast<const ushort8*>(klb + ((size_t)(t01 + r)) * 128 + c8);
      }
#pragma unroll
      for (int i = 0; i < 2; ++i) {
        int cid = tid + i * 256;
        int d = cid >> 3, t8 = (cid & 7) * 8;
        svh[i] = *reinterpret_cast<const ushort8*>(vhb + (size_t)d * S_ + t01 + t8);
        svl[i] = *reinterpret_cast<const ushort8*>(vlb + (size_t)d * S_ + t01 + t8);
      }
    }
  }
  __syncthreads();

  for (int kt = kt0; kt < kt1; ++kt) {
    int vb = (kt - kt0) & 1;
    // QK^T split-MFMA, 2x2 quadrant — setprio'd cluster.
    floatx4 accS[2][2];
#pragma unroll
    for (int rt = 0; rt < 2; ++rt)
#pragma unroll
      for (int ns = 0; ns < 2; ++ns) accS[rt][ns] = (floatx4){0.f, 0.f, 0.f, 0.f};
    __builtin_amdgcn_s_setprio(1);
#pragma unroll
    for (int ns = 0; ns < 2; ++ns) {
      int krow = wc * 32 + ns * 16 + ln;
#pragma unroll
      for (int ks = 0; ks < 4; ++ks) {
        int off = krow * 256 + ((ks * 64 + quad * 16) ^ ((ln & 7) << 4));
        short8 kh = *reinterpret_cast<const short8*>(KhB + off);
        short8 kl = *reinterpret_cast<const short8*>(KlB + off);
#pragma unroll
        for (int rt = 0; rt < 2; ++rt) {
          accS[rt][ns] = __builtin_amdgcn_mfma_f32_16x16x32_bf16(qfh[rt][ks], kh, accS[rt][ns], 0, 0, 0);
          accS[rt][ns] = __builtin_amdgcn_mfma_f32_16x16x32_bf16(qfl[rt][ks], kh, accS[rt][ns], 0, 0, 0);
          accS[rt][ns] = __builtin_amdgcn_mfma_f32_16x16x32_bf16(qfh[rt][ks], kl, accS[rt][ns], 0, 0, 0);
        }
      }
    }
    __builtin_amdgcn_s_setprio(0);

    // Factored decay (+ causal select only on the diagonal tile) -> Sc.
    float tf = __expf((float)(64 * (qt - kt)) * logg);
    float trf[2][4];
#pragma unroll
    for (int rt = 0; rt < 2; ++rt)
#pragma unroll
      for (int rr = 0; rr < 4; ++rr) trf[rt][rr] = tf * rowf[rt][rr];
    if (kt < qt) {
#pragma unroll
      for (int rt = 0; rt < 2; ++rt)
#pragma unroll
        for (int ns = 0; ns < 2; ++ns) {
          int col = wc * 32 + ns * 16 + ln;
#pragma unroll
          for (int rr = 0; rr < 4; ++rr) {
            int row = wr * 32 + rt * 16 + quad * 4 + rr;
            *reinterpret_cast<float*>(ScB + SCOFF(row, col * 4)) =
                accS[rt][ns][rr] * trf[rt][rr] * colf[ns];
          }
        }
    } else {
#pragma unroll
      for (int rt = 0; rt < 2; ++rt)
#pragma unroll
        for (int ns = 0; ns < 2; ++ns) {
          int col = wc * 32 + ns * 16 + ln;
#pragma unroll
          for (int rr = 0; rr < 4; ++rr) {
            int row = wr * 32 + rt * 16 + quad * 4 + rr;
            float v = accS[rt][ns][rr] * trf[rt][rr] * colf[ns];
            *reinterpret_cast<float*>(ScB + SCOFF(row, col * 4)) =
                (row >= col) ? v : 0.f;
          }
        }
    }
    __syncthreads();  // B1: Sc visible; all K reads AND V[vb^1] reads done

    // Staged writes overlap PV: K (single buffer, reads finished at B1) and
    // V[next] into the alternate buffer. Then issue kt+2 prefetch.
    if (kt + 1 < kt1) {
#pragma unroll
      for (int i = 0; i < 4; ++i) {
        int cid = tid + i * 256;
        int r = cid >> 4;
        int ko = r * 256 + (((cid & 15) * 16) ^ ((r & 7) << 4));
        *reinterpret_cast<ushort8*>(KhB + ko) = skh[i];
        *reinterpret_cast<ushort8*>(KlB + ko) = skl[i];
      }
#pragma unroll
      for (int i = 0; i < 2; ++i) {
        int cid = tid + i * 256;
        int d = cid >> 3;
        int vo = (vb ^ 1) * 8192 + d * 128 + (((cid & 7) * 16) ^ ((d & 7) << 4));
        *reinterpret_cast<ushort8*>(VhB + vo) = svh[i];
        *reinterpret_cast<ushort8*>(VlB + vo) = svl[i];
      }
      if (kt + 2 < kt1) {
        int t0n = (kt + 2) * 64;
#pragma unroll
        for (int i = 0; i < 4; ++i) {
          int cid = tid + i * 256;
          int r = cid >> 4, c8 = (cid & 15) * 8;
          skh[i] = *reinterpret_cast<const ushort8*>(khb + ((size_t)(t0n + r)) * 128 + c8);
          skl[i] = *reinterpret_cast<const ushort8*>(klb + ((size_t)(t0n + r)) * 128 + c8);
        }
#pragma unroll
        for (int i = 0; i < 2; ++i) {
          int cid = tid + i * 256;
          int d = cid >> 3, t8 = (cid & 7) * 8;
          svh[i] = *reinterpret_cast<const ushort8*>(vhb + (size_t)d * S_ + t0n + t8);
          svl[i] = *reinterpret_cast<const ushort8*>(vlb + (size_t)d * S_ + t0n + t8);
        }
      }
    }

    // PV split-MFMA: reads Sc + V[vb] (disjoint from the writes above).
    __builtin_amdgcn_s_setprio(1);
#pragma unroll
    for (int ks = 0; ks < 2; ++ks) {
      int prw = w * 16 + ln;
      int cb = ks * 128 + quad * 32;
      float4v p0 = *reinterpret_cast<const float4v*>(ScB + SCOFF(prw, cb));
      float4v p1 = *reinterpret_cast<const float4v*>(ScB + SCOFF(prw, cb + 16));
      short8 ph, pl;
#pragma unroll
      for (int j = 0; j < 4; ++j) {
        unsigned short hh = f2bf(p0[j]);
        ph[j] = (short)hh;
        pl[j] = (short)f2bf(p0[j] - bf2f(hh));
        unsigned short hh2 = f2bf(p1[j]);
        ph[4 + j] = (short)hh2;
        pl[4 + j] = (short)f2bf(p1[j] - bf2f(hh2));
      }
#pragma unroll
      for (int ds = 0; ds < 4; ++ds) {
        int d = ds * 16 + ln;
        int voff = vb * 8192 + d * 128 + ((ks * 64 + quad * 16) ^ ((ln & 7) << 4));
        short8 vh = *reinterpret_cast<const short8*>(VhB + voff);
        short8 vl = *reinterpret_cast<const short8*>(VlB + voff);
        accO[ds] = __builtin_amdgcn_mfma_f32_16x16x32_bf16(ph, vh, accO[ds], 0, 0, 0);
        accO[ds] = __builtin_amdgcn_mfma_f32_16x16x32_bf16(pl, vh, accO[ds], 0, 0, 0);
        accO[ds] = __builtin_amdgcn_mfma_f32_16x16x32_bf16(ph, vl, accO[ds], 0, 0, 0);
      }
    }
    __builtin_amdgcn_s_setprio(0);

    __syncthreads();  // B2: PV reads done; staged K/V writes visible
  }

  // Epilogue: store raw fp32 partial accO (16 KB/block).
  float* pout = partial + ((size_t)(((h * 32 + qt) << 1) + half)) * 4096;
#pragma unroll
  for (int ds = 0; ds < 4; ++ds) {
#pragma unroll
    for (int rr = 0; rr < 4; ++rr) {
      pout[(w * 16 + quad * 4 + rr) * 64 + ds * 16 + ln] = accO[ds][rr];
    }
  }
}

// ---------------------------------------------------------------------------
// Kernel B2: combine halves + GroupNorm (proven).
// ---------------------------------------------------------------------------
__global__ __launch_bounds__(256) void combine_gn_kernel(
    const float* __restrict__ partial, const float* __restrict__ gn_w,
    const float* __restrict__ gn_b, float* __restrict__ retn, int b) {
  __shared__ float gnred[64][8];
  int tid = threadIdx.x;
  int qi = blockIdx.x;            // qi = h*32 + qt
  int h = qi >> 5, qt = qi & 31;
  const float* p0 = partial + (size_t)qi * 8192;
  const float* p1 = p0 + 4096;

  int r2 = tid >> 2;
  int sub = tid & 3;
  float a16[16];
#pragma unroll
  for (int c = 0; c < 4; ++c) {
    int o = r2 * 64 + sub * 16 + c * 4;
    float4v va = *reinterpret_cast<const float4v*>(p0 + o);
    float4v vb = *reinterpret_cast<const float4v*>(p1 + o);
#pragma unroll
    for (int j = 0; j < 4; ++j) a16[c * 4 + j] = va[j] + vb[j];
  }

  float psum = 0.f, psq = 0.f;
#pragma unroll
  for (int i = 0; i < 16; ++i) { psum += a16[i]; psq += a16[i] * a16[i]; }
  gnred[r2][sub] = psum;
  gnred[r2][4 + sub] = psq;
  __syncthreads();
  float sum = gnred[r2][0] + gnred[r2][1] + gnred[r2][2] + gnred[r2][3];
  float sq = gnred[r2][4] + gnred[r2][5] + gnred[r2][6] + gnred[r2][7];
  float mean = sum * (1.f / 64.f);
  float var = sq * (1.f / 64.f) - mean * mean;
  float rstd = rsqrtf(var + 1e-5f);

  size_t obase = ((size_t)(b * S_ + qt * 64 + r2)) * HID_ + h * DH_ + sub * 16;
#pragma unroll
  for (int i = 0; i < 16; ++i) {
    float gw = gn_w[h * DH_ + sub * 16 + i];
    float gb = gn_b[h * DH_ + sub * 16 + i];
    retn[obase + i] = (a16[i] - mean) * rstd * gw + gb;
  }
}

// ---------------------------------------------------------------------------
// GEMM 1 (gate): BM 128->64, BN=64 (grid 1024 -> 4 blocks/CU, the session's
// proven occupancy lever applied to the GEMMs). BK=32, stride 56, register
// prefetch (r10, proven). Wave tile 32x32, acc[2][2]. Same k accumulation
// order -> bit-identical outputs.
// ---------------------------------------------------------------------------
__global__ __launch_bounds__(256) void gemm_gate_kernel(
    const unsigned short* __restrict__ A, const unsigned short* __restrict__ Bt,
    const float* __restrict__ retn, unsigned short* __restrict__ pre_hi,
    unsigned short* __restrict__ pre_lo) {
  const int K = HID_;
  __shared__ __align__(16) unsigned short Al[64 * 56];  // 7 KiB
  __shared__ __align__(16) unsigned short Bl[64 * 56];  // 7 KiB

  int tid = threadIdx.x;
  int lane = tid & 63, ln = lane & 15, quad = lane >> 4;
  int w = tid >> 6, wm = w >> 1, wn = w & 1;
  int m0 = blockIdx.y * 64, n0 = blockIdx.x * 64;

  floatx4 acc[2][2];
#pragma unroll
  for (int i = 0; i < 2; ++i)
#pragma unroll
    for (int j = 0; j < 2; ++j) acc[i][j] = (floatx4){0.f, 0.f, 0.f, 0.f};

  int rr_ = tid >> 2, cc_ = (tid & 3) * 8;

  // Prefetch tile 0.
  ushort8 ra = *reinterpret_cast<const ushort8*>(A + (size_t)(m0 + rr_) * K + cc_);
  ushort8 rb = *reinterpret_cast<const ushort8*>(Bt + (size_t)(n0 + rr_) * K + cc_);

  for (int k0 = 0; k0 < K; k0 += 32) {
    *reinterpret_cast<ushort8*>(&Al[rr_ * 56 + cc_]) = ra;
    *reinterpret_cast<ushort8*>(&Bl[rr_ * 56 + cc_]) = rb;
    if (k0 + 32 < K) {
      ra = *reinterpret_cast<const ushort8*>(A + (size_t)(m0 + rr_) * K + k0 + 32 + cc_);
      rb = *reinterpret_cast<const ushort8*>(Bt + (size_t)(n0 + rr_) * K + k0 + 32 + cc_);
    }
    __syncthreads();

    short8 af[2], bfr[2];
#pragma unroll
    for (int i = 0; i < 2; ++i) {
      af[i] = *reinterpret_cast<const short8*>(&Al[(wm * 32 + i * 16 + ln) * 56 + quad * 8]);
      bfr[i] = *reinterpret_cast<const short8*>(&Bl[(wn * 32 + i * 16 + ln) * 56 + quad * 8]);
    }
#pragma unroll
    for (int mi = 0; mi < 2; ++mi)
#pragma unroll
      for (int ni = 0; ni < 2; ++ni)
        acc[mi][ni] = __builtin_amdgcn_mfma_f32_16x16x32_bf16(af[mi], bfr[ni], acc[mi][ni], 0, 0, 0);
    __syncthreads();
  }

#pragma unroll
  for (int mi = 0; mi < 2; ++mi) {
#pragma unroll
    for (int r = 0; r < 4; ++r) {
      int row = m0 + wm * 32 + mi * 16 + quad * 4 + r;
#pragma unroll
      for (int ni = 0; ni < 2; ++ni) {
        int col = n0 + wn * 32 + ni * 16 + ln;
        float g = acc[mi][ni][r];
        float val = g * (1.f / (1.f + __expf(-g))) + retn[(size_t)row * HID_ + col];
        unsigned short hh = f2bf(val);
        size_t oidx = (size_t)row * HID_ + col;
        pre_hi[oidx] = hh;
        pre_lo[oidx] = f2bf(val - bf2f(hh));
      }
    }
  }
}

// ---------------------------------------------------------------------------
// GEMM 2 (output): BM 64, BN 64, BK 32, register prefetch (4 streams).
// LDS 28 KiB -> 4 blocks/CU (grid 1024).
// ---------------------------------------------------------------------------
__global__ __launch_bounds__(256) void gemm_out_kernel(
    const unsigned short* __restrict__ Ah, const unsigned short* __restrict__ Alo,
    const unsigned short* __restrict__ Bth, const unsigned short* __restrict__ Btlo,
    float* __restrict__ out_f) {
  const int K = HID_;
  __shared__ __align__(16) unsigned short AhS[64 * 56];  // 7 KiB
  __shared__ __align__(16) unsigned short AlS[64 * 56];  // 7 KiB
  __shared__ __align__(16) unsigned short BhS[64 * 56];  // 7 KiB
  __shared__ __align__(16) unsigned short BlS[64 * 56];  // 7 KiB

  int tid = threadIdx.x;
  int lane = tid & 63, ln = lane & 15, quad = lane >> 4;
  int w = tid >> 6, wm = w >> 1, wn = w & 1;
  int m0 = blockIdx.y * 64, n0 = blockIdx.x * 64;

  floatx4 acc[2][2];
#pragma unroll
  for (int i = 0; i < 2; ++i)
#pragma unroll
    for (int j = 0; j < 2; ++j) acc[i][j] = (floatx4){0.f, 0.f, 0.f, 0.f};

  int rr_ = tid >> 2, cc_ = (tid & 3) * 8;

  // Prefetch tile 0.
  ushort8 rah, ral, rbh, rbl;
  {
    size_t ga = (size_t)(m0 + rr_) * K + cc_;
    rah = *reinterpret_cast<const ushort8*>(Ah + ga);
    ral = *reinterpret_cast<const ushort8*>(Alo + ga);
    size_t gb = (size_t)(n0 + rr_) * K + cc_;
    rbh = *reinterpret_cast<const ushort8*>(Bth + gb);
    rbl = *reinterpret_cast<const ushort8*>(Btlo + gb);
  }

  for (int k0 = 0; k0 < K; k0 += 32) {
    *reinterpret_cast<ushort8*>(&AhS[rr_ * 56 + cc_]) = rah;
    *reinterpret_cast<ushort8*>(&AlS[rr_ * 56 + cc_]) = ral;
    *reinterpret_cast<ushort8*>(&BhS[rr_ * 56 + cc_]) = rbh;
    *reinterpret_cast<ushort8*>(&BlS[rr_ * 56 + cc_]) = rbl;
    if (k0 + 32 < K) {
      size_t ga = (size_t)(m0 + rr_) * K + k0 + 32 + cc_;
      rah = *reinterpret_cast<const ushort8*>(Ah + ga);
      ral = *reinterpret_cast<const ushort8*>(Alo + ga);
      size_t gb = (size_t)(n0 + rr_) * K + k0 + 32 + cc_;
      rbh = *reinterpret_cast<const ushort8*>(Bth + gb);
      rbl = *reinterpret_cast<const ushort8*>(Btlo + gb);
    }
    __syncthreads();

    short8 afh[2], afl[2], bfh[2], bfl[2];
#pragma unroll
    for (int i = 0; i < 2; ++i) {
      int ao = (wm * 32 + i * 16 + ln) * 56 + quad * 8;
      int bo = (wn * 32 + i * 16 + ln) * 56 + quad * 8;
      afh[i] = *reinterpret_cast<const short8*>(&AhS[ao]);
      afl[i] = *reinterpret_cast<const short8*>(&AlS[ao]);
      bfh[i] = *reinterpret_cast<const short8*>(&BhS[bo]);
      bfl[i] = *reinterpret_cast<const short8*>(&BlS[bo]);
    }
#pragma unroll
    for (int mi = 0; mi < 2; ++mi)
#pragma unroll
      for (int ni = 0; ni < 2; ++ni) {
        floatx4 a = acc[mi][ni];
        a = __builtin_amdgcn_mfma_f32_16x16x32_bf16(afh[mi], bfh[ni], a, 0, 0, 0);
        a = __builtin_amdgcn_mfma_f32_16x16x32_bf16(afl[mi], bfh[ni], a, 0, 0, 0);
        a = __builtin_amdgcn_mfma_f32_16x16x32_bf16(afh[mi], bfl[ni], a, 0, 0, 0);
        acc[mi][ni] = a;
      }
    __syncthreads();
  }

#pragma unroll
  for (int mi = 0; mi < 2; ++mi) {
#pragma unroll
    for (int r = 0; r < 4; ++r) {
      int row = m0 + wm * 32 + mi * 16 + quad * 4 + r;
#pragma unroll
      for (int ni = 0; ni < 2; ++ni) {
        int col = n0 + wn * 32 + ni * 16 + ln;
        out_f[(size_t)row * HID_ + col] = acc[mi][ni][r];
      }
    }
  }
}

// ---------------------------------------------------------------------------
extern "C" void kernel_launch(void* const* d_in, const int* in_sizes, int n_in,
                              void* d_out, int out_size, void* d_ws,
                              size_t ws_size, hipStream_t stream) {
  (void)in_sizes; (void)n_in; (void)out_size; (void)ws_size;
  const float* x = (const float*)d_in[0];
  const float* wq = (const float*)d_in[1];
  const float* bq = (const float*)d_in[2];
  const float* wk = (const float*)d_in[3];
  const float* bk = (const float*)d_in[4];
  const float* wv = (const float*)d_in[5];
  const float* theta = (const float*)d_in[6];
  const float* gn_w = (const float*)d_in[7];
  const float* gn_b = (const float*)d_in[8];
  const float* w1 = (const float*)d_in[9];
  const float* w2 = (const float*)d_in[10];

  const size_t MB = 1024 * 1024;
  char* ws = (char*)d_ws;
  unsigned short* x_bf   = (unsigned short*)(ws + 0 * MB);    //  8 MiB
  unsigned short* w1t    = (unsigned short*)(ws + 8 * MB);    //  2 MiB
  unsigned short* w2t_hi = (unsigned short*)(ws + 10 * MB);   //  2 MiB
  unsigned short* w2t_lo = (unsigned short*)(ws + 12 * MB);   //  2 MiB
  unsigned short* q_h    = (unsigned short*)(ws + 14 * MB);   //  8 MiB (1 batch)
  unsigned short* q_l    = (unsigned short*)(ws + 22 * MB);   //  8 MiB
  unsigned short* k_h    = (unsigned short*)(ws + 30 * MB);   //  8 MiB
  unsigned short* k_l    = (unsigned short*)(ws + 38 * MB);   //  8 MiB
  unsigned short* v_th   = (unsigned short*)(ws + 46 * MB);   //  4 MiB
  unsigned short* v_tl   = (unsigned short*)(ws + 50 * MB);   //  4 MiB
  float*          retn   = (float*)(ws + 54 * MB);            // 16 MiB (both batches)
  float*          partial= (float*)(ws + 70 * MB);            // 16 MiB (per batch, reused)
  unsigned short* pre_hi = (unsigned short*)(ws + 14 * MB);   //  8 MiB (alias q_h, dead by then)
  unsigned short* pre_lo = (unsigned short*)(ws + 22 * MB);   //  8 MiB (alias q_l)
  float* out = (float*)d_out;

  convert_kernel<<<dim3(24576), 256, 0, stream>>>(x, w1, w2, x_bf, w1t, w2t_hi, w2t_lo);
  for (int b = 0; b < B_; ++b) {
    qkv_kernel<<<dim3(S_ / 64, H_), 256, 0, stream>>>(
        x, wq, bq, wk, bk, wv, theta, q_h, q_l, k_h, k_l, v_th, v_tl, b);
    retention_split_kernel<<<dim3(1024), 256, 0, stream>>>(
        q_h, q_l, k_h, k_l, v_th, v_tl, partial);
    combine_gn_kernel<<<dim3(512), 256, 0, stream>>>(
        partial, gn_w, gn_b, retn, b);
  }
  gemm_gate_kernel<<<dim3(HID_ / 64, (B_ * S_) / 64), 256, 0, stream>>>(
      x_bf, w1t, retn, pre_hi, pre_lo);
  gemm_out_kernel<<<dim3(HID_ / 64, (B_ * S_) / 64), 256, 0, stream>>>(
      pre_hi, pre_lo, w2t_hi, w2t_lo, out);
}

// Round 13
// 320.688 us; speedup vs baseline: 1.1433x; 1.0203x over previous
//
#include <hip/hip_runtime.h>
#include <cstdint>
#include <cstddef>

#define B_ 2
#define S_ 2048
#define HID_ 1024
#define H_ 16
#define DH_ 64

typedef __attribute__((ext_vector_type(8))) short short8;
typedef __attribute__((ext_vector_type(8))) unsigned short ushort8;
typedef __attribute__((ext_vector_type(4))) unsigned short ushort4v;
typedef __attribute__((ext_vector_type(4))) float floatx4;
typedef __attribute__((ext_vector_type(4))) float float4v;

static __device__ __forceinline__ unsigned short f2bf(float f) {
  unsigned int u = __float_as_uint(f);
  u += 0x7fffu + ((u >> 16) & 1u);
  return (unsigned short)(u >> 16);
}
static __device__ __forceinline__ float bf2f(unsigned short h) {
  return __uint_as_float(((unsigned int)h) << 16);
}

// ---------------------------------------------------------------------------
// Kernel 0: conversions. x path vectorized x8 (G13); weight transposes stay
// scalar (strided reads don't vectorize without an LDS transpose). Same f2bf
// per element -> bit-identical outputs.
// ---------------------------------------------------------------------------
__global__ __launch_bounds__(256) void convert_kernel(
    const float* __restrict__ x, const float* __restrict__ w1,
    const float* __restrict__ w2, unsigned short* __restrict__ x_bf,
    unsigned short* __restrict__ w1t, unsigned short* __restrict__ w2t_hi,
    unsigned short* __restrict__ w2t_lo) {
  const int NX = B_ * S_ * HID_;
  const int NW = HID_ * HID_;
  const int NXV = NX / 8;
  int idx = blockIdx.x * 256 + threadIdx.x;
  if (idx < NXV) {
    const float4v* xp = reinterpret_cast<const float4v*>(x + (size_t)idx * 8);
    float4v a = xp[0], b = xp[1];
    ushort8 o;
    o[0] = f2bf(a[0]); o[1] = f2bf(a[1]); o[2] = f2bf(a[2]); o[3] = f2bf(a[3]);
    o[4] = f2bf(b[0]); o[5] = f2bf(b[1]); o[6] = f2bf(b[2]); o[7] = f2bf(b[3]);
    *reinterpret_cast<ushort8*>(x_bf + (size_t)idx * 8) = o;
  } else if (idx < NXV + NW) {
    int i = idx - NXV;
    int n = i >> 10, k = i & 1023;
    w1t[i] = f2bf(w1[k * HID_ + n]);
  } else if (idx < NXV + 2 * NW) {
    int i = idx - NXV - NW;
    int n = i >> 10, k = i & 1023;
    float v = w2[k * HID_ + n];
    unsigned short h = f2bf(v);
    w2t_hi[i] = h;
    w2t_lo[i] = f2bf(v - bf2f(h));
  }
}

// ---------------------------------------------------------------------------
// Kernel A: per-head QKV projection + bias + rotary. (unchanged, proven)
// ---------------------------------------------------------------------------
__global__ __launch_bounds__(256) void qkv_kernel(
    const float* __restrict__ x, const float* __restrict__ wq,
    const float* __restrict__ bq, const float* __restrict__ wk,
    const float* __restrict__ bk, const float* __restrict__ wv,
    const float* __restrict__ theta,
    unsigned short* __restrict__ q_h, unsigned short* __restrict__ q_l,
    unsigned short* __restrict__ k_h, unsigned short* __restrict__ k_l,
    unsigned short* __restrict__ v_th, unsigned short* __restrict__ v_tl,
    int b) {
  __shared__ __align__(16) float xs[64 * 68];
  __shared__ __align__(16) float wqs[64 * 68];
  __shared__ __align__(16) float wks[64 * 68];
  __shared__ __align__(16) float wvs[64 * 68];

  int tid = threadIdx.x;
  int st = blockIdx.x, h = blockIdx.y;
  int s0 = st * 64;

#pragma unroll
  for (int i = 0; i < 4; ++i) {
    int cid = tid + i * 256;
    int r = cid >> 4, c4 = (cid & 15) * 4;
    *reinterpret_cast<float4v*>(&xs[r * 68 + c4]) =
        *reinterpret_cast<const float4v*>(x + ((size_t)(b * S_ + s0 + r)) * HID_ + h * DH_ + c4);
  }
#pragma unroll
  for (int i = 0; i < 4; ++i) {
    int cid = tid + i * 256;
    int d = cid >> 4, c4 = (cid & 15) * 4;
    *reinterpret_cast<float4v*>(&wqs[d * 68 + c4]) =
        *reinterpret_cast<const float4v*>(wq + (size_t)(h * DH_ + d) * DH_ + c4);
    *reinterpret_cast<float4v*>(&wks[d * 68 + c4]) =
        *reinterpret_cast<const float4v*>(wk + (size_t)(h * DH_ + d) * DH_ + c4);
    *reinterpret_cast<float4v*>(&wvs[d * 68 + c4]) =
        *reinterpret_cast<const float4v*>(wv + (size_t)(h * DH_ + d) * DH_ + c4);
  }
  __syncthreads();

  int rg = tid >> 3;
  int cg = tid & 7;
  int r0 = rg * 2, c0 = cg * 8;

  float aq[2][8], ak[2][8], av[2][8];
#pragma unroll
  for (int i = 0; i < 2; ++i)
#pragma unroll
    for (int j = 0; j < 8; ++j) { aq[i][j] = 0.f; ak[i][j] = 0.f; av[i][j] = 0.f; }

  for (int d = 0; d < 64; ++d) {
    float x0 = xs[(r0 + 0) * 68 + d];
    float x1 = xs[(r0 + 1) * 68 + d];
#pragma unroll
    for (int j = 0; j < 8; ++j) {
      float wqv = wqs[d * 68 + c0 + j];
      float wkv = wks[d * 68 + c0 + j];
      float wvv = wvs[d * 68 + c0 + j];
      aq[0][j] += x0 * wqv; aq[1][j] += x1 * wqv;
      ak[0][j] += x0 * wkv; ak[1][j] += x1 * wkv;
      av[0][j] += x0 * wvv; av[1][j] += x1 * wvv;
    }
  }

  float thv[8], bqv[8], bkv[8];
#pragma unroll
  for (int j = 0; j < 8; ++j) {
    thv[j] = theta[h * DH_ + c0 + j];
    bqv[j] = bq[h * DH_ + c0 + j];
    bkv[j] = bk[h * DH_ + c0 + j];
  }

  // Reuse xs/wqs LDS as bf16 V-transpose staging (all reads of them are done).
  __syncthreads();
  unsigned short* VtH = reinterpret_cast<unsigned short*>(xs);   // [64 d][72]
  unsigned short* VtL = reinterpret_cast<unsigned short*>(wqs);  // [64 d][72]

#pragma unroll
  for (int i = 0; i < 2; ++i) {
    int s = s0 + r0 + i;
    size_t qb = ((size_t)h * S_ + s) * 128;
    ushort8 qch, qcl, qsh, qsl, kch, kcl, ksh, ksl;
#pragma unroll
    for (int j = 0; j < 8; ++j) {
      float q = aq[i][j] + bqv[j];
      float k = ak[i][j] + bkv[j];
      float ang = (float)s * thv[j];
      float cs = cosf(ang), sn = sinf(ang);
      float qc = q * cs, qs = q * sn;
      unsigned short hq1 = f2bf(qc);
      qch[j] = hq1;
      qcl[j] = f2bf(qc - bf2f(hq1));
      unsigned short hq2 = f2bf(qs);
      qsh[j] = hq2;
      qsl[j] = f2bf(qs - bf2f(hq2));
      float kc = k * cs, ksn = k * sn;
      unsigned short h1 = f2bf(kc);
      kch[j] = h1;
      kcl[j] = f2bf(kc - bf2f(h1));
      unsigned short h2 = f2bf(ksn);
      ksh[j] = h2;
      ksl[j] = f2bf(ksn - bf2f(h2));
      float vv = av[i][j];
      unsigned short vh1 = f2bf(vv);
      VtH[(c0 + j) * 72 + (r0 + i)] = vh1;
      VtL[(c0 + j) * 72 + (r0 + i)] = f2bf(vv - bf2f(vh1));
    }
    *reinterpret_cast<ushort8*>(q_h + qb + c0) = qch;
    *reinterpret_cast<ushort8*>(q_h + qb + 64 + c0) = qsh;
    *reinterpret_cast<ushort8*>(q_l + qb + c0) = qcl;
    *reinterpret_cast<ushort8*>(q_l + qb + 64 + c0) = qsl;
    *reinterpret_cast<ushort8*>(k_h + qb + c0) = kch;
    *reinterpret_cast<ushort8*>(k_h + qb + 64 + c0) = ksh;
    *reinterpret_cast<ushort8*>(k_l + qb + c0) = kcl;
    *reinterpret_cast<ushort8*>(k_l + qb + 64 + c0) = ksl;
  }
  __syncthreads();
  // Coalesced transposed store: v_t[h][d][S]
#pragma unroll
  for (int i = 0; i < 2; ++i) {
    int cid = tid + i * 256;
    int d = cid >> 3, t8 = (cid & 7) * 8;
    size_t gb = ((size_t)(h * 64 + d)) * S_ + s0 + t8;
    *reinterpret_cast<ushort8*>(v_th + gb) = *reinterpret_cast<const ushort8*>(&VtH[d * 72 + t8]);
    *reinterpret_cast<ushort8*>(v_tl + gb) = *reinterpret_cast<const ushort8*>(&VtL[d * 72 + t8]);
  }
}

// ---------------------------------------------------------------------------
// Kernel B: retention v8 (r11/r12, passing: 60.0 µs) — unchanged.
// ---------------------------------------------------------------------------
#define SCOFF(row, colb)   ((row) * 256 + ((colb) ^ (((row) & 7) << 4)))

__global__ __launch_bounds__(256) void retention_split_kernel(
    const unsigned short* __restrict__ q_h, const unsigned short* __restrict__ q_l,
    const unsigned short* __restrict__ k_h, const unsigned short* __restrict__ k_l,
    const unsigned short* __restrict__ v_th, const unsigned short* __restrict__ v_tl,
    float* __restrict__ partial) {
  __shared__ __align__(16) unsigned short Kh[64 * 128];     // 16 KiB swizzled
  __shared__ __align__(16) unsigned short Kl[64 * 128];     // 16 KiB
  __shared__ __align__(16) unsigned short Vh[2][64 * 64];   // 16 KiB [d][t] dbuf
  __shared__ __align__(16) unsigned short Vl[2][64 * 64];   // 16 KiB
  __shared__ __align__(16) float Sc[64 * 64];               // 16 KiB swizzled

  char* KhB = (char*)Kh;
  char* KlB = (char*)Kl;
  char* VhB = (char*)Vh;
  char* VlB = (char*)Vl;
  char* ScB = (char*)Sc;

  int tid = threadIdx.x;
  int w = tid >> 6;
  int lane = tid & 63, ln = lane & 15, quad = lane >> 4;
  int wr = w >> 1, wc = w & 1;
  // Decode (bijective on [0,1024)): xcd-affine h, half bit, heavy-first qt.
  int f = blockIdx.x;
  int h = ((f & 7) << 1) | ((f >> 3) & 1);
  int half = (f >> 4) & 1;
  int qt = 31 - (f >> 5);
  int s0 = qt * 64;

  // kt range for this half: [kt0, kt1). m = ceil((qt+1)/2).
  int m = (qt + 2) >> 1;
  int kt0 = half ? m : 0;
  int kt1 = half ? (qt + 1) : m;

  const float lo_c = -6.2383246250395075f, hi_c = -3.4657359027997265f;
  float gam = 1.f - __expf(lo_c + (hi_c - lo_c) * ((float)h * (1.f / 15.f)));
  float logg = __logf(gam);

  // Factored decay (same integer exp arguments as r6/r9 -> identical values).
  float rowf[2][4], colf[2];
#pragma unroll
  for (int rt = 0; rt < 2; ++rt)
#pragma unroll
    for (int rr = 0; rr < 4; ++rr)
      rowf[rt][rr] = __expf((float)(wr * 32 + rt * 16 + quad * 4 + rr) * logg);
#pragma unroll
  for (int ns = 0; ns < 2; ++ns)
    colf[ns] = __expf(-(float)(wc * 32 + ns * 16 + ln) * logg);

  const unsigned short* khb = k_h + (size_t)h * S_ * 128;
  const unsigned short* klb = k_l + (size_t)h * S_ * 128;
  const unsigned short* vhb = v_th + (size_t)h * 64 * S_;
  const unsigned short* vlb = v_tl + (size_t)h * 64 * S_;

  // Q fragments (A-layout), 2 row-tiles, precomputed bf16 hi/lo.
  short8 qfh[2][4], qfl[2][4];
#pragma unroll
  for (int rt = 0; rt < 2; ++rt) {
    int sQ = s0 + wr * 32 + rt * 16 + ln;
    const unsigned short* qhp = q_h + ((size_t)h * S_ + sQ) * 128 + quad * 8;
    const unsigned short* qlp = q_l + ((size_t)h * S_ + sQ) * 128 + quad * 8;
#pragma unroll
    for (int c = 0; c < 4; ++c) {
      qfh[rt][c] = *reinterpret_cast<const short8*>(qhp + c * 32);
      qfl[rt][c] = *reinterpret_cast<const short8*>(qlp + c * 32);
    }
  }

  floatx4 accO[4];
#pragma unroll
  for (int i = 0; i < 4; ++i) accO[i] = (floatx4){0.f, 0.f, 0.f, 0.f};

  // Prologue: stage tile kt0 -> K + V[0]; prefetch kt0+1 into regs.
  ushort8 skh[4], skl[4], svh[2], svl[2];
  {
    int t00 = kt0 * 64;
#pragma unroll
    for (int i = 0; i < 4; ++i) {
      int cid = tid + i * 256;
      int r = cid >> 4, c8 = (cid & 15) * 8;
      skh[i] = *reinterpret_cast<const ushort8*>(khb + ((size_t)(t00 + r)) * 128 + c8);
      skl[i] = *reinterpret_cast<const ushort8*>(klb + ((size_t)(t00 + r)) * 128 + c8);
    }
#pragma unroll
    for (int i = 0; i < 2; ++i) {
      int cid = tid + i * 256;
      int d = cid >> 3, t8 = (cid & 7) * 8;
      svh[i] = *reinterpret_cast<const ushort8*>(vhb + (size_t)d * S_ + t00 + t8);
      svl[i] = *reinterpret_cast<const ushort8*>(vlb + (size_t)d * S_ + t00 + t8);
    }
#pragma unroll
    for (int i = 0; i < 4; ++i) {
      int cid = tid + i * 256;
      int r = cid >> 4;
      int ko = r * 256 + (((cid & 15) * 16) ^ ((r & 7) << 4));
      *reinterpret_cast<ushort8*>(KhB + ko) = skh[i];
      *reinterpret_cast<ushort8*>(KlB + ko) = skl[i];
    }
#pragma unroll
    for (int i = 0; i < 2; ++i) {
      int cid = tid + i * 256;
      int d = cid >> 3;
      int vo = d * 128 + (((cid & 7) * 16) ^ ((d & 7) << 4));  // buffer 0
      *reinterpret_cast<ushort8*>(VhB + vo) = svh[i];
      *reinterpret_cast<ushort8*>(VlB + vo) = svl[i];
    }
    if (kt0 + 1 < kt1) {
      int t01 = (kt0 + 1) * 64;
#pragma unroll
      for (int i = 0; i < 4; ++i) {
        int cid = tid + i * 256;
        int r = cid >> 4, c8 = (cid & 15) * 8;
        skh[i] = *reinterpret_cast<const ushort8*>(khb + ((size_t)(t01 + r)) * 128 + c8);
        skl[i] = *reinterpret_cast<const ushort8*>(klb + ((size_t)(t01 + r)) * 128 + c8);
      }
#pragma unroll
      for (int i = 0; i < 2; ++i) {
        int cid = tid + i * 256;
        int d = cid >> 3, t8 = (cid & 7) * 8;
        svh[i] = *reinterpret_cast<const ushort8*>(vhb + (size_t)d * S_ + t01 + t8);
        svl[i] = *reinterpret_cast<const ushort8*>(vlb + (size_t)d * S_ + t01 + t8);
      }
    }
  }
  __syncthreads();

  for (int kt = kt0; kt < kt1; ++kt) {
    int vb = (kt - kt0) & 1;
    // QK^T split-MFMA, 2x2 quadrant — setprio'd cluster.
    floatx4 accS[2][2];
#pragma unroll
    for (int rt = 0; rt < 2; ++rt)
#pragma unroll
      for (int ns = 0; ns < 2; ++ns) accS[rt][ns] = (floatx4){0.f, 0.f, 0.f, 0.f};
    __builtin_amdgcn_s_setprio(1);
#pragma unroll
    for (int ns = 0; ns < 2; ++ns) {
      int krow = wc * 32 + ns * 16 + ln;
#pragma unroll
      for (int ks = 0; ks < 4; ++ks) {
        int off = krow * 256 + ((ks * 64 + quad * 16) ^ ((ln & 7) << 4));
        short8 kh = *reinterpret_cast<const short8*>(KhB + off);
        short8 kl = *reinterpret_cast<const short8*>(KlB + off);
#pragma unroll
        for (int rt = 0; rt < 2; ++rt) {
          accS[rt][ns] = __builtin_amdgcn_mfma_f32_16x16x32_bf16(qfh[rt][ks], kh, accS[rt][ns], 0, 0, 0);
          accS[rt][ns] = __builtin_amdgcn_mfma_f32_16x16x32_bf16(qfl[rt][ks], kh, accS[rt][ns], 0, 0, 0);
          accS[rt][ns] = __builtin_amdgcn_mfma_f32_16x16x32_bf16(qfh[rt][ks], kl, accS[rt][ns], 0, 0, 0);
        }
      }
    }
    __builtin_amdgcn_s_setprio(0);

    // Factored decay (+ causal select only on the diagonal tile) -> Sc.
    float tf = __expf((float)(64 * (qt - kt)) * logg);
    float trf[2][4];
#pragma unroll
    for (int rt = 0; rt < 2; ++rt)
#pragma unroll
      for (int rr = 0; rr < 4; ++rr) trf[rt][rr] = tf * rowf[rt][rr];
    if (kt < qt) {
#pragma unroll
      for (int rt = 0; rt < 2; ++rt)
#pragma unroll
        for (int ns = 0; ns < 2; ++ns) {
          int col = wc * 32 + ns * 16 + ln;
#pragma unroll
          for (int rr = 0; rr < 4; ++rr) {
            int row = wr * 32 + rt * 16 + quad * 4 + rr;
            *reinterpret_cast<float*>(ScB + SCOFF(row, col * 4)) =
                accS[rt][ns][rr] * trf[rt][rr] * colf[ns];
          }
        }
    } else {
#pragma unroll
      for (int rt = 0; rt < 2; ++rt)
#pragma unroll
        for (int ns = 0; ns < 2; ++ns) {
          int col = wc * 32 + ns * 16 + ln;
#pragma unroll
          for (int rr = 0; rr < 4; ++rr) {
            int row = wr * 32 + rt * 16 + quad * 4 + rr;
            float v = accS[rt][ns][rr] * trf[rt][rr] * colf[ns];
            *reinterpret_cast<float*>(ScB + SCOFF(row, col * 4)) =
                (row >= col) ? v : 0.f;
          }
        }
    }
    __syncthreads();  // B1: Sc visible; all K reads AND V[vb^1] reads done

    // Staged writes overlap PV: K (single buffer, reads finished at B1) and
    // V[next] into the alternate buffer. Then issue kt+2 prefetch.
    if (kt + 1 < kt1) {
#pragma unroll
      for (int i = 0; i < 4; ++i) {
        int cid = tid + i * 256;
        int r = cid >> 4;
        int ko = r * 256 + (((cid & 15) * 16) ^ ((r & 7) << 4));
        *reinterpret_cast<ushort8*>(KhB + ko) = skh[i];
        *reinterpret_cast<ushort8*>(KlB + ko) = skl[i];
      }
#pragma unroll
      for (int i = 0; i < 2; ++i) {
        int cid = tid + i * 256;
        int d = cid >> 3;
        int vo = (vb ^ 1) * 8192 + d * 128 + (((cid & 7) * 16) ^ ((d & 7) << 4));
        *reinterpret_cast<ushort8*>(VhB + vo) = svh[i];
        *reinterpret_cast<ushort8*>(VlB + vo) = svl[i];
      }
      if (kt + 2 < kt1) {
        int t0n = (kt + 2) * 64;
#pragma unroll
        for (int i = 0; i < 4; ++i) {
          int cid = tid + i * 256;
          int r = cid >> 4, c8 = (cid & 15) * 8;
          skh[i] = *reinterpret_cast<const ushort8*>(khb + ((size_t)(t0n + r)) * 128 + c8);
          skl[i] = *reinterpret_cast<const ushort8*>(klb + ((size_t)(t0n + r)) * 128 + c8);
        }
#pragma unroll
        for (int i = 0; i < 2; ++i) {
          int cid = tid + i * 256;
          int d = cid >> 3, t8 = (cid & 7) * 8;
          svh[i] = *reinterpret_cast<const ushort8*>(vhb + (size_t)d * S_ + t0n + t8);
          svl[i] = *reinterpret_cast<const ushort8*>(vlb + (size_t)d * S_ + t0n + t8);
        }
      }
    }

    // PV split-MFMA: reads Sc + V[vb] (disjoint from the writes above).
    __builtin_amdgcn_s_setprio(1);
#pragma unroll
    for (int ks = 0; ks < 2; ++ks) {
      int prw = w * 16 + ln;
      int cb = ks * 128 + quad * 32;
      float4v p0 = *reinterpret_cast<const float4v*>(ScB + SCOFF(prw, cb));
      float4v p1 = *reinterpret_cast<const float4v*>(ScB + SCOFF(prw, cb + 16));
      short8 ph, pl;
#pragma unroll
      for (int j = 0; j < 4; ++j) {
        unsigned short hh = f2bf(p0[j]);
        ph[j] = (short)hh;
        pl[j] = (short)f2bf(p0[j] - bf2f(hh));
        unsigned short hh2 = f2bf(p1[j]);
        ph[4 + j] = (short)hh2;
        pl[4 + j] = (short)f2bf(p1[j] - bf2f(hh2));
      }
#pragma unroll
      for (int ds = 0; ds < 4; ++ds) {
        int d = ds * 16 + ln;
        int voff = vb * 8192 + d * 128 + ((ks * 64 + quad * 16) ^ ((ln & 7) << 4));
        short8 vh = *reinterpret_cast<const short8*>(VhB + voff);
        short8 vl = *reinterpret_cast<const short8*>(VlB + voff);
        accO[ds] = __builtin_amdgcn_mfma_f32_16x16x32_bf16(ph, vh, accO[ds], 0, 0, 0);
        accO[ds] = __builtin_amdgcn_mfma_f32_16x16x32_bf16(pl, vh, accO[ds], 0, 0, 0);
        accO[ds] = __builtin_amdgcn_mfma_f32_16x16x32_bf16(ph, vl, accO[ds], 0, 0, 0);
      }
    }
    __builtin_amdgcn_s_setprio(0);

    __syncthreads();  // B2: PV reads done; staged K/V writes visible
  }

  // Epilogue: store raw fp32 partial accO (16 KB/block).
  float* pout = partial + ((size_t)(((h * 32 + qt) << 1) + half)) * 4096;
#pragma unroll
  for (int ds = 0; ds < 4; ++ds) {
#pragma unroll
    for (int rr = 0; rr < 4; ++rr) {
      pout[(w * 16 + quad * 4 + rr) * 64 + ds * 16 + ln] = accO[ds][rr];
    }
  }
}

// ---------------------------------------------------------------------------
// Kernel B2: combine halves + GroupNorm (proven).
// ---------------------------------------------------------------------------
__global__ __launch_bounds__(256) void combine_gn_kernel(
    const float* __restrict__ partial, const float* __restrict__ gn_w,
    const float* __restrict__ gn_b, float* __restrict__ retn, int b) {
  __shared__ float gnred[64][8];
  int tid = threadIdx.x;
  int qi = blockIdx.x;            // qi = h*32 + qt
  int h = qi >> 5, qt = qi & 31;
  const float* p0 = partial + (size_t)qi * 8192;
  const float* p1 = p0 + 4096;

  int r2 = tid >> 2;
  int sub = tid & 3;
  float a16[16];
#pragma unroll
  for (int c = 0; c < 4; ++c) {
    int o = r2 * 64 + sub * 16 + c * 4;
    float4v va = *reinterpret_cast<const float4v*>(p0 + o);
    float4v vb = *reinterpret_cast<const float4v*>(p1 + o);
#pragma unroll
    for (int j = 0; j < 4; ++j) a16[c * 4 + j] = va[j] + vb[j];
  }

  float psum = 0.f, psq = 0.f;
#pragma unroll
  for (int i = 0; i < 16; ++i) { psum += a16[i]; psq += a16[i] * a16[i]; }
  gnred[r2][sub] = psum;
  gnred[r2][4 + sub] = psq;
  __syncthreads();
  float sum = gnred[r2][0] + gnred[r2][1] + gnred[r2][2] + gnred[r2][3];
  float sq = gnred[r2][4] + gnred[r2][5] + gnred[r2][6] + gnred[r2][7];
  float mean = sum * (1.f / 64.f);
  float var = sq * (1.f / 64.f) - mean * mean;
  float rstd = rsqrtf(var + 1e-5f);

  size_t obase = ((size_t)(b * S_ + qt * 64 + r2)) * HID_ + h * DH_ + sub * 16;
#pragma unroll
  for (int i = 0; i < 16; ++i) {
    float gw = gn_w[h * DH_ + sub * 16 + i];
    float gb = gn_b[h * DH_ + sub * 16 + i];
    retn[obase + i] = (a16[i] - mean) * rstd * gw + gb;
  }
}

// ---------------------------------------------------------------------------
// GEMM 1 (gate): r10 config (BM128/BN64/BK32, acc[4][2], reg prefetch — the
// proven best) + LDS double-buffer -> ONE barrier per K-step (64 -> 33).
// LDS 43 KiB, 2 blocks/CU. Same k accumulation order -> bit-identical.
// ---------------------------------------------------------------------------
__global__ __launch_bounds__(256) void gemm_gate_kernel(
    const unsigned short* __restrict__ A, const unsigned short* __restrict__ Bt,
    const float* __restrict__ retn, unsigned short* __restrict__ pre_hi,
    unsigned short* __restrict__ pre_lo) {
  const int K = HID_;
  __shared__ __align__(16) unsigned short Al[2][128 * 56];  // 28.7 KiB
  __shared__ __align__(16) unsigned short Bl[2][64 * 56];   // 14.3 KiB

  int tid = threadIdx.x;
  int lane = tid & 63, ln = lane & 15, quad = lane >> 4;
  int w = tid >> 6, wm = w >> 1, wn = w & 1;
  int m0 = blockIdx.y * 128, n0 = blockIdx.x * 64;

  floatx4 acc[4][2];
#pragma unroll
  for (int i = 0; i < 4; ++i)
#pragma unroll
    for (int j = 0; j < 2; ++j) acc[i][j] = (floatx4){0.f, 0.f, 0.f, 0.f};

  int ra_r[2], ra_c[2], rb_r, rb_c;
#pragma unroll
  for (int i = 0; i < 2; ++i) {
    int cid = tid + i * 256;
    ra_r[i] = cid >> 2; ra_c[i] = (cid & 3) * 8;
  }
  rb_r = tid >> 2; rb_c = (tid & 3) * 8;

  // Prologue: tile0 -> buf0; tile1 -> regs.
  ushort8 ra[2], rb;
#pragma unroll
  for (int i = 0; i < 2; ++i)
    ra[i] = *reinterpret_cast<const ushort8*>(A + (size_t)(m0 + ra_r[i]) * K + ra_c[i]);
  rb = *reinterpret_cast<const ushort8*>(Bt + (size_t)(n0 + rb_r) * K + rb_c);
#pragma unroll
  for (int i = 0; i < 2; ++i)
    *reinterpret_cast<ushort8*>(&Al[0][ra_r[i] * 56 + ra_c[i]]) = ra[i];
  *reinterpret_cast<ushort8*>(&Bl[0][rb_r * 56 + rb_c]) = rb;
#pragma unroll
  for (int i = 0; i < 2; ++i)
    ra[i] = *reinterpret_cast<const ushort8*>(A + (size_t)(m0 + ra_r[i]) * K + 32 + ra_c[i]);
  rb = *reinterpret_cast<const ushort8*>(Bt + (size_t)(n0 + rb_r) * K + 32 + rb_c);
  __syncthreads();

  for (int k0 = 0; k0 < K; k0 += 32) {
    int cur = (k0 >> 5) & 1;
    if (k0 + 32 < K) {
      int nx = cur ^ 1;
      // Write tile k+1 into alternate buffer (its readers finished at the
      // previous barrier); overlaps the MFMA compute below.
#pragma unroll
      for (int i = 0; i < 2; ++i)
        *reinterpret_cast<ushort8*>(&Al[nx][ra_r[i] * 56 + ra_c[i]]) = ra[i];
      *reinterpret_cast<ushort8*>(&Bl[nx][rb_r * 56 + rb_c]) = rb;
      if (k0 + 64 < K) {
#pragma unroll
        for (int i = 0; i < 2; ++i)
          ra[i] = *reinterpret_cast<const ushort8*>(A + (size_t)(m0 + ra_r[i]) * K + k0 + 64 + ra_c[i]);
        rb = *reinterpret_cast<const ushort8*>(Bt + (size_t)(n0 + rb_r) * K + k0 + 64 + rb_c);
      }
    }

    short8 af[4], bfr[2];
#pragma unroll
    for (int i = 0; i < 4; ++i)
      af[i] = *reinterpret_cast<const short8*>(&Al[cur][(wm * 64 + i * 16 + ln) * 56 + quad * 8]);
#pragma unroll
    for (int i = 0; i < 2; ++i)
      bfr[i] = *reinterpret_cast<const short8*>(&Bl[cur][(wn * 32 + i * 16 + ln) * 56 + quad * 8]);
#pragma unroll
    for (int mi = 0; mi < 4; ++mi)
#pragma unroll
      for (int ni = 0; ni < 2; ++ni)
        acc[mi][ni] = __builtin_amdgcn_mfma_f32_16x16x32_bf16(af[mi], bfr[ni], acc[mi][ni], 0, 0, 0);
    __syncthreads();  // writes to buf^1 visible; reads of buf done
  }

#pragma unroll
  for (int mi = 0; mi < 4; ++mi) {
#pragma unroll
    for (int r = 0; r < 4; ++r) {
      int row = m0 + wm * 64 + mi * 16 + quad * 4 + r;
#pragma unroll
      for (int ni = 0; ni < 2; ++ni) {
        int col = n0 + wn * 32 + ni * 16 + ln;
        float g = acc[mi][ni][r];
        float val = g * (1.f / (1.f + __expf(-g))) + retn[(size_t)row * HID_ + col];
        unsigned short hh = f2bf(val);
        size_t oidx = (size_t)row * HID_ + col;
        pre_hi[oidx] = hh;
        pre_lo[oidx] = f2bf(val - bf2f(hh));
      }
    }
  }
}

// ---------------------------------------------------------------------------
// GEMM 2 (output): r10 config exactly (BM128/BN64/BK32, acc[4][2], register
// prefetch, 2 barriers) — the proven best; dbuf would exceed the 2-block/CU
// LDS budget.
// ---------------------------------------------------------------------------
__global__ __launch_bounds__(256) void gemm_out_kernel(
    const unsigned short* __restrict__ Ah, const unsigned short* __restrict__ Alo,
    const unsigned short* __restrict__ Bth, const unsigned short* __restrict__ Btlo,
    float* __restrict__ out_f) {
  const int K = HID_;
  __shared__ __align__(16) unsigned short AhS[128 * 56];
  __shared__ __align__(16) unsigned short AlS[128 * 56];
  __shared__ __align__(16) unsigned short BhS[64 * 56];
  __shared__ __align__(16) unsigned short BlS[64 * 56];

  int tid = threadIdx.x;
  int lane = tid & 63, ln = lane & 15, quad = lane >> 4;
  int w = tid >> 6, wm = w >> 1, wn = w & 1;
  int m0 = blockIdx.y * 128, n0 = blockIdx.x * 64;

  floatx4 acc[4][2];
#pragma unroll
  for (int i = 0; i < 4; ++i)
#pragma unroll
    for (int j = 0; j < 2; ++j) acc[i][j] = (floatx4){0.f, 0.f, 0.f, 0.f};

  int ra_r[2], ra_c[2], rb_r, rb_c;
#pragma unroll
  for (int i = 0; i < 2; ++i) {
    int cid = tid + i * 256;
    ra_r[i] = cid >> 2; ra_c[i] = (cid & 3) * 8;
  }
  rb_r = tid >> 2; rb_c = (tid & 3) * 8;

  // Prefetch tile 0.
  ushort8 rah[2], ral[2], rbh, rbl;
#pragma unroll
  for (int i = 0; i < 2; ++i) {
    size_t ga = (size_t)(m0 + ra_r[i]) * K + ra_c[i];
    rah[i] = *reinterpret_cast<const ushort8*>(Ah + ga);
    ral[i] = *reinterpret_cast<const ushort8*>(Alo + ga);
  }
  {
    size_t gb = (size_t)(n0 + rb_r) * K + rb_c;
    rbh = *reinterpret_cast<const ushort8*>(Bth + gb);
    rbl = *reinterpret_cast<const ushort8*>(Btlo + gb);
  }

  for (int k0 = 0; k0 < K; k0 += 32) {
#pragma unroll
    for (int i = 0; i < 2; ++i) {
      *reinterpret_cast<ushort8*>(&AhS[ra_r[i] * 56 + ra_c[i]]) = rah[i];
      *reinterpret_cast<ushort8*>(&AlS[ra_r[i] * 56 + ra_c[i]]) = ral[i];
    }
    *reinterpret_cast<ushort8*>(&BhS[rb_r * 56 + rb_c]) = rbh;
    *reinterpret_cast<ushort8*>(&BlS[rb_r * 56 + rb_c]) = rbl;
    if (k0 + 32 < K) {
#pragma unroll
      for (int i = 0; i < 2; ++i) {
        size_t ga = (size_t)(m0 + ra_r[i]) * K + k0 + 32 + ra_c[i];
        rah[i] = *reinterpret_cast<const ushort8*>(Ah + ga);
        ral[i] = *reinterpret_cast<const ushort8*>(Alo + ga);
      }
      size_t gb = (size_t)(n0 + rb_r) * K + k0 + 32 + rb_c;
      rbh = *reinterpret_cast<const ushort8*>(Bth + gb);
      rbl = *reinterpret_cast<const ushort8*>(Btlo + gb);
    }
    __syncthreads();

    short8 afh[4], afl[4], bfh[2], bfl[2];
#pragma unroll
    for (int i = 0; i < 4; ++i) {
      int ao = (wm * 64 + i * 16 + ln) * 56 + quad * 8;
      afh[i] = *reinterpret_cast<const short8*>(&AhS[ao]);
      afl[i] = *reinterpret_cast<const short8*>(&AlS[ao]);
    }
#pragma unroll
    for (int i = 0; i < 2; ++i) {
      int bo = (wn * 32 + i * 16 + ln) * 56 + quad * 8;
      bfh[i] = *reinterpret_cast<const short8*>(&BhS[bo]);
      bfl[i] = *reinterpret_cast<const short8*>(&BlS[bo]);
    }
#pragma unroll
    for (int mi = 0; mi < 4; ++mi)
#pragma unroll
      for (int ni = 0; ni < 2; ++ni) {
        floatx4 a = acc[mi][ni];
        a = __builtin_amdgcn_mfma_f32_16x16x32_bf16(afh[mi], bfh[ni], a, 0, 0, 0);
        a = __builtin_amdgcn_mfma_f32_16x16x32_bf16(afl[mi], bfh[ni], a, 0, 0, 0);
        a = __builtin_amdgcn_mfma_f32_16x16x32_bf16(afh[mi], bfl[ni], a, 0, 0, 0);
        acc[mi][ni] = a;
      }
    __syncthreads();
  }

#pragma unroll
  for (int mi = 0; mi < 4; ++mi) {
#pragma unroll
    for (int r = 0; r < 4; ++r) {
      int row = m0 + wm * 64 + mi * 16 + quad * 4 + r;
#pragma unroll
      for (int ni = 0; ni < 2; ++ni) {
        int col = n0 + wn * 32 + ni * 16 + ln;
        out_f[(size_t)row * HID_ + col] = acc[mi][ni][r];
      }
    }
  }
}

// ---------------------------------------------------------------------------
extern "C" void kernel_launch(void* const* d_in, const int* in_sizes, int n_in,
                              void* d_out, int out_size, void* d_ws,
                              size_t ws_size, hipStream_t stream) {
  (void)in_sizes; (void)n_in; (void)out_size; (void)ws_size;
  const float* x = (const float*)d_in[0];
  const float* wq = (const float*)d_in[1];
  const float* bq = (const float*)d_in[2];
  const float* wk = (const float*)d_in[3];
  const float* bk = (const float*)d_in[4];
  const float* wv = (const float*)d_in[5];
  const float* theta = (const float*)d_in[6];
  const float* gn_w = (const float*)d_in[7];
  const float* gn_b = (const float*)d_in[8];
  const float* w1 = (const float*)d_in[9];
  const float* w2 = (const float*)d_in[10];

  const size_t MB = 1024 * 1024;
  char* ws = (char*)d_ws;
  unsigned short* x_bf   = (unsigned short*)(ws + 0 * MB);    //  8 MiB
  unsigned short* w1t    = (unsigned short*)(ws + 8 * MB);    //  2 MiB
  unsigned short* w2t_hi = (unsigned short*)(ws + 10 * MB);   //  2 MiB
  unsigned short* w2t_lo = (unsigned short*)(ws + 12 * MB);   //  2 MiB
  unsigned short* q_h    = (unsigned short*)(ws + 14 * MB);   //  8 MiB (1 batch)
  unsigned short* q_l    = (unsigned short*)(ws + 22 * MB);   //  8 MiB
  unsigned short* k_h    = (unsigned short*)(ws + 30 * MB);   //  8 MiB
  unsigned short* k_l    = (unsigned short*)(ws + 38 * MB);   //  8 MiB
  unsigned short* v_th   = (unsigned short*)(ws + 46 * MB);   //  4 MiB
  unsigned short* v_tl   = (unsigned short*)(ws + 50 * MB);   //  4 MiB
  float*          retn   = (float*)(ws + 54 * MB);            // 16 MiB (both batches)
  float*          partial= (float*)(ws + 70 * MB);            // 16 MiB (per batch, reused)
  unsigned short* pre_hi = (unsigned short*)(ws + 14 * MB);   //  8 MiB (alias q_h, dead by then)
  unsigned short* pre_lo = (unsigned short*)(ws + 22 * MB);   //  8 MiB (alias q_l)
  float* out = (float*)d_out;

  // convert: NX/8 vector chunks + 2*NW scalar weight elements.
  const int conv_threads = (B_ * S_ * HID_) / 8 + 2 * HID_ * HID_;
  convert_kernel<<<dim3(conv_threads / 256), 256, 0, stream>>>(
      x, w1, w2, x_bf, w1t, w2t_hi, w2t_lo);
  for (int b = 0; b < B_; ++b) {
    qkv_kernel<<<dim3(S_ / 64, H_), 256, 0, stream>>>(
        x, wq, bq, wk, bk, wv, theta, q_h, q_l, k_h, k_l, v_th, v_tl, b);
    retention_split_kernel<<<dim3(1024), 256, 0, stream>>>(
        q_h, q_l, k_h, k_l, v_th, v_tl, partial);
    combine_gn_kernel<<<dim3(512), 256, 0, stream>>>(
        partial, gn_w, gn_b, retn, b);
  }
  gemm_gate_kernel<<<dim3(HID_ / 64, (B_ * S_) / 128), 256, 0, stream>>>(
      x_bf, w1t, retn, pre_hi, pre_lo);
  gemm_out_kernel<<<dim3(HID_ / 64, (B_ * S_) / 128), 256, 0, stream>>>(
      pre_hi, pre_lo, w2t_hi, w2t_lo, out);
}

// Round 14
// 309.896 us; speedup vs baseline: 1.1831x; 1.0348x over previous
//
#include <hip/hip_runtime.h>
#include <cstdint>
#include <cstddef>

#define B_ 2
#define S_ 2048
#define HID_ 1024
#define H_ 16
#define DH_ 64

typedef __attribute__((ext_vector_type(8))) short short8;
typedef __attribute__((ext_vector_type(8))) unsigned short ushort8;
typedef __attribute__((ext_vector_type(4))) unsigned short ushort4v;
typedef __attribute__((ext_vector_type(4))) float floatx4;
typedef __attribute__((ext_vector_type(4))) float float4v;

static __device__ __forceinline__ unsigned short f2bf(float f) {
  unsigned int u = __float_as_uint(f);
  u += 0x7fffu + ((u >> 16) & 1u);
  return (unsigned short)(u >> 16);
}
static __device__ __forceinline__ float bf2f(unsigned short h) {
  return __uint_as_float(((unsigned int)h) << 16);
}

// ---------------------------------------------------------------------------
// Kernel 0a: x -> bf16, vectorized x8 (r13, passing).
// ---------------------------------------------------------------------------
__global__ __launch_bounds__(256) void convert_x_kernel(
    const float* __restrict__ x, unsigned short* __restrict__ x_bf) {
  int idx = blockIdx.x * 256 + threadIdx.x;  // < NX/8 = 524288
  const float4v* xp = reinterpret_cast<const float4v*>(x + (size_t)idx * 8);
  float4v a = xp[0], b = xp[1];
  ushort8 o;
  o[0] = f2bf(a[0]); o[1] = f2bf(a[1]); o[2] = f2bf(a[2]); o[3] = f2bf(a[3]);
  o[4] = f2bf(b[0]); o[5] = f2bf(b[1]); o[6] = f2bf(b[2]); o[7] = f2bf(b[3]);
  *reinterpret_cast<ushort8*>(x_bf + (size_t)idx * 8) = o;
}

// ---------------------------------------------------------------------------
// Kernel 0b: weight transpose via LDS tiles (fixes the 16x over-fetch of the
// old strided reads). 64x64 tile, stride-65 pad (2-way banks both phases),
// coalesced reads AND writes. Same f2bf per element -> bit-identical.
// blocks 0..255 -> w1 (bf16), 256..511 -> w2 (hi/lo split).
// ---------------------------------------------------------------------------
__global__ __launch_bounds__(256) void transpose_w_kernel(
    const float* __restrict__ w1, const float* __restrict__ w2,
    unsigned short* __restrict__ w1t, unsigned short* __restrict__ w2t_hi,
    unsigned short* __restrict__ w2t_lo) {
  __shared__ float tile[64 * 65];
  int bid = blockIdx.x;
  int isw2 = bid >> 8;
  int tb = bid & 255;
  int tr = (tb >> 4) * 64;  // k-block in source
  int tc = (tb & 15) * 64;  // n-block in source
  const float* src = isw2 ? w2 : w1;
  int tid = threadIdx.x;
  int rg = tid >> 4, cg = (tid & 15) * 4;

#pragma unroll
  for (int i = 0; i < 4; ++i) {
    int r = rg + i * 16;
    const float* s = src + (size_t)(tr + r) * HID_ + tc + cg;
    tile[r * 65 + cg + 0] = s[0];
    tile[r * 65 + cg + 1] = s[1];
    tile[r * 65 + cg + 2] = s[2];
    tile[r * 65 + cg + 3] = s[3];
  }
  __syncthreads();

#pragma unroll
  for (int i = 0; i < 4; ++i) {
    int rn = rg + i * 16;                    // n within tile
    size_t ob = (size_t)(tc + rn) * HID_ + tr + cg;
    float v0 = tile[(cg + 0) * 65 + rn];
    float v1 = tile[(cg + 1) * 65 + rn];
    float v2 = tile[(cg + 2) * 65 + rn];
    float v3 = tile[(cg + 3) * 65 + rn];
    if (!isw2) {
      ushort4v o;
      o[0] = f2bf(v0); o[1] = f2bf(v1); o[2] = f2bf(v2); o[3] = f2bf(v3);
      *reinterpret_cast<ushort4v*>(w1t + ob) = o;
    } else {
      ushort4v hi, lo;
      hi[0] = f2bf(v0); lo[0] = f2bf(v0 - bf2f(hi[0]));
      hi[1] = f2bf(v1); lo[1] = f2bf(v1 - bf2f(hi[1]));
      hi[2] = f2bf(v2); lo[2] = f2bf(v2 - bf2f(hi[2]));
      hi[3] = f2bf(v3); lo[3] = f2bf(v3 - bf2f(hi[3]));
      *reinterpret_cast<ushort4v*>(w2t_hi + ob) = hi;
      *reinterpret_cast<ushort4v*>(w2t_lo + ob) = lo;
    }
  }
}

// ---------------------------------------------------------------------------
// Kernel A: per-head QKV projection + bias + rotary. (unchanged, proven)
// ---------------------------------------------------------------------------
__global__ __launch_bounds__(256) void qkv_kernel(
    const float* __restrict__ x, const float* __restrict__ wq,
    const float* __restrict__ bq, const float* __restrict__ wk,
    const float* __restrict__ bk, const float* __restrict__ wv,
    const float* __restrict__ theta,
    unsigned short* __restrict__ q_h, unsigned short* __restrict__ q_l,
    unsigned short* __restrict__ k_h, unsigned short* __restrict__ k_l,
    unsigned short* __restrict__ v_th, unsigned short* __restrict__ v_tl,
    int b) {
  __shared__ __align__(16) float xs[64 * 68];
  __shared__ __align__(16) float wqs[64 * 68];
  __shared__ __align__(16) float wks[64 * 68];
  __shared__ __align__(16) float wvs[64 * 68];

  int tid = threadIdx.x;
  int st = blockIdx.x, h = blockIdx.y;
  int s0 = st * 64;

#pragma unroll
  for (int i = 0; i < 4; ++i) {
    int cid = tid + i * 256;
    int r = cid >> 4, c4 = (cid & 15) * 4;
    *reinterpret_cast<float4v*>(&xs[r * 68 + c4]) =
        *reinterpret_cast<const float4v*>(x + ((size_t)(b * S_ + s0 + r)) * HID_ + h * DH_ + c4);
  }
#pragma unroll
  for (int i = 0; i < 4; ++i) {
    int cid = tid + i * 256;
    int d = cid >> 4, c4 = (cid & 15) * 4;
    *reinterpret_cast<float4v*>(&wqs[d * 68 + c4]) =
        *reinterpret_cast<const float4v*>(wq + (size_t)(h * DH_ + d) * DH_ + c4);
    *reinterpret_cast<float4v*>(&wks[d * 68 + c4]) =
        *reinterpret_cast<const float4v*>(wk + (size_t)(h * DH_ + d) * DH_ + c4);
    *reinterpret_cast<float4v*>(&wvs[d * 68 + c4]) =
        *reinterpret_cast<const float4v*>(wv + (size_t)(h * DH_ + d) * DH_ + c4);
  }
  __syncthreads();

  int rg = tid >> 3;
  int cg = tid & 7;
  int r0 = rg * 2, c0 = cg * 8;

  float aq[2][8], ak[2][8], av[2][8];
#pragma unroll
  for (int i = 0; i < 2; ++i)
#pragma unroll
    for (int j = 0; j < 8; ++j) { aq[i][j] = 0.f; ak[i][j] = 0.f; av[i][j] = 0.f; }

  for (int d = 0; d < 64; ++d) {
    float x0 = xs[(r0 + 0) * 68 + d];
    float x1 = xs[(r0 + 1) * 68 + d];
#pragma unroll
    for (int j = 0; j < 8; ++j) {
      float wqv = wqs[d * 68 + c0 + j];
      float wkv = wks[d * 68 + c0 + j];
      float wvv = wvs[d * 68 + c0 + j];
      aq[0][j] += x0 * wqv; aq[1][j] += x1 * wqv;
      ak[0][j] += x0 * wkv; ak[1][j] += x1 * wkv;
      av[0][j] += x0 * wvv; av[1][j] += x1 * wvv;
    }
  }

  float thv[8], bqv[8], bkv[8];
#pragma unroll
  for (int j = 0; j < 8; ++j) {
    thv[j] = theta[h * DH_ + c0 + j];
    bqv[j] = bq[h * DH_ + c0 + j];
    bkv[j] = bk[h * DH_ + c0 + j];
  }

  // Reuse xs/wqs LDS as bf16 V-transpose staging (all reads of them are done).
  __syncthreads();
  unsigned short* VtH = reinterpret_cast<unsigned short*>(xs);   // [64 d][72]
  unsigned short* VtL = reinterpret_cast<unsigned short*>(wqs);  // [64 d][72]

#pragma unroll
  for (int i = 0; i < 2; ++i) {
    int s = s0 + r0 + i;
    size_t qb = ((size_t)h * S_ + s) * 128;
    ushort8 qch, qcl, qsh, qsl, kch, kcl, ksh, ksl;
#pragma unroll
    for (int j = 0; j < 8; ++j) {
      float q = aq[i][j] + bqv[j];
      float k = ak[i][j] + bkv[j];
      float ang = (float)s * thv[j];
      float cs = cosf(ang), sn = sinf(ang);
      float qc = q * cs, qs = q * sn;
      unsigned short hq1 = f2bf(qc);
      qch[j] = hq1;
      qcl[j] = f2bf(qc - bf2f(hq1));
      unsigned short hq2 = f2bf(qs);
      qsh[j] = hq2;
      qsl[j] = f2bf(qs - bf2f(hq2));
      float kc = k * cs, ksn = k * sn;
      unsigned short h1 = f2bf(kc);
      kch[j] = h1;
      kcl[j] = f2bf(kc - bf2f(h1));
      unsigned short h2 = f2bf(ksn);
      ksh[j] = h2;
      ksl[j] = f2bf(ksn - bf2f(h2));
      float vv = av[i][j];
      unsigned short vh1 = f2bf(vv);
      VtH[(c0 + j) * 72 + (r0 + i)] = vh1;
      VtL[(c0 + j) * 72 + (r0 + i)] = f2bf(vv - bf2f(vh1));
    }
    *reinterpret_cast<ushort8*>(q_h + qb + c0) = qch;
    *reinterpret_cast<ushort8*>(q_h + qb + 64 + c0) = qsh;
    *reinterpret_cast<ushort8*>(q_l + qb + c0) = qcl;
    *reinterpret_cast<ushort8*>(q_l + qb + 64 + c0) = qsl;
    *reinterpret_cast<ushort8*>(k_h + qb + c0) = kch;
    *reinterpret_cast<ushort8*>(k_h + qb + 64 + c0) = ksh;
    *reinterpret_cast<ushort8*>(k_l + qb + c0) = kcl;
    *reinterpret_cast<ushort8*>(k_l + qb + 64 + c0) = ksl;
  }
  __syncthreads();
  // Coalesced transposed store: v_t[h][d][S]
#pragma unroll
  for (int i = 0; i < 2; ++i) {
    int cid = tid + i * 256;
    int d = cid >> 3, t8 = (cid & 7) * 8;
    size_t gb = ((size_t)(h * 64 + d)) * S_ + s0 + t8;
    *reinterpret_cast<ushort8*>(v_th + gb) = *reinterpret_cast<const ushort8*>(&VtH[d * 72 + t8]);
    *reinterpret_cast<ushort8*>(v_tl + gb) = *reinterpret_cast<const ushort8*>(&VtL[d * 72 + t8]);
  }
}

// ---------------------------------------------------------------------------
// Kernel B: retention v8 (r11-r13, passing: ~60 µs) — unchanged.
// ---------------------------------------------------------------------------
#define SCOFF(row, colb)   ((row) * 256 + ((colb) ^ (((row) & 7) << 4)))

__global__ __launch_bounds__(256) void retention_split_kernel(
    const unsigned short* __restrict__ q_h, const unsigned short* __restrict__ q_l,
    const unsigned short* __restrict__ k_h, const unsigned short* __restrict__ k_l,
    const unsigned short* __restrict__ v_th, const unsigned short* __restrict__ v_tl,
    float* __restrict__ partial) {
  __shared__ __align__(16) unsigned short Kh[64 * 128];     // 16 KiB swizzled
  __shared__ __align__(16) unsigned short Kl[64 * 128];     // 16 KiB
  __shared__ __align__(16) unsigned short Vh[2][64 * 64];   // 16 KiB [d][t] dbuf
  __shared__ __align__(16) unsigned short Vl[2][64 * 64];   // 16 KiB
  __shared__ __align__(16) float Sc[64 * 64];               // 16 KiB swizzled

  char* KhB = (char*)Kh;
  char* KlB = (char*)Kl;
  char* VhB = (char*)Vh;
  char* VlB = (char*)Vl;
  char* ScB = (char*)Sc;

  int tid = threadIdx.x;
  int w = tid >> 6;
  int lane = tid & 63, ln = lane & 15, quad = lane >> 4;
  int wr = w >> 1, wc = w & 1;
  // Decode (bijective on [0,1024)): xcd-affine h, half bit, heavy-first qt.
  int f = blockIdx.x;
  int h = ((f & 7) << 1) | ((f >> 3) & 1);
  int half = (f >> 4) & 1;
  int qt = 31 - (f >> 5);
  int s0 = qt * 64;

  // kt range for this half: [kt0, kt1). m = ceil((qt+1)/2).
  int m = (qt + 2) >> 1;
  int kt0 = half ? m : 0;
  int kt1 = half ? (qt + 1) : m;

  const float lo_c = -6.2383246250395075f, hi_c = -3.4657359027997265f;
  float gam = 1.f - __expf(lo_c + (hi_c - lo_c) * ((float)h * (1.f / 15.f)));
  float logg = __logf(gam);

  // Factored decay (same integer exp arguments as r6/r9 -> identical values).
  float rowf[2][4], colf[2];
#pragma unroll
  for (int rt = 0; rt < 2; ++rt)
#pragma unroll
    for (int rr = 0; rr < 4; ++rr)
      rowf[rt][rr] = __expf((float)(wr * 32 + rt * 16 + quad * 4 + rr) * logg);
#pragma unroll
  for (int ns = 0; ns < 2; ++ns)
    colf[ns] = __expf(-(float)(wc * 32 + ns * 16 + ln) * logg);

  const unsigned short* khb = k_h + (size_t)h * S_ * 128;
  const unsigned short* klb = k_l + (size_t)h * S_ * 128;
  const unsigned short* vhb = v_th + (size_t)h * 64 * S_;
  const unsigned short* vlb = v_tl + (size_t)h * 64 * S_;

  // Q fragments (A-layout), 2 row-tiles, precomputed bf16 hi/lo.
  short8 qfh[2][4], qfl[2][4];
#pragma unroll
  for (int rt = 0; rt < 2; ++rt) {
    int sQ = s0 + wr * 32 + rt * 16 + ln;
    const unsigned short* qhp = q_h + ((size_t)h * S_ + sQ) * 128 + quad * 8;
    const unsigned short* qlp = q_l + ((size_t)h * S_ + sQ) * 128 + quad * 8;
#pragma unroll
    for (int c = 0; c < 4; ++c) {
      qfh[rt][c] = *reinterpret_cast<const short8*>(qhp + c * 32);
      qfl[rt][c] = *reinterpret_cast<const short8*>(qlp + c * 32);
    }
  }

  floatx4 accO[4];
#pragma unroll
  for (int i = 0; i < 4; ++i) accO[i] = (floatx4){0.f, 0.f, 0.f, 0.f};

  // Prologue: stage tile kt0 -> K + V[0]; prefetch kt0+1 into regs.
  ushort8 skh[4], skl[4], svh[2], svl[2];
  {
    int t00 = kt0 * 64;
#pragma unroll
    for (int i = 0; i < 4; ++i) {
      int cid = tid + i * 256;
      int r = cid >> 4, c8 = (cid & 15) * 8;
      skh[i] = *reinterpret_cast<const ushort8*>(khb + ((size_t)(t00 + r)) * 128 + c8);
      skl[i] = *reinterpret_cast<const ushort8*>(klb + ((size_t)(t00 + r)) * 128 + c8);
    }
#pragma unroll
    for (int i = 0; i < 2; ++i) {
      int cid = tid + i * 256;
      int d = cid >> 3, t8 = (cid & 7) * 8;
      svh[i] = *reinterpret_cast<const ushort8*>(vhb + (size_t)d * S_ + t00 + t8);
      svl[i] = *reinterpret_cast<const ushort8*>(vlb + (size_t)d * S_ + t00 + t8);
    }
#pragma unroll
    for (int i = 0; i < 4; ++i) {
      int cid = tid + i * 256;
      int r = cid >> 4;
      int ko = r * 256 + (((cid & 15) * 16) ^ ((r & 7) << 4));
      *reinterpret_cast<ushort8*>(KhB + ko) = skh[i];
      *reinterpret_cast<ushort8*>(KlB + ko) = skl[i];
    }
#pragma unroll
    for (int i = 0; i < 2; ++i) {
      int cid = tid + i * 256;
      int d = cid >> 3;
      int vo = d * 128 + (((cid & 7) * 16) ^ ((d & 7) << 4));  // buffer 0
      *reinterpret_cast<ushort8*>(VhB + vo) = svh[i];
      *reinterpret_cast<ushort8*>(VlB + vo) = svl[i];
    }
    if (kt0 + 1 < kt1) {
      int t01 = (kt0 + 1) * 64;
#pragma unroll
      for (int i = 0; i < 4; ++i) {
        int cid = tid + i * 256;
        int r = cid >> 4, c8 = (cid & 15) * 8;
        skh[i] = *reinterpret_cast<const ushort8*>(khb + ((size_t)(t01 + r)) * 128 + c8);
        skl[i] = *reinterpret_cast<const ushort8*>(klb + ((size_t)(t01 + r)) * 128 + c8);
      }
#pragma unroll
      for (int i = 0; i < 2; ++i) {
        int cid = tid + i * 256;
        int d = cid >> 3, t8 = (cid & 7) * 8;
        svh[i] = *reinterpret_cast<const ushort8*>(vhb + (size_t)d * S_ + t01 + t8);
        svl[i] = *reinterpret_cast<const ushort8*>(vlb + (size_t)d * S_ + t01 + t8);
      }
    }
  }
  __syncthreads();

  for (int kt = kt0; kt < kt1; ++kt) {
    int vb = (kt - kt0) & 1;
    // QK^T split-MFMA, 2x2 quadrant — setprio'd cluster.
    floatx4 accS[2][2];
#pragma unroll
    for (int rt = 0; rt < 2; ++rt)
#pragma unroll
      for (int ns = 0; ns < 2; ++ns) accS[rt][ns] = (floatx4){0.f, 0.f, 0.f, 0.f};
    __builtin_amdgcn_s_setprio(1);
#pragma unroll
    for (int ns = 0; ns < 2; ++ns) {
      int krow = wc * 32 + ns * 16 + ln;
#pragma unroll
      for (int ks = 0; ks < 4; ++ks) {
        int off = krow * 256 + ((ks * 64 + quad * 16) ^ ((ln & 7) << 4));
        short8 kh = *reinterpret_cast<const short8*>(KhB + off);
        short8 kl = *reinterpret_cast<const short8*>(KlB + off);
#pragma unroll
        for (int rt = 0; rt < 2; ++rt) {
          accS[rt][ns] = __builtin_amdgcn_mfma_f32_16x16x32_bf16(qfh[rt][ks], kh, accS[rt][ns], 0, 0, 0);
          accS[rt][ns] = __builtin_amdgcn_mfma_f32_16x16x32_bf16(qfl[rt][ks], kh, accS[rt][ns], 0, 0, 0);
          accS[rt][ns] = __builtin_amdgcn_mfma_f32_16x16x32_bf16(qfh[rt][ks], kl, accS[rt][ns], 0, 0, 0);
        }
      }
    }
    __builtin_amdgcn_s_setprio(0);

    // Factored decay (+ causal select only on the diagonal tile) -> Sc.
    float tf = __expf((float)(64 * (qt - kt)) * logg);
    float trf[2][4];
#pragma unroll
    for (int rt = 0; rt < 2; ++rt)
#pragma unroll
      for (int rr = 0; rr < 4; ++rr) trf[rt][rr] = tf * rowf[rt][rr];
    if (kt < qt) {
#pragma unroll
      for (int rt = 0; rt < 2; ++rt)
#pragma unroll
        for (int ns = 0; ns < 2; ++ns) {
          int col = wc * 32 + ns * 16 + ln;
#pragma unroll
          for (int rr = 0; rr < 4; ++rr) {
            int row = wr * 32 + rt * 16 + quad * 4 + rr;
            *reinterpret_cast<float*>(ScB + SCOFF(row, col * 4)) =
                accS[rt][ns][rr] * trf[rt][rr] * colf[ns];
          }
        }
    } else {
#pragma unroll
      for (int rt = 0; rt < 2; ++rt)
#pragma unroll
        for (int ns = 0; ns < 2; ++ns) {
          int col = wc * 32 + ns * 16 + ln;
#pragma unroll
          for (int rr = 0; rr < 4; ++rr) {
            int row = wr * 32 + rt * 16 + quad * 4 + rr;
            float v = accS[rt][ns][rr] * trf[rt][rr] * colf[ns];
            *reinterpret_cast<float*>(ScB + SCOFF(row, col * 4)) =
                (row >= col) ? v : 0.f;
          }
        }
    }
    __syncthreads();  // B1: Sc visible; all K reads AND V[vb^1] reads done

    // Staged writes overlap PV: K (single buffer, reads finished at B1) and
    // V[next] into the alternate buffer. Then issue kt+2 prefetch.
    if (kt + 1 < kt1) {
#pragma unroll
      for (int i = 0; i < 4; ++i) {
        int cid = tid + i * 256;
        int r = cid >> 4;
        int ko = r * 256 + (((cid & 15) * 16) ^ ((r & 7) << 4));
        *reinterpret_cast<ushort8*>(KhB + ko) = skh[i];
        *reinterpret_cast<ushort8*>(KlB + ko) = skl[i];
      }
#pragma unroll
      for (int i = 0; i < 2; ++i) {
        int cid = tid + i * 256;
        int d = cid >> 3;
        int vo = (vb ^ 1) * 8192 + d * 128 + (((cid & 7) * 16) ^ ((d & 7) << 4));
        *reinterpret_cast<ushort8*>(VhB + vo) = svh[i];
        *reinterpret_cast<ushort8*>(VlB + vo) = svl[i];
      }
      if (kt + 2 < kt1) {
        int t0n = (kt + 2) * 64;
#pragma unroll
        for (int i = 0; i < 4; ++i) {
          int cid = tid + i * 256;
          int r = cid >> 4, c8 = (cid & 15) * 8;
          skh[i] = *reinterpret_cast<const ushort8*>(khb + ((size_t)(t0n + r)) * 128 + c8);
          skl[i] = *reinterpret_cast<const ushort8*>(klb + ((size_t)(t0n + r)) * 128 + c8);
        }
#pragma unroll
        for (int i = 0; i < 2; ++i) {
          int cid = tid + i * 256;
          int d = cid >> 3, t8 = (cid & 7) * 8;
          svh[i] = *reinterpret_cast<const ushort8*>(vhb + (size_t)d * S_ + t0n + t8);
          svl[i] = *reinterpret_cast<const ushort8*>(vlb + (size_t)d * S_ + t0n + t8);
        }
      }
    }

    // PV split-MFMA: reads Sc + V[vb] (disjoint from the writes above).
    __builtin_amdgcn_s_setprio(1);
#pragma unroll
    for (int ks = 0; ks < 2; ++ks) {
      int prw = w * 16 + ln;
      int cb = ks * 128 + quad * 32;
      float4v p0 = *reinterpret_cast<const float4v*>(ScB + SCOFF(prw, cb));
      float4v p1 = *reinterpret_cast<const float4v*>(ScB + SCOFF(prw, cb + 16));
      short8 ph, pl;
#pragma unroll
      for (int j = 0; j < 4; ++j) {
        unsigned short hh = f2bf(p0[j]);
        ph[j] = (short)hh;
        pl[j] = (short)f2bf(p0[j] - bf2f(hh));
        unsigned short hh2 = f2bf(p1[j]);
        ph[4 + j] = (short)hh2;
        pl[4 + j] = (short)f2bf(p1[j] - bf2f(hh2));
      }
#pragma unroll
      for (int ds = 0; ds < 4; ++ds) {
        int d = ds * 16 + ln;
        int voff = vb * 8192 + d * 128 + ((ks * 64 + quad * 16) ^ ((ln & 7) << 4));
        short8 vh = *reinterpret_cast<const short8*>(VhB + voff);
        short8 vl = *reinterpret_cast<const short8*>(VlB + voff);
        accO[ds] = __builtin_amdgcn_mfma_f32_16x16x32_bf16(ph, vh, accO[ds], 0, 0, 0);
        accO[ds] = __builtin_amdgcn_mfma_f32_16x16x32_bf16(pl, vh, accO[ds], 0, 0, 0);
        accO[ds] = __builtin_amdgcn_mfma_f32_16x16x32_bf16(ph, vl, accO[ds], 0, 0, 0);
      }
    }
    __builtin_amdgcn_s_setprio(0);

    __syncthreads();  // B2: PV reads done; staged K/V writes visible
  }

  // Epilogue: store raw fp32 partial accO (16 KB/block).
  float* pout = partial + ((size_t)(((h * 32 + qt) << 1) + half)) * 4096;
#pragma unroll
  for (int ds = 0; ds < 4; ++ds) {
#pragma unroll
    for (int rr = 0; rr < 4; ++rr) {
      pout[(w * 16 + quad * 4 + rr) * 64 + ds * 16 + ln] = accO[ds][rr];
    }
  }
}

// ---------------------------------------------------------------------------
// Kernel B2: combine halves + GroupNorm (proven).
// ---------------------------------------------------------------------------
__global__ __launch_bounds__(256) void combine_gn_kernel(
    const float* __restrict__ partial, const float* __restrict__ gn_w,
    const float* __restrict__ gn_b, float* __restrict__ retn, int b) {
  __shared__ float gnred[64][8];
  int tid = threadIdx.x;
  int qi = blockIdx.x;            // qi = h*32 + qt
  int h = qi >> 5, qt = qi & 31;
  const float* p0 = partial + (size_t)qi * 8192;
  const float* p1 = p0 + 4096;

  int r2 = tid >> 2;
  int sub = tid & 3;
  float a16[16];
#pragma unroll
  for (int c = 0; c < 4; ++c) {
    int o = r2 * 64 + sub * 16 + c * 4;
    float4v va = *reinterpret_cast<const float4v*>(p0 + o);
    float4v vb = *reinterpret_cast<const float4v*>(p1 + o);
#pragma unroll
    for (int j = 0; j < 4; ++j) a16[c * 4 + j] = va[j] + vb[j];
  }

  float psum = 0.f, psq = 0.f;
#pragma unroll
  for (int i = 0; i < 16; ++i) { psum += a16[i]; psq += a16[i] * a16[i]; }
  gnred[r2][sub] = psum;
  gnred[r2][4 + sub] = psq;
  __syncthreads();
  float sum = gnred[r2][0] + gnred[r2][1] + gnred[r2][2] + gnred[r2][3];
  float sq = gnred[r2][4] + gnred[r2][5] + gnred[r2][6] + gnred[r2][7];
  float mean = sum * (1.f / 64.f);
  float var = sq * (1.f / 64.f) - mean * mean;
  float rstd = rsqrtf(var + 1e-5f);

  size_t obase = ((size_t)(b * S_ + qt * 64 + r2)) * HID_ + h * DH_ + sub * 16;
#pragma unroll
  for (int i = 0; i < 16; ++i) {
    float gw = gn_w[h * DH_ + sub * 16 + i];
    float gb = gn_b[h * DH_ + sub * 16 + i];
    retn[obase + i] = (a16[i] - mean) * rstd * gw + gb;
  }
}

// ---------------------------------------------------------------------------
// GEMM 1 (gate): r13 config (BM128/BN64/BK32, acc[4][2], reg prefetch, LDS
// double-buffer, 1 barrier/K-step). Passing — unchanged.
// ---------------------------------------------------------------------------
__global__ __launch_bounds__(256) void gemm_gate_kernel(
    const unsigned short* __restrict__ A, const unsigned short* __restrict__ Bt,
    const float* __restrict__ retn, unsigned short* __restrict__ pre_hi,
    unsigned short* __restrict__ pre_lo) {
  const int K = HID_;
  __shared__ __align__(16) unsigned short Al[2][128 * 56];  // 28.7 KiB
  __shared__ __align__(16) unsigned short Bl[2][64 * 56];   // 14.3 KiB

  int tid = threadIdx.x;
  int lane = tid & 63, ln = lane & 15, quad = lane >> 4;
  int w = tid >> 6, wm = w >> 1, wn = w & 1;
  int m0 = blockIdx.y * 128, n0 = blockIdx.x * 64;

  floatx4 acc[4][2];
#pragma unroll
  for (int i = 0; i < 4; ++i)
#pragma unroll
    for (int j = 0; j < 2; ++j) acc[i][j] = (floatx4){0.f, 0.f, 0.f, 0.f};

  int ra_r[2], ra_c[2], rb_r, rb_c;
#pragma unroll
  for (int i = 0; i < 2; ++i) {
    int cid = tid + i * 256;
    ra_r[i] = cid >> 2; ra_c[i] = (cid & 3) * 8;
  }
  rb_r = tid >> 2; rb_c = (tid & 3) * 8;

  // Prologue: tile0 -> buf0; tile1 -> regs.
  ushort8 ra[2], rb;
#pragma unroll
  for (int i = 0; i < 2; ++i)
    ra[i] = *reinterpret_cast<const ushort8*>(A + (size_t)(m0 + ra_r[i]) * K + ra_c[i]);
  rb = *reinterpret_cast<const ushort8*>(Bt + (size_t)(n0 + rb_r) * K + rb_c);
#pragma unroll
  for (int i = 0; i < 2; ++i)
    *reinterpret_cast<ushort8*>(&Al[0][ra_r[i] * 56 + ra_c[i]]) = ra[i];
  *reinterpret_cast<ushort8*>(&Bl[0][rb_r * 56 + rb_c]) = rb;
#pragma unroll
  for (int i = 0; i < 2; ++i)
    ra[i] = *reinterpret_cast<const ushort8*>(A + (size_t)(m0 + ra_r[i]) * K + 32 + ra_c[i]);
  rb = *reinterpret_cast<const ushort8*>(Bt + (size_t)(n0 + rb_r) * K + 32 + rb_c);
  __syncthreads();

  for (int k0 = 0; k0 < K; k0 += 32) {
    int cur = (k0 >> 5) & 1;
    if (k0 + 32 < K) {
      int nx = cur ^ 1;
#pragma unroll
      for (int i = 0; i < 2; ++i)
        *reinterpret_cast<ushort8*>(&Al[nx][ra_r[i] * 56 + ra_c[i]]) = ra[i];
      *reinterpret_cast<ushort8*>(&Bl[nx][rb_r * 56 + rb_c]) = rb;
      if (k0 + 64 < K) {
#pragma unroll
        for (int i = 0; i < 2; ++i)
          ra[i] = *reinterpret_cast<const ushort8*>(A + (size_t)(m0 + ra_r[i]) * K + k0 + 64 + ra_c[i]);
        rb = *reinterpret_cast<const ushort8*>(Bt + (size_t)(n0 + rb_r) * K + k0 + 64 + rb_c);
      }
    }

    short8 af[4], bfr[2];
#pragma unroll
    for (int i = 0; i < 4; ++i)
      af[i] = *reinterpret_cast<const short8*>(&Al[cur][(wm * 64 + i * 16 + ln) * 56 + quad * 8]);
#pragma unroll
    for (int i = 0; i < 2; ++i)
      bfr[i] = *reinterpret_cast<const short8*>(&Bl[cur][(wn * 32 + i * 16 + ln) * 56 + quad * 8]);
#pragma unroll
    for (int mi = 0; mi < 4; ++mi)
#pragma unroll
      for (int ni = 0; ni < 2; ++ni)
        acc[mi][ni] = __builtin_amdgcn_mfma_f32_16x16x32_bf16(af[mi], bfr[ni], acc[mi][ni], 0, 0, 0);
    __syncthreads();  // writes to buf^1 visible; reads of buf done
  }

#pragma unroll
  for (int mi = 0; mi < 4; ++mi) {
#pragma unroll
    for (int r = 0; r < 4; ++r) {
      int row = m0 + wm * 64 + mi * 16 + quad * 4 + r;
#pragma unroll
      for (int ni = 0; ni < 2; ++ni) {
        int col = n0 + wn * 32 + ni * 16 + ln;
        float g = acc[mi][ni][r];
        float val = g * (1.f / (1.f + __expf(-g))) + retn[(size_t)row * HID_ + col];
        unsigned short hh = f2bf(val);
        size_t oidx = (size_t)row * HID_ + col;
        pre_hi[oidx] = hh;
        pre_lo[oidx] = f2bf(val - bf2f(hh));
      }
    }
  }
}

// ---------------------------------------------------------------------------
// GEMM 2 (output): r10/r13 config (BM128/BN64/BK32, acc[4][2], register
// prefetch, 2 barriers). Passing — unchanged.
// ---------------------------------------------------------------------------
__global__ __launch_bounds__(256) void gemm_out_kernel(
    const unsigned short* __restrict__ Ah, const unsigned short* __restrict__ Alo,
    const unsigned short* __restrict__ Bth, const unsigned short* __restrict__ Btlo,
    float* __restrict__ out_f) {
  const int K = HID_;
  __shared__ __align__(16) unsigned short AhS[128 * 56];
  __shared__ __align__(16) unsigned short AlS[128 * 56];
  __shared__ __align__(16) unsigned short BhS[64 * 56];
  __shared__ __align__(16) unsigned short BlS[64 * 56];

  int tid = threadIdx.x;
  int lane = tid & 63, ln = lane & 15, quad = lane >> 4;
  int w = tid >> 6, wm = w >> 1, wn = w & 1;
  int m0 = blockIdx.y * 128, n0 = blockIdx.x * 64;

  floatx4 acc[4][2];
#pragma unroll
  for (int i = 0; i < 4; ++i)
#pragma unroll
    for (int j = 0; j < 2; ++j) acc[i][j] = (floatx4){0.f, 0.f, 0.f, 0.f};

  int ra_r[2], ra_c[2], rb_r, rb_c;
#pragma unroll
  for (int i = 0; i < 2; ++i) {
    int cid = tid + i * 256;
    ra_r[i] = cid >> 2; ra_c[i] = (cid & 3) * 8;
  }
  rb_r = tid >> 2; rb_c = (tid & 3) * 8;

  // Prefetch tile 0.
  ushort8 rah[2], ral[2], rbh, rbl;
#pragma unroll
  for (int i = 0; i < 2; ++i) {
    size_t ga = (size_t)(m0 + ra_r[i]) * K + ra_c[i];
    rah[i] = *reinterpret_cast<const ushort8*>(Ah + ga);
    ral[i] = *reinterpret_cast<const ushort8*>(Alo + ga);
  }
  {
    size_t gb = (size_t)(n0 + rb_r) * K + rb_c;
    rbh = *reinterpret_cast<const ushort8*>(Bth + gb);
    rbl = *reinterpret_cast<const ushort8*>(Btlo + gb);
  }

  for (int k0 = 0; k0 < K; k0 += 32) {
#pragma unroll
    for (int i = 0; i < 2; ++i) {
      *reinterpret_cast<ushort8*>(&AhS[ra_r[i] * 56 + ra_c[i]]) = rah[i];
      *reinterpret_cast<ushort8*>(&AlS[ra_r[i] * 56 + ra_c[i]]) = ral[i];
    }
    *reinterpret_cast<ushort8*>(&BhS[rb_r * 56 + rb_c]) = rbh;
    *reinterpret_cast<ushort8*>(&BlS[rb_r * 56 + rb_c]) = rbl;
    if (k0 + 32 < K) {
#pragma unroll
      for (int i = 0; i < 2; ++i) {
        size_t ga = (size_t)(m0 + ra_r[i]) * K + k0 + 32 + ra_c[i];
        rah[i] = *reinterpret_cast<const ushort8*>(Ah + ga);
        ral[i] = *reinterpret_cast<const ushort8*>(Alo + ga);
      }
      size_t gb = (size_t)(n0 + rb_r) * K + k0 + 32 + rb_c;
      rbh = *reinterpret_cast<const ushort8*>(Bth + gb);
      rbl = *reinterpret_cast<const ushort8*>(Btlo + gb);
    }
    __syncthreads();

    short8 afh[4], afl[4], bfh[2], bfl[2];
#pragma unroll
    for (int i = 0; i < 4; ++i) {
      int ao = (wm * 64 + i * 16 + ln) * 56 + quad * 8;
      afh[i] = *reinterpret_cast<const short8*>(&AhS[ao]);
      afl[i] = *reinterpret_cast<const short8*>(&AlS[ao]);
    }
#pragma unroll
    for (int i = 0; i < 2; ++i) {
      int bo = (wn * 32 + i * 16 + ln) * 56 + quad * 8;
      bfh[i] = *reinterpret_cast<const short8*>(&BhS[bo]);
      bfl[i] = *reinterpret_cast<const short8*>(&BlS[bo]);
    }
#pragma unroll
    for (int mi = 0; mi < 4; ++mi)
#pragma unroll
      for (int ni = 0; ni < 2; ++ni) {
        floatx4 a = acc[mi][ni];
        a = __builtin_amdgcn_mfma_f32_16x16x32_bf16(afh[mi], bfh[ni], a, 0, 0, 0);
        a = __builtin_amdgcn_mfma_f32_16x16x32_bf16(afl[mi], bfh[ni], a, 0, 0, 0);
        a = __builtin_amdgcn_mfma_f32_16x16x32_bf16(afh[mi], bfl[ni], a, 0, 0, 0);
        acc[mi][ni] = a;
      }
    __syncthreads();
  }

#pragma unroll
  for (int mi = 0; mi < 4; ++mi) {
#pragma unroll
    for (int r = 0; r < 4; ++r) {
      int row = m0 + wm * 64 + mi * 16 + quad * 4 + r;
#pragma unroll
      for (int ni = 0; ni < 2; ++ni) {
        int col = n0 + wn * 32 + ni * 16 + ln;
        out_f[(size_t)row * HID_ + col] = acc[mi][ni][r];
      }
    }
  }
}

// ---------------------------------------------------------------------------
extern "C" void kernel_launch(void* const* d_in, const int* in_sizes, int n_in,
                              void* d_out, int out_size, void* d_ws,
                              size_t ws_size, hipStream_t stream) {
  (void)in_sizes; (void)n_in; (void)out_size; (void)ws_size;
  const float* x = (const float*)d_in[0];
  const float* wq = (const float*)d_in[1];
  const float* bq = (const float*)d_in[2];
  const float* wk = (const float*)d_in[3];
  const float* bk = (const float*)d_in[4];
  const float* wv = (const float*)d_in[5];
  const float* theta = (const float*)d_in[6];
  const float* gn_w = (const float*)d_in[7];
  const float* gn_b = (const float*)d_in[8];
  const float* w1 = (const float*)d_in[9];
  const float* w2 = (const float*)d_in[10];

  const size_t MB = 1024 * 1024;
  char* ws = (char*)d_ws;
  unsigned short* x_bf   = (unsigned short*)(ws + 0 * MB);    //  8 MiB
  unsigned short* w1t    = (unsigned short*)(ws + 8 * MB);    //  2 MiB
  unsigned short* w2t_hi = (unsigned short*)(ws + 10 * MB);   //  2 MiB
  unsigned short* w2t_lo = (unsigned short*)(ws + 12 * MB);   //  2 MiB
  unsigned short* q_h    = (unsigned short*)(ws + 14 * MB);   //  8 MiB (1 batch)
  unsigned short* q_l    = (unsigned short*)(ws + 22 * MB);   //  8 MiB
  unsigned short* k_h    = (unsigned short*)(ws + 30 * MB);   //  8 MiB
  unsigned short* k_l    = (unsigned short*)(ws + 38 * MB);   //  8 MiB
  unsigned short* v_th   = (unsigned short*)(ws + 46 * MB);   //  4 MiB
  unsigned short* v_tl   = (unsigned short*)(ws + 50 * MB);   //  4 MiB
  float*          retn   = (float*)(ws + 54 * MB);            // 16 MiB (both batches)
  float*          partial= (float*)(ws + 70 * MB);            // 16 MiB (per batch, reused)
  unsigned short* pre_hi = (unsigned short*)(ws + 14 * MB);   //  8 MiB (alias q_h, dead by then)
  unsigned short* pre_lo = (unsigned short*)(ws + 22 * MB);   //  8 MiB (alias q_l)
  float* out = (float*)d_out;

  convert_x_kernel<<<dim3((B_ * S_ * HID_) / 8 / 256), 256, 0, stream>>>(x, x_bf);
  transpose_w_kernel<<<dim3(512), 256, 0, stream>>>(w1, w2, w1t, w2t_hi, w2t_lo);
  for (int b = 0; b < B_; ++b) {
    qkv_kernel<<<dim3(S_ / 64, H_), 256, 0, stream>>>(
        x, wq, bq, wk, bk, wv, theta, q_h, q_l, k_h, k_l, v_th, v_tl, b);
    retention_split_kernel<<<dim3(1024), 256, 0, stream>>>(
        q_h, q_l, k_h, k_l, v_th, v_tl, partial);
    combine_gn_kernel<<<dim3(512), 256, 0, stream>>>(
        partial, gn_w, gn_b, retn, b);
  }
  gemm_gate_kernel<<<dim3(HID_ / 64, (B_ * S_) / 128), 256, 0, stream>>>(
      x_bf, w1t, retn, pre_hi, pre_lo);
  gemm_out_kernel<<<dim3(HID_ / 64, (B_ * S_) / 128), 256, 0, stream>>>(
      pre_hi, pre_lo, w2t_hi, w2t_lo, out);
}